// Round 1
// baseline (2770.856 us; speedup 1.0000x reference)
//
#include <hip/hip_runtime.h>
#include <hip/hip_bf16.h>

#define NN 100000
#define NE 600000
#define DD 128

__device__ __forceinline__ void atomic_max_float(float* addr, float val) {
    if (val >= 0.0f) {
        atomicMax((int*)addr, __float_as_int(val));
    } else {
        atomicMin((unsigned int*)addr, __float_as_uint(val));
    }
}

// ---------------- init: zero aggr & attn_sum, attn_max = -inf ----------------
__global__ void k_init(float* __restrict__ aggr, float* __restrict__ attn_sum,
                       unsigned int* __restrict__ attn_max_bits) {
    int i = blockIdx.x * blockDim.x + threadIdx.x;
    int stride = gridDim.x * blockDim.x;
    for (int idx = i; idx < NN * DD; idx += stride) aggr[idx] = 0.0f;
    for (int idx = i; idx < NN; idx += stride) {
        attn_sum[idx] = 0.0f;
        attn_max_bits[idx] = 0xFF800000u; // -inf
    }
}

// ---------------- edge kernel: messages + attn logits + segment max ----------
// block = 128 threads (2 waves), 8 edges per block. thread t owns channel j=t.
__global__ __launch_bounds__(128) void k_edge(
    const float* __restrict__ nf, const int* __restrict__ src,
    const int* __restrict__ dst, const int* __restrict__ etype,
    const float* __restrict__ rel,
    const float* __restrict__ mw1, const float* __restrict__ mb1,
    const float* __restrict__ mw2, const float* __restrict__ mb2,
    const float* __restrict__ aw1, const float* __restrict__ ab1,
    const float* __restrict__ aw2, const float* __restrict__ ab2,
    __hip_bfloat16* __restrict__ msg_out,
    float* __restrict__ attn_raw, float* __restrict__ attn_max)
{
    __shared__ float hbuf[8][256];
    __shared__ float hid[8][128];
    __shared__ float red[8][2];
    __shared__ int sdst[8];
    const int t = threadIdx.x;
    const int e0 = blockIdx.x * 8;

    // stage h = [nf[src] || rel[type]]
    #pragma unroll
    for (int e = 0; e < 8; ++e) {
        int eg = e0 + e;
        hbuf[e][t]       = nf[(long)src[eg] * DD + t];
        hbuf[e][128 + t] = rel[(long)etype[eg] * DD + t];
    }
    if (t < 8) sdst[t] = dst[e0 + t];
    __syncthreads();

    // phase 1: hidden = relu(h @ mw1 + mb1)
    float acc[8];
    {
        float b = mb1[t];
        #pragma unroll
        for (int e = 0; e < 8; ++e) acc[e] = b;
    }
    for (int kc = 0; kc < 64; ++kc) {
        float w0 = mw1[(kc * 4 + 0) * DD + t];
        float w1 = mw1[(kc * 4 + 1) * DD + t];
        float w2 = mw1[(kc * 4 + 2) * DD + t];
        float w3 = mw1[(kc * 4 + 3) * DD + t];
        #pragma unroll
        for (int e = 0; e < 8; ++e) {
            float4 h = *reinterpret_cast<const float4*>(&hbuf[e][kc * 4]);
            acc[e] = fmaf(h.x, w0, acc[e]);
            acc[e] = fmaf(h.y, w1, acc[e]);
            acc[e] = fmaf(h.z, w2, acc[e]);
            acc[e] = fmaf(h.w, w3, acc[e]);
        }
    }
    #pragma unroll
    for (int e = 0; e < 8; ++e) hid[e][t] = fmaxf(acc[e], 0.0f);
    __syncthreads();

    // phase 2: messages = hidden @ mw2 + mb2
    {
        float b = mb2[t];
        #pragma unroll
        for (int e = 0; e < 8; ++e) acc[e] = b;
    }
    for (int kc = 0; kc < 32; ++kc) {
        float w0 = mw2[(kc * 4 + 0) * DD + t];
        float w1 = mw2[(kc * 4 + 1) * DD + t];
        float w2 = mw2[(kc * 4 + 2) * DD + t];
        float w3 = mw2[(kc * 4 + 3) * DD + t];
        #pragma unroll
        for (int e = 0; e < 8; ++e) {
            float4 h = *reinterpret_cast<const float4*>(&hid[e][kc * 4]);
            acc[e] = fmaf(h.x, w0, acc[e]);
            acc[e] = fmaf(h.y, w1, acc[e]);
            acc[e] = fmaf(h.z, w2, acc[e]);
            acc[e] = fmaf(h.w, w3, acc[e]);
        }
    }
    // store messages (bf16), build a_in = [nf[dst] || messages] in hbuf
    #pragma unroll
    for (int e = 0; e < 8; ++e) {
        int eg = e0 + e;
        msg_out[(long)eg * DD + t] = __float2bfloat16(acc[e]);
        hbuf[e][128 + t] = acc[e];
        hbuf[e][t] = nf[(long)sdst[e] * DD + t];
    }
    __syncthreads();

    // phase 3: z = leaky_relu(a_in @ aw1 + ab1, 0.2)
    float acc3[8];
    {
        float b = ab1[t];
        #pragma unroll
        for (int e = 0; e < 8; ++e) acc3[e] = b;
    }
    for (int kc = 0; kc < 64; ++kc) {
        float w0 = aw1[(kc * 4 + 0) * DD + t];
        float w1 = aw1[(kc * 4 + 1) * DD + t];
        float w2 = aw1[(kc * 4 + 2) * DD + t];
        float w3 = aw1[(kc * 4 + 3) * DD + t];
        #pragma unroll
        for (int e = 0; e < 8; ++e) {
            float4 h = *reinterpret_cast<const float4*>(&hbuf[e][kc * 4]);
            acc3[e] = fmaf(h.x, w0, acc3[e]);
            acc3[e] = fmaf(h.y, w1, acc3[e]);
            acc3[e] = fmaf(h.z, w2, acc3[e]);
            acc3[e] = fmaf(h.w, w3, acc3[e]);
        }
    }
    // phase 4: attn_raw = z . aw2 + ab2 (reduce over 128 channels)
    float aw2v = aw2[t];
    #pragma unroll
    for (int e = 0; e < 8; ++e) {
        float v = acc3[e];
        v = (v > 0.0f) ? v : 0.2f * v;
        v *= aw2v;
        #pragma unroll
        for (int off = 32; off >= 1; off >>= 1)
            v += __shfl_down(v, off, 64);
        if ((t & 63) == 0) red[e][t >> 6] = v;
    }
    __syncthreads();
    if (t < 8) {
        float raw = red[t][0] + red[t][1] + ab2[0];
        attn_raw[e0 + t] = raw;
        atomic_max_float(&attn_max[sdst[t]], raw);
    }
}

// ---------------- segment softmax: exp + sum ----------------
__global__ void k_expsum(const float* __restrict__ attn_raw, const int* __restrict__ dst,
                         const float* __restrict__ attn_max,
                         float* __restrict__ attn_exp, float* __restrict__ attn_sum)
{
    int e = blockIdx.x * 256 + threadIdx.x;
    if (e < NE) {
        int d = dst[e];
        float ex = expf(attn_raw[e] - attn_max[d]);
        attn_exp[e] = ex;
        atomicAdd(&attn_sum[d], ex);
    }
}

// ---------------- scatter: aggr += attn_w * messages ----------------
__global__ __launch_bounds__(128) void k_scatter(
    const __hip_bfloat16* __restrict__ msg, const float* __restrict__ attn_exp,
    const float* __restrict__ attn_sum, const int* __restrict__ dst,
    float* __restrict__ aggr)
{
    const int t = threadIdx.x;
    const int e0 = blockIdx.x * 8;
    #pragma unroll
    for (int e = 0; e < 8; ++e) {
        int eg = e0 + e;
        int d = dst[eg];
        float w = attn_exp[eg] / (attn_sum[d] + 1e-8f);
        float m = __bfloat162float(msg[(long)eg * DD + t]);
        atomicAdd(&aggr[(long)d * DD + t], w * m);
    }
}

// ---------------- node kernel: LN1 + FFN + LN2 ----------------
// block = 128 threads, 8 nodes per block.
__global__ __launch_bounds__(128) void k_node(
    const float* __restrict__ nf, const float* __restrict__ aggr,
    const float* __restrict__ g1, const float* __restrict__ b1,
    const float* __restrict__ fw1, const float* __restrict__ fb1,
    const float* __restrict__ fw2, const float* __restrict__ fb2,
    const float* __restrict__ g2, const float* __restrict__ b2,
    float* __restrict__ out)
{
    __shared__ float xbuf[8][128];
    __shared__ float hid[8][512];
    __shared__ float rsum[8][2], rsq[8][2];
    const int t = threadIdx.x;
    const long n0 = (long)blockIdx.x * 8;

    float xr[8];
    #pragma unroll
    for (int nn = 0; nn < 8; ++nn) {
        long idx = (n0 + nn) * DD + t;
        xr[nn] = nf[idx] + aggr[idx];
    }
    // LN1 reduce
    #pragma unroll
    for (int nn = 0; nn < 8; ++nn) {
        float s = xr[nn], q = xr[nn] * xr[nn];
        #pragma unroll
        for (int off = 32; off >= 1; off >>= 1) {
            s += __shfl_down(s, off, 64);
            q += __shfl_down(q, off, 64);
        }
        if ((t & 63) == 0) { rsum[nn][t >> 6] = s; rsq[nn][t >> 6] = q; }
    }
    __syncthreads();
    {
        float g1v = g1[t], b1v = b1[t];
        #pragma unroll
        for (int nn = 0; nn < 8; ++nn) {
            float mu  = (rsum[nn][0] + rsum[nn][1]) * (1.0f / DD);
            float var = (rsq[nn][0] + rsq[nn][1]) * (1.0f / DD) - mu * mu;
            float x = (xr[nn] - mu) * rsqrtf(var + 1e-5f) * g1v + b1v;
            xr[nn] = x;
            xbuf[nn][t] = x;
        }
    }
    __syncthreads();

    // FFN layer 1: hidden j = t + 128u, u=0..3
    float fbv[4];
    #pragma unroll
    for (int u = 0; u < 4; ++u) fbv[u] = fb1[t + 128 * u];
    float acc[8][4];
    #pragma unroll
    for (int nn = 0; nn < 8; ++nn)
        #pragma unroll
        for (int u = 0; u < 4; ++u) acc[nn][u] = fbv[u];

    for (int kc = 0; kc < 32; ++kc) {
        float4 xv[8];
        #pragma unroll
        for (int nn = 0; nn < 8; ++nn)
            xv[nn] = *reinterpret_cast<const float4*>(&xbuf[nn][kc * 4]);
        #pragma unroll
        for (int i = 0; i < 4; ++i) {
            int k = kc * 4 + i;
            float w0 = fw1[k * 512 + t];
            float w1 = fw1[k * 512 + t + 128];
            float w2 = fw1[k * 512 + t + 256];
            float w3 = fw1[k * 512 + t + 384];
            #pragma unroll
            for (int nn = 0; nn < 8; ++nn) {
                float xk = (i == 0) ? xv[nn].x : (i == 1) ? xv[nn].y
                         : (i == 2) ? xv[nn].z : xv[nn].w;
                acc[nn][0] = fmaf(xk, w0, acc[nn][0]);
                acc[nn][1] = fmaf(xk, w1, acc[nn][1]);
                acc[nn][2] = fmaf(xk, w2, acc[nn][2]);
                acc[nn][3] = fmaf(xk, w3, acc[nn][3]);
            }
        }
    }
    // exact gelu
    #pragma unroll
    for (int nn = 0; nn < 8; ++nn)
        #pragma unroll
        for (int u = 0; u < 4; ++u) {
            float h = acc[nn][u];
            hid[nn][t + 128 * u] = 0.5f * h * (1.0f + erff(h * 0.70710678118654752f));
        }
    __syncthreads();

    // FFN layer 2
    float acc2[8];
    {
        float b = fb2[t];
        #pragma unroll
        for (int nn = 0; nn < 8; ++nn) acc2[nn] = b;
    }
    for (int kc = 0; kc < 128; ++kc) {
        float w0 = fw2[(kc * 4 + 0) * DD + t];
        float w1 = fw2[(kc * 4 + 1) * DD + t];
        float w2 = fw2[(kc * 4 + 2) * DD + t];
        float w3 = fw2[(kc * 4 + 3) * DD + t];
        #pragma unroll
        for (int nn = 0; nn < 8; ++nn) {
            float4 h = *reinterpret_cast<const float4*>(&hid[nn][kc * 4]);
            acc2[nn] = fmaf(h.x, w0, acc2[nn]);
            acc2[nn] = fmaf(h.y, w1, acc2[nn]);
            acc2[nn] = fmaf(h.z, w2, acc2[nn]);
            acc2[nn] = fmaf(h.w, w3, acc2[nn]);
        }
    }

    // residual + LN2
    #pragma unroll
    for (int nn = 0; nn < 8; ++nn) xr[nn] += acc2[nn];
    __syncthreads();  // rsum/rsq reuse
    #pragma unroll
    for (int nn = 0; nn < 8; ++nn) {
        float s = xr[nn], q = xr[nn] * xr[nn];
        #pragma unroll
        for (int off = 32; off >= 1; off >>= 1) {
            s += __shfl_down(s, off, 64);
            q += __shfl_down(q, off, 64);
        }
        if ((t & 63) == 0) { rsum[nn][t >> 6] = s; rsq[nn][t >> 6] = q; }
    }
    __syncthreads();
    {
        float g2v = g2[t], b2v = b2[t];
        #pragma unroll
        for (int nn = 0; nn < 8; ++nn) {
            float mu  = (rsum[nn][0] + rsum[nn][1]) * (1.0f / DD);
            float var = (rsq[nn][0] + rsq[nn][1]) * (1.0f / DD) - mu * mu;
            out[(n0 + nn) * DD + t] = (xr[nn] - mu) * rsqrtf(var + 1e-5f) * g2v + b2v;
        }
    }
}

extern "C" void kernel_launch(void* const* d_in, const int* in_sizes, int n_in,
                              void* d_out, int out_size, void* d_ws, size_t ws_size,
                              hipStream_t stream)
{
    const float* nf  = (const float*)d_in[0];
    const int*   ei  = (const int*)d_in[1];
    const int*   et  = (const int*)d_in[2];
    const float* rel = (const float*)d_in[3];
    const float* mw1 = (const float*)d_in[4];
    const float* mb1 = (const float*)d_in[5];
    const float* mw2 = (const float*)d_in[6];
    const float* mb2 = (const float*)d_in[7];
    const float* aw1 = (const float*)d_in[8];
    const float* ab1 = (const float*)d_in[9];
    const float* aw2 = (const float*)d_in[10];
    const float* ab2 = (const float*)d_in[11];
    const float* g1  = (const float*)d_in[12];
    const float* b1  = (const float*)d_in[13];
    const float* fw1 = (const float*)d_in[14];
    const float* fb1 = (const float*)d_in[15];
    const float* fw2 = (const float*)d_in[16];
    const float* fb2 = (const float*)d_in[17];
    const float* g2  = (const float*)d_in[18];
    const float* b2  = (const float*)d_in[19];
    float* out = (float*)d_out;

    char* ws = (char*)d_ws;
    size_t off = 0;
    auto alloc = [&](size_t bytes) -> char* {
        char* p = ws + off;
        off += (bytes + 255) & ~(size_t)255;
        return p;
    };
    __hip_bfloat16* msg = (__hip_bfloat16*)alloc((size_t)NE * DD * 2);
    float* attn_raw = (float*)alloc((size_t)NE * 4);
    float* attn_exp = (float*)alloc((size_t)NE * 4);
    float* attn_max = (float*)alloc((size_t)NN * 4);
    float* attn_sum = (float*)alloc((size_t)NN * 4);
    float* aggr     = (float*)alloc((size_t)NN * DD * 4);

    const int* srcp = ei;
    const int* dstp = ei + NE;

    hipLaunchKernelGGL(k_init, dim3(2048), dim3(256), 0, stream,
                       aggr, attn_sum, (unsigned int*)attn_max);
    hipLaunchKernelGGL(k_edge, dim3(NE / 8), dim3(128), 0, stream,
                       nf, srcp, dstp, et, rel,
                       mw1, mb1, mw2, mb2, aw1, ab1, aw2, ab2,
                       msg, attn_raw, attn_max);
    hipLaunchKernelGGL(k_expsum, dim3((NE + 255) / 256), dim3(256), 0, stream,
                       attn_raw, dstp, attn_max, attn_exp, attn_sum);
    hipLaunchKernelGGL(k_scatter, dim3(NE / 8), dim3(128), 0, stream,
                       msg, attn_exp, attn_sum, dstp, aggr);
    hipLaunchKernelGGL(k_node, dim3(NN / 8), dim3(128), 0, stream,
                       nf, aggr, g1, b1, fw1, fb1, fw2, fb2, g2, b2, out);
}

// Round 2
// 1284.041 us; speedup vs baseline: 2.1579x; 2.1579x over previous
//
#include <hip/hip_runtime.h>
#include <hip/hip_bf16.h>

#define NN 100000
#define NE 600000
#define DD 128

typedef __attribute__((ext_vector_type(8))) short bf16x8;
typedef __attribute__((ext_vector_type(4))) float f32x4;

__device__ __forceinline__ unsigned int bfbits(float x) {
    return (unsigned int)__builtin_bit_cast(unsigned short, __float2bfloat16(x));
}
__device__ __forceinline__ unsigned int pk2(float a, float b) {
    return bfbits(a) | (bfbits(b) << 16);
}
__device__ __forceinline__ unsigned short bf16s(float x) {
    return __builtin_bit_cast(unsigned short, __float2bfloat16(x));
}

__device__ __forceinline__ void atomic_max_float(float* addr, float val) {
    if (val >= 0.0f) {
        atomicMax((int*)addr, __float_as_int(val));
    } else {
        atomicMin((unsigned int*)addr, __float_as_uint(val));
    }
}

// ---------------- init ----------------
__global__ void k_init(float* __restrict__ aggr, float* __restrict__ attn_sum,
                       unsigned int* __restrict__ attn_max_bits) {
    int i = blockIdx.x * blockDim.x + threadIdx.x;
    int stride = gridDim.x * blockDim.x;
    for (int idx = i; idx < NN * DD; idx += stride) aggr[idx] = 0.0f;
    for (int idx = i; idx < NN; idx += stride) {
        attn_sum[idx] = 0.0f;
        attn_max_bits[idx] = 0xFF800000u; // -inf
    }
}

// ---------------- pack weights into MFMA B-fragment order (bf16) ------------
// layout: packed[((ntile*KS + kstep)*64 + lane)*8 + i]
//   n = ntile*16 + (lane&15), k = kstep*32 + (lane>>4)*8 + i, val = W[k*128 + n]
__global__ void k_pack(const float* __restrict__ mw1, const float* __restrict__ mw2,
                       const float* __restrict__ aw1,
                       unsigned short* __restrict__ mw1p,
                       unsigned short* __restrict__ mw2p,
                       unsigned short* __restrict__ aw1p) {
    int idx = blockIdx.x * 256 + threadIdx.x; // 81920 total
    if (idx < 32768) { // mw1: K=256 (KS=8), N=128
        int i = idx & 7, l = (idx >> 3) & 63, ks = (idx >> 9) & 7, nt = idx >> 12;
        int k = ks * 32 + (l >> 4) * 8 + i, n = nt * 16 + (l & 15);
        mw1p[idx] = bf16s(mw1[k * 128 + n]);
    } else if (idx < 49152) { // mw2: K=128 (KS=4)
        int j = idx - 32768;
        int i = j & 7, l = (j >> 3) & 63, ks = (j >> 9) & 3, nt = j >> 11;
        int k = ks * 32 + (l >> 4) * 8 + i, n = nt * 16 + (l & 15);
        mw2p[j] = bf16s(mw2[k * 128 + n]);
    } else { // aw1: K=256 (KS=8)
        int j = idx - 49152;
        int i = j & 7, l = (j >> 3) & 63, ks = (j >> 9) & 7, nt = j >> 12;
        int k = ks * 32 + (l >> 4) * 8 + i, n = nt * 16 + (l & 15);
        aw1p[j] = bf16s(aw1[k * 128 + n]);
    }
}

// ---------------- edge kernel: MFMA msg MLP + attn MLP + segment max --------
// block = 256 thr (4 waves, 2x2), 64 edges/block.
// LDS A-tile [64 rows][32 chunks of 8 bf16], slot = chunk ^ (row&7)
__global__ __launch_bounds__(256) void k_edge(
    const float* __restrict__ nf, const int* __restrict__ src,
    const int* __restrict__ dst, const int* __restrict__ etype,
    const float* __restrict__ rel,
    const unsigned short* __restrict__ mw1p, const float* __restrict__ mb1,
    const unsigned short* __restrict__ mw2p, const float* __restrict__ mb2,
    const unsigned short* __restrict__ aw1p, const float* __restrict__ ab1,
    const float* __restrict__ aw2, const float* __restrict__ ab2,
    unsigned short* __restrict__ msg_out,
    float* __restrict__ attn_raw, float* __restrict__ attn_max)
{
    __shared__ alignas(16) unsigned short A1[64 * 256]; // 32 KB
    __shared__ alignas(16) unsigned short HID[64 * 128]; // 16 KB
    __shared__ float RED[64][2];

    const int t = threadIdx.x;
    const int w = t >> 6, l = t & 63;
    const int wm = w >> 1, wn = w & 1;
    const int lm = l & 15, lk = l >> 4;
    const int e0 = blockIdx.x * 64;

    // ---- stage A1 = [nf[src] || rel[etype]] bf16, swizzled ----
    #pragma unroll
    for (int it = 0; it < 8; ++it) {
        int q = w * 512 + it * 64 + l;      // slot id: 64 rows x 32 slots
        int row = q >> 5, s = q & 31;
        int c = s ^ (row & 7);              // global chunk held at this slot
        int e = e0 + row;
        const float* rowp = (c < 16) ? (nf + (size_t)src[e] * DD + c * 8)
                                     : (rel + (size_t)etype[e] * DD + (c - 16) * 8);
        float4 f0 = *reinterpret_cast<const float4*>(rowp);
        float4 f1 = *reinterpret_cast<const float4*>(rowp + 4);
        uint4 v;
        v.x = pk2(f0.x, f0.y); v.y = pk2(f0.z, f0.w);
        v.z = pk2(f1.x, f1.y); v.w = pk2(f1.z, f1.w);
        *reinterpret_cast<uint4*>(&A1[row * 256 + s * 8]) = v;
    }
    __syncthreads();

    // ---- GEMM1: hidden = relu(A1 @ mw1 + mb1), out 64x128, K=256 ----
    f32x4 acc[2][4];
    #pragma unroll
    for (int mf = 0; mf < 2; ++mf)
        #pragma unroll
        for (int nfr = 0; nfr < 4; ++nfr) acc[mf][nfr] = (f32x4){0.f, 0.f, 0.f, 0.f};

    #pragma unroll
    for (int ks = 0; ks < 8; ++ks) {
        bf16x8 a[2];
        #pragma unroll
        for (int mf = 0; mf < 2; ++mf) {
            int m = wm * 32 + mf * 16 + lm;
            int slot = (ks * 4 + lk) ^ (m & 7);
            a[mf] = *reinterpret_cast<const bf16x8*>(&A1[m * 256 + slot * 8]);
        }
        #pragma unroll
        for (int nfr = 0; nfr < 4; ++nfr) {
            int nt = wn * 4 + nfr;
            bf16x8 b = *reinterpret_cast<const bf16x8*>(&mw1p[((nt * 8 + ks) * 64 + l) * 8]);
            acc[0][nfr] = __builtin_amdgcn_mfma_f32_16x16x32_bf16(a[0], b, acc[0][nfr], 0, 0, 0);
            acc[1][nfr] = __builtin_amdgcn_mfma_f32_16x16x32_bf16(a[1], b, acc[1][nfr], 0, 0, 0);
        }
    }
    // epilogue: bias + relu -> HID (swizzled, 16 chunks/row)
    #pragma unroll
    for (int nfr = 0; nfr < 4; ++nfr) {
        int n = wn * 64 + nfr * 16 + lm;
        float bv = mb1[n];
        #pragma unroll
        for (int mf = 0; mf < 2; ++mf)
            #pragma unroll
            for (int r = 0; r < 4; ++r) {
                int m = wm * 32 + mf * 16 + lk * 4 + r;
                float v = fmaxf(acc[mf][nfr][r] + bv, 0.0f);
                HID[m * 128 + ((n >> 3) ^ (m & 7)) * 8 + (n & 7)] = bf16s(v);
            }
    }
    __syncthreads(); // A1 reads done everywhere; HID valid

    // ---- stage nf[dst] into A1 chunks 0..15 (overwrites src half) ----
    #pragma unroll
    for (int it = 0; it < 4; ++it) {
        int q = w * 256 + it * 64 + l;      // 64 rows x 16 slots
        int row = q >> 4, s = q & 15;
        int c = s ^ (row & 7);
        const float* rowp = nf + (size_t)dst[e0 + row] * DD + c * 8;
        float4 f0 = *reinterpret_cast<const float4*>(rowp);
        float4 f1 = *reinterpret_cast<const float4*>(rowp + 4);
        uint4 v;
        v.x = pk2(f0.x, f0.y); v.y = pk2(f0.z, f0.w);
        v.z = pk2(f1.x, f1.y); v.w = pk2(f1.z, f1.w);
        *reinterpret_cast<uint4*>(&A1[row * 256 + s * 8]) = v;
    }

    // ---- GEMM2: msg = HID @ mw2 + mb2, K=128 ----
    #pragma unroll
    for (int mf = 0; mf < 2; ++mf)
        #pragma unroll
        for (int nfr = 0; nfr < 4; ++nfr) acc[mf][nfr] = (f32x4){0.f, 0.f, 0.f, 0.f};

    #pragma unroll
    for (int ks = 0; ks < 4; ++ks) {
        bf16x8 a[2];
        #pragma unroll
        for (int mf = 0; mf < 2; ++mf) {
            int m = wm * 32 + mf * 16 + lm;
            int slot = (ks * 4 + lk) ^ (m & 7);
            a[mf] = *reinterpret_cast<const bf16x8*>(&HID[m * 128 + slot * 8]);
        }
        #pragma unroll
        for (int nfr = 0; nfr < 4; ++nfr) {
            int nt = wn * 4 + nfr;
            bf16x8 b = *reinterpret_cast<const bf16x8*>(&mw2p[((nt * 4 + ks) * 64 + l) * 8]);
            acc[0][nfr] = __builtin_amdgcn_mfma_f32_16x16x32_bf16(a[0], b, acc[0][nfr], 0, 0, 0);
            acc[1][nfr] = __builtin_amdgcn_mfma_f32_16x16x32_bf16(a[1], b, acc[1][nfr], 0, 0, 0);
        }
    }
    // epilogue: bias -> msg bf16 into A1 chunks 16..31 (overwrites rel half)
    #pragma unroll
    for (int nfr = 0; nfr < 4; ++nfr) {
        int n = wn * 64 + nfr * 16 + lm;
        float bv = mb2[n];
        #pragma unroll
        for (int mf = 0; mf < 2; ++mf)
            #pragma unroll
            for (int r = 0; r < 4; ++r) {
                int m = wm * 32 + mf * 16 + lk * 4 + r;
                float v = acc[mf][nfr][r] + bv;
                A1[m * 256 + (16 + ((n >> 3) ^ (m & 7))) * 8 + (n & 7)] = bf16s(v);
            }
    }
    __syncthreads(); // dst staged + msg written

    // ---- copy msg half -> global (coalesced), overlaps GEMM3 issue ----
    #pragma unroll
    for (int j = 0; j < 4; ++j) {
        int q = j * 256 + t;                // 64 rows x 16 chunks
        int row = q >> 4, c16 = q & 15;
        int slot = 16 + (c16 ^ (row & 7));
        uint4 v = *reinterpret_cast<const uint4*>(&A1[row * 256 + slot * 8]);
        *reinterpret_cast<uint4*>(&msg_out[(size_t)(e0 + row) * DD + c16 * 8]) = v;
    }

    // ---- GEMM3: z = leaky(A1 @ aw1 + ab1), then logits = z . aw2 + ab2 ----
    #pragma unroll
    for (int mf = 0; mf < 2; ++mf)
        #pragma unroll
        for (int nfr = 0; nfr < 4; ++nfr) acc[mf][nfr] = (f32x4){0.f, 0.f, 0.f, 0.f};

    #pragma unroll
    for (int ks = 0; ks < 8; ++ks) {
        bf16x8 a[2];
        #pragma unroll
        for (int mf = 0; mf < 2; ++mf) {
            int m = wm * 32 + mf * 16 + lm;
            int slot = (ks * 4 + lk) ^ (m & 7);
            a[mf] = *reinterpret_cast<const bf16x8*>(&A1[m * 256 + slot * 8]);
        }
        #pragma unroll
        for (int nfr = 0; nfr < 4; ++nfr) {
            int nt = wn * 4 + nfr;
            bf16x8 b = *reinterpret_cast<const bf16x8*>(&aw1p[((nt * 8 + ks) * 64 + l) * 8]);
            acc[0][nfr] = __builtin_amdgcn_mfma_f32_16x16x32_bf16(a[0], b, acc[0][nfr], 0, 0, 0);
            acc[1][nfr] = __builtin_amdgcn_mfma_f32_16x16x32_bf16(a[1], b, acc[1][nfr], 0, 0, 0);
        }
    }
    // epilogue: leaky + dot(aw2), row-reduce
    float ab1v[4], aw2v[4];
    #pragma unroll
    for (int nfr = 0; nfr < 4; ++nfr) {
        int n = wn * 64 + nfr * 16 + lm;
        ab1v[nfr] = ab1[n]; aw2v[nfr] = aw2[n];
    }
    #pragma unroll
    for (int mf = 0; mf < 2; ++mf)
        #pragma unroll
        for (int r = 0; r < 4; ++r) {
            float s = 0.0f;
            #pragma unroll
            for (int nfr = 0; nfr < 4; ++nfr) {
                float v = acc[mf][nfr][r] + ab1v[nfr];
                v = (v > 0.0f) ? v : 0.2f * v;
                s = fmaf(v, aw2v[nfr], s);
            }
            s += __shfl_xor(s, 1, 64);
            s += __shfl_xor(s, 2, 64);
            s += __shfl_xor(s, 4, 64);
            s += __shfl_xor(s, 8, 64);
            if (lm == 0) RED[wm * 32 + mf * 16 + lk * 4 + r][wn] = s;
        }
    __syncthreads();

    if (t < 64) {
        float raw = RED[t][0] + RED[t][1] + ab2[0];
        int e = e0 + t;
        attn_raw[e] = raw;
        atomic_max_float(&attn_max[dst[e]], raw);
    }
}

// ---------------- segment softmax: exp-sum ----------------
__global__ void k_expsum(const float* __restrict__ attn_raw, const int* __restrict__ dst,
                         const float* __restrict__ attn_max, float* __restrict__ attn_sum)
{
    int e = blockIdx.x * 256 + threadIdx.x;
    if (e < NE) {
        int d = dst[e];
        atomicAdd(&attn_sum[d], expf(attn_raw[e] - attn_max[d]));
    }
}

// ---------------- scatter: aggr += attn_w * messages ----------------
__global__ __launch_bounds__(128) void k_scatter(
    const unsigned short* __restrict__ msg, const float* __restrict__ attn_raw,
    const float* __restrict__ attn_max, const float* __restrict__ attn_sum,
    const int* __restrict__ dst, float* __restrict__ aggr)
{
    const int t = threadIdx.x;
    const int e0 = blockIdx.x * 8;
    #pragma unroll
    for (int e = 0; e < 8; ++e) {
        int eg = e0 + e;
        int d = dst[eg];
        float w = expf(attn_raw[eg] - attn_max[d]) / (attn_sum[d] + 1e-8f);
        unsigned short mb = msg[(size_t)eg * DD + t];
        unsigned int bits = ((unsigned int)mb) << 16;
        float m = __builtin_bit_cast(float, bits);
        atomicAdd(&aggr[(size_t)d * DD + t], w * m);
    }
}

// ---------------- node kernel: LN1 + FFN + LN2 ----------------
__global__ __launch_bounds__(128) void k_node(
    const float* __restrict__ nf, const float* __restrict__ aggr,
    const float* __restrict__ g1, const float* __restrict__ b1,
    const float* __restrict__ fw1, const float* __restrict__ fb1,
    const float* __restrict__ fw2, const float* __restrict__ fb2,
    const float* __restrict__ g2, const float* __restrict__ b2,
    float* __restrict__ out)
{
    __shared__ float xbuf[8][128];
    __shared__ float hid[8][512];
    __shared__ float rsum[8][2], rsq[8][2];
    const int t = threadIdx.x;
    const long n0 = (long)blockIdx.x * 8;

    float xr[8];
    #pragma unroll
    for (int nn = 0; nn < 8; ++nn) {
        long idx = (n0 + nn) * DD + t;
        xr[nn] = nf[idx] + aggr[idx];
    }
    #pragma unroll
    for (int nn = 0; nn < 8; ++nn) {
        float s = xr[nn], q = xr[nn] * xr[nn];
        #pragma unroll
        for (int off = 32; off >= 1; off >>= 1) {
            s += __shfl_down(s, off, 64);
            q += __shfl_down(q, off, 64);
        }
        if ((t & 63) == 0) { rsum[nn][t >> 6] = s; rsq[nn][t >> 6] = q; }
    }
    __syncthreads();
    {
        float g1v = g1[t], b1v = b1[t];
        #pragma unroll
        for (int nn = 0; nn < 8; ++nn) {
            float mu  = (rsum[nn][0] + rsum[nn][1]) * (1.0f / DD);
            float var = (rsq[nn][0] + rsq[nn][1]) * (1.0f / DD) - mu * mu;
            float x = (xr[nn] - mu) * rsqrtf(var + 1e-5f) * g1v + b1v;
            xr[nn] = x;
            xbuf[nn][t] = x;
        }
    }
    __syncthreads();

    float fbv[4];
    #pragma unroll
    for (int u = 0; u < 4; ++u) fbv[u] = fb1[t + 128 * u];
    float acc[8][4];
    #pragma unroll
    for (int nn = 0; nn < 8; ++nn)
        #pragma unroll
        for (int u = 0; u < 4; ++u) acc[nn][u] = fbv[u];

    for (int kc = 0; kc < 32; ++kc) {
        float4 xv[8];
        #pragma unroll
        for (int nn = 0; nn < 8; ++nn)
            xv[nn] = *reinterpret_cast<const float4*>(&xbuf[nn][kc * 4]);
        #pragma unroll
        for (int i = 0; i < 4; ++i) {
            int k = kc * 4 + i;
            float w0 = fw1[k * 512 + t];
            float w1 = fw1[k * 512 + t + 128];
            float w2 = fw1[k * 512 + t + 256];
            float w3 = fw1[k * 512 + t + 384];
            #pragma unroll
            for (int nn = 0; nn < 8; ++nn) {
                float xk = (i == 0) ? xv[nn].x : (i == 1) ? xv[nn].y
                         : (i == 2) ? xv[nn].z : xv[nn].w;
                acc[nn][0] = fmaf(xk, w0, acc[nn][0]);
                acc[nn][1] = fmaf(xk, w1, acc[nn][1]);
                acc[nn][2] = fmaf(xk, w2, acc[nn][2]);
                acc[nn][3] = fmaf(xk, w3, acc[nn][3]);
            }
        }
    }
    #pragma unroll
    for (int nn = 0; nn < 8; ++nn)
        #pragma unroll
        for (int u = 0; u < 4; ++u) {
            float h = acc[nn][u];
            hid[nn][t + 128 * u] = 0.5f * h * (1.0f + erff(h * 0.70710678118654752f));
        }
    __syncthreads();

    float acc2[8];
    {
        float b = fb2[t];
        #pragma unroll
        for (int nn = 0; nn < 8; ++nn) acc2[nn] = b;
    }
    for (int kc = 0; kc < 128; ++kc) {
        float w0 = fw2[(kc * 4 + 0) * DD + t];
        float w1 = fw2[(kc * 4 + 1) * DD + t];
        float w2 = fw2[(kc * 4 + 2) * DD + t];
        float w3 = fw2[(kc * 4 + 3) * DD + t];
        #pragma unroll
        for (int nn = 0; nn < 8; ++nn) {
            float4 h = *reinterpret_cast<const float4*>(&hid[nn][kc * 4]);
            acc2[nn] = fmaf(h.x, w0, acc2[nn]);
            acc2[nn] = fmaf(h.y, w1, acc2[nn]);
            acc2[nn] = fmaf(h.z, w2, acc2[nn]);
            acc2[nn] = fmaf(h.w, w3, acc2[nn]);
        }
    }

    #pragma unroll
    for (int nn = 0; nn < 8; ++nn) xr[nn] += acc2[nn];
    __syncthreads();
    #pragma unroll
    for (int nn = 0; nn < 8; ++nn) {
        float s = xr[nn], q = xr[nn] * xr[nn];
        #pragma unroll
        for (int off = 32; off >= 1; off >>= 1) {
            s += __shfl_down(s, off, 64);
            q += __shfl_down(q, off, 64);
        }
        if ((t & 63) == 0) { rsum[nn][t >> 6] = s; rsq[nn][t >> 6] = q; }
    }
    __syncthreads();
    {
        float g2v = g2[t], b2v = b2[t];
        #pragma unroll
        for (int nn = 0; nn < 8; ++nn) {
            float mu  = (rsum[nn][0] + rsum[nn][1]) * (1.0f / DD);
            float var = (rsq[nn][0] + rsq[nn][1]) * (1.0f / DD) - mu * mu;
            out[(n0 + nn) * DD + t] = (xr[nn] - mu) * rsqrtf(var + 1e-5f) * g2v + b2v;
        }
    }
}

extern "C" void kernel_launch(void* const* d_in, const int* in_sizes, int n_in,
                              void* d_out, int out_size, void* d_ws, size_t ws_size,
                              hipStream_t stream)
{
    const float* nf  = (const float*)d_in[0];
    const int*   ei  = (const int*)d_in[1];
    const int*   et  = (const int*)d_in[2];
    const float* rel = (const float*)d_in[3];
    const float* mw1 = (const float*)d_in[4];
    const float* mb1 = (const float*)d_in[5];
    const float* mw2 = (const float*)d_in[6];
    const float* mb2 = (const float*)d_in[7];
    const float* aw1 = (const float*)d_in[8];
    const float* ab1 = (const float*)d_in[9];
    const float* aw2 = (const float*)d_in[10];
    const float* ab2 = (const float*)d_in[11];
    const float* g1  = (const float*)d_in[12];
    const float* b1  = (const float*)d_in[13];
    const float* fw1 = (const float*)d_in[14];
    const float* fb1 = (const float*)d_in[15];
    const float* fw2 = (const float*)d_in[16];
    const float* fb2 = (const float*)d_in[17];
    const float* g2  = (const float*)d_in[18];
    const float* b2  = (const float*)d_in[19];
    float* out = (float*)d_out;

    char* ws = (char*)d_ws;
    size_t off = 0;
    auto alloc = [&](size_t bytes) -> char* {
        char* p = ws + off;
        off += (bytes + 255) & ~(size_t)255;
        return p;
    };
    unsigned short* msg = (unsigned short*)alloc((size_t)NE * DD * 2);
    float* attn_raw = (float*)alloc((size_t)NE * 4);
    float* attn_max = (float*)alloc((size_t)NN * 4);
    float* attn_sum = (float*)alloc((size_t)NN * 4);
    float* aggr     = (float*)alloc((size_t)NN * DD * 4);
    unsigned short* mw1p = (unsigned short*)alloc(32768 * 2);
    unsigned short* mw2p = (unsigned short*)alloc(16384 * 2);
    unsigned short* aw1p = (unsigned short*)alloc(32768 * 2);

    const int* srcp = ei;
    const int* dstp = ei + NE;

    hipLaunchKernelGGL(k_init, dim3(2048), dim3(256), 0, stream,
                       aggr, attn_sum, (unsigned int*)attn_max);
    hipLaunchKernelGGL(k_pack, dim3(320), dim3(256), 0, stream,
                       mw1, mw2, aw1, mw1p, mw2p, aw1p);
    hipLaunchKernelGGL(k_edge, dim3(NE / 64), dim3(256), 0, stream,
                       nf, srcp, dstp, et, rel,
                       mw1p, mb1, mw2p, mb2, aw1p, ab1, aw2, ab2,
                       msg, attn_raw, attn_max);
    hipLaunchKernelGGL(k_expsum, dim3((NE + 255) / 256), dim3(256), 0, stream,
                       attn_raw, dstp, attn_max, attn_sum);
    hipLaunchKernelGGL(k_scatter, dim3(NE / 8), dim3(128), 0, stream,
                       msg, attn_raw, attn_max, attn_sum, dstp, aggr);
    hipLaunchKernelGGL(k_node, dim3(NN / 8), dim3(128), 0, stream,
                       nf, aggr, g1, b1, fw1, fb1, fw2, fb2, g2, b2, out);
}

// Round 3
// 878.235 us; speedup vs baseline: 3.1550x; 1.4621x over previous
//
#include <hip/hip_runtime.h>
#include <hip/hip_bf16.h>

#define NN 100000
#define NE 600000
#define DD 128

typedef __attribute__((ext_vector_type(8))) short bf16x8;
typedef __attribute__((ext_vector_type(4))) float f32x4;

__device__ __forceinline__ unsigned int bfbits(float x) {
    return (unsigned int)__builtin_bit_cast(unsigned short, __float2bfloat16(x));
}
__device__ __forceinline__ unsigned int pk2(float a, float b) {
    return bfbits(a) | (bfbits(b) << 16);
}
__device__ __forceinline__ unsigned short bf16s(float x) {
    return __builtin_bit_cast(unsigned short, __float2bfloat16(x));
}
__device__ __forceinline__ float unlo(unsigned int u) {
    return __builtin_bit_cast(float, u << 16);
}
__device__ __forceinline__ float unhi(unsigned int u) {
    return __builtin_bit_cast(float, u & 0xffff0000u);
}

__device__ __forceinline__ void atomic_max_float(float* addr, float val) {
    if (val >= 0.0f) {
        atomicMax((int*)addr, __float_as_int(val));
    } else {
        atomicMin((unsigned int*)addr, __float_as_uint(val));
    }
}

// ---------------- init ----------------
__global__ void k_init(float* __restrict__ aggr, float* __restrict__ attn_sum,
                       unsigned int* __restrict__ attn_max_bits) {
    int i = blockIdx.x * blockDim.x + threadIdx.x;
    int stride = gridDim.x * blockDim.x;
    for (int idx = i; idx < NN * DD; idx += stride) aggr[idx] = 0.0f;
    for (int idx = i; idx < NN; idx += stride) {
        attn_sum[idx] = 0.0f;
        attn_max_bits[idx] = 0xFF800000u; // -inf
    }
}

// ---------------- pack weights into MFMA B-fragment order (bf16) ------------
// packed[((ntile*KS + kstep)*64 + lane)*8 + i]:
//   n = ntile*16 + (lane&15), k = kstep*32 + (lane>>4)*8 + i, val = W[k*N + n]
__global__ void k_pack(const float* __restrict__ mw1, const float* __restrict__ mw2,
                       const float* __restrict__ aw1,
                       const float* __restrict__ fw1, const float* __restrict__ fw2,
                       unsigned short* __restrict__ mw1p,
                       unsigned short* __restrict__ mw2p,
                       unsigned short* __restrict__ aw1p,
                       unsigned short* __restrict__ fw1p,
                       unsigned short* __restrict__ fw2p) {
    int idx = blockIdx.x * 256 + threadIdx.x; // 212992 total
    if (idx < 32768) { // mw1: K=256 (KS=8), N=128
        int i = idx & 7, l = (idx >> 3) & 63, ks = (idx >> 9) & 7, nt = idx >> 12;
        int k = ks * 32 + (l >> 4) * 8 + i, n = nt * 16 + (l & 15);
        mw1p[idx] = bf16s(mw1[k * 128 + n]);
    } else if (idx < 49152) { // mw2: K=128 (KS=4), N=128
        int j = idx - 32768;
        int i = j & 7, l = (j >> 3) & 63, ks = (j >> 9) & 3, nt = j >> 11;
        int k = ks * 32 + (l >> 4) * 8 + i, n = nt * 16 + (l & 15);
        mw2p[j] = bf16s(mw2[k * 128 + n]);
    } else if (idx < 81920) { // aw1: K=256 (KS=8), N=128
        int j = idx - 49152;
        int i = j & 7, l = (j >> 3) & 63, ks = (j >> 9) & 7, nt = j >> 12;
        int k = ks * 32 + (l >> 4) * 8 + i, n = nt * 16 + (l & 15);
        aw1p[j] = bf16s(aw1[k * 128 + n]);
    } else if (idx < 147456) { // fw1: K=128 (KS=4), N=512
        int j = idx - 81920;
        int i = j & 7, l = (j >> 3) & 63, ks = (j >> 9) & 3, nt = j >> 11; // nt 0..31
        int k = ks * 32 + (l >> 4) * 8 + i, n = nt * 16 + (l & 15);
        fw1p[j] = bf16s(fw1[k * 512 + n]);
    } else if (idx < 212992) { // fw2: K=512 (KS=16), N=128
        int j = idx - 147456;
        int i = j & 7, l = (j >> 3) & 63, ks = (j >> 9) & 15, nt = j >> 13; // nt 0..7
        int k = ks * 32 + (l >> 4) * 8 + i, n = nt * 16 + (l & 15);
        fw2p[j] = bf16s(fw2[k * 128 + n]);
    }
}

// ---------------- edge kernel: MFMA msg MLP + attn MLP + segment max --------
__global__ __launch_bounds__(256) void k_edge(
    const float* __restrict__ nf, const int* __restrict__ src,
    const int* __restrict__ dst, const int* __restrict__ etype,
    const float* __restrict__ rel,
    const unsigned short* __restrict__ mw1p, const float* __restrict__ mb1,
    const unsigned short* __restrict__ mw2p, const float* __restrict__ mb2,
    const unsigned short* __restrict__ aw1p, const float* __restrict__ ab1,
    const float* __restrict__ aw2, const float* __restrict__ ab2,
    unsigned short* __restrict__ msg_out,
    float* __restrict__ attn_raw, float* __restrict__ attn_max)
{
    __shared__ alignas(16) unsigned short A1[64 * 256]; // 32 KB
    __shared__ alignas(16) unsigned short HID[64 * 128]; // 16 KB
    __shared__ float RED[64][2];

    const int t = threadIdx.x;
    const int w = t >> 6, l = t & 63;
    const int wm = w >> 1, wn = w & 1;
    const int lm = l & 15, lk = l >> 4;
    const int e0 = blockIdx.x * 64;

    #pragma unroll
    for (int it = 0; it < 8; ++it) {
        int q = w * 512 + it * 64 + l;
        int row = q >> 5, s = q & 31;
        int c = s ^ (row & 7);
        int e = e0 + row;
        const float* rowp = (c < 16) ? (nf + (size_t)src[e] * DD + c * 8)
                                     : (rel + (size_t)etype[e] * DD + (c - 16) * 8);
        float4 f0 = *reinterpret_cast<const float4*>(rowp);
        float4 f1 = *reinterpret_cast<const float4*>(rowp + 4);
        uint4 v;
        v.x = pk2(f0.x, f0.y); v.y = pk2(f0.z, f0.w);
        v.z = pk2(f1.x, f1.y); v.w = pk2(f1.z, f1.w);
        *reinterpret_cast<uint4*>(&A1[row * 256 + s * 8]) = v;
    }
    __syncthreads();

    f32x4 acc[2][4];
    #pragma unroll
    for (int mf = 0; mf < 2; ++mf)
        #pragma unroll
        for (int nfr = 0; nfr < 4; ++nfr) acc[mf][nfr] = (f32x4){0.f, 0.f, 0.f, 0.f};

    #pragma unroll
    for (int ks = 0; ks < 8; ++ks) {
        bf16x8 a[2];
        #pragma unroll
        for (int mf = 0; mf < 2; ++mf) {
            int m = wm * 32 + mf * 16 + lm;
            int slot = (ks * 4 + lk) ^ (m & 7);
            a[mf] = *reinterpret_cast<const bf16x8*>(&A1[m * 256 + slot * 8]);
        }
        #pragma unroll
        for (int nfr = 0; nfr < 4; ++nfr) {
            int nt = wn * 4 + nfr;
            bf16x8 b = *reinterpret_cast<const bf16x8*>(&mw1p[((nt * 8 + ks) * 64 + l) * 8]);
            acc[0][nfr] = __builtin_amdgcn_mfma_f32_16x16x32_bf16(a[0], b, acc[0][nfr], 0, 0, 0);
            acc[1][nfr] = __builtin_amdgcn_mfma_f32_16x16x32_bf16(a[1], b, acc[1][nfr], 0, 0, 0);
        }
    }
    #pragma unroll
    for (int nfr = 0; nfr < 4; ++nfr) {
        int n = wn * 64 + nfr * 16 + lm;
        float bv = mb1[n];
        #pragma unroll
        for (int mf = 0; mf < 2; ++mf)
            #pragma unroll
            for (int r = 0; r < 4; ++r) {
                int m = wm * 32 + mf * 16 + lk * 4 + r;
                float v = fmaxf(acc[mf][nfr][r] + bv, 0.0f);
                HID[m * 128 + ((n >> 3) ^ (m & 7)) * 8 + (n & 7)] = bf16s(v);
            }
    }
    __syncthreads();

    #pragma unroll
    for (int it = 0; it < 4; ++it) {
        int q = w * 256 + it * 64 + l;
        int row = q >> 4, s = q & 15;
        int c = s ^ (row & 7);
        const float* rowp = nf + (size_t)dst[e0 + row] * DD + c * 8;
        float4 f0 = *reinterpret_cast<const float4*>(rowp);
        float4 f1 = *reinterpret_cast<const float4*>(rowp + 4);
        uint4 v;
        v.x = pk2(f0.x, f0.y); v.y = pk2(f0.z, f0.w);
        v.z = pk2(f1.x, f1.y); v.w = pk2(f1.z, f1.w);
        *reinterpret_cast<uint4*>(&A1[row * 256 + s * 8]) = v;
    }

    #pragma unroll
    for (int mf = 0; mf < 2; ++mf)
        #pragma unroll
        for (int nfr = 0; nfr < 4; ++nfr) acc[mf][nfr] = (f32x4){0.f, 0.f, 0.f, 0.f};

    #pragma unroll
    for (int ks = 0; ks < 4; ++ks) {
        bf16x8 a[2];
        #pragma unroll
        for (int mf = 0; mf < 2; ++mf) {
            int m = wm * 32 + mf * 16 + lm;
            int slot = (ks * 4 + lk) ^ (m & 7);
            a[mf] = *reinterpret_cast<const bf16x8*>(&HID[m * 128 + slot * 8]);
        }
        #pragma unroll
        for (int nfr = 0; nfr < 4; ++nfr) {
            int nt = wn * 4 + nfr;
            bf16x8 b = *reinterpret_cast<const bf16x8*>(&mw2p[((nt * 4 + ks) * 64 + l) * 8]);
            acc[0][nfr] = __builtin_amdgcn_mfma_f32_16x16x32_bf16(a[0], b, acc[0][nfr], 0, 0, 0);
            acc[1][nfr] = __builtin_amdgcn_mfma_f32_16x16x32_bf16(a[1], b, acc[1][nfr], 0, 0, 0);
        }
    }
    #pragma unroll
    for (int nfr = 0; nfr < 4; ++nfr) {
        int n = wn * 64 + nfr * 16 + lm;
        float bv = mb2[n];
        #pragma unroll
        for (int mf = 0; mf < 2; ++mf)
            #pragma unroll
            for (int r = 0; r < 4; ++r) {
                int m = wm * 32 + mf * 16 + lk * 4 + r;
                float v = acc[mf][nfr][r] + bv;
                A1[m * 256 + (16 + ((n >> 3) ^ (m & 7))) * 8 + (n & 7)] = bf16s(v);
            }
    }
    __syncthreads();

    #pragma unroll
    for (int j = 0; j < 4; ++j) {
        int q = j * 256 + t;
        int row = q >> 4, c16 = q & 15;
        int slot = 16 + (c16 ^ (row & 7));
        uint4 v = *reinterpret_cast<const uint4*>(&A1[row * 256 + slot * 8]);
        *reinterpret_cast<uint4*>(&msg_out[(size_t)(e0 + row) * DD + c16 * 8]) = v;
    }

    #pragma unroll
    for (int mf = 0; mf < 2; ++mf)
        #pragma unroll
        for (int nfr = 0; nfr < 4; ++nfr) acc[mf][nfr] = (f32x4){0.f, 0.f, 0.f, 0.f};

    #pragma unroll
    for (int ks = 0; ks < 8; ++ks) {
        bf16x8 a[2];
        #pragma unroll
        for (int mf = 0; mf < 2; ++mf) {
            int m = wm * 32 + mf * 16 + lm;
            int slot = (ks * 4 + lk) ^ (m & 7);
            a[mf] = *reinterpret_cast<const bf16x8*>(&A1[m * 256 + slot * 8]);
        }
        #pragma unroll
        for (int nfr = 0; nfr < 4; ++nfr) {
            int nt = wn * 4 + nfr;
            bf16x8 b = *reinterpret_cast<const bf16x8*>(&aw1p[((nt * 8 + ks) * 64 + l) * 8]);
            acc[0][nfr] = __builtin_amdgcn_mfma_f32_16x16x32_bf16(a[0], b, acc[0][nfr], 0, 0, 0);
            acc[1][nfr] = __builtin_amdgcn_mfma_f32_16x16x32_bf16(a[1], b, acc[1][nfr], 0, 0, 0);
        }
    }
    float ab1v[4], aw2v[4];
    #pragma unroll
    for (int nfr = 0; nfr < 4; ++nfr) {
        int n = wn * 64 + nfr * 16 + lm;
        ab1v[nfr] = ab1[n]; aw2v[nfr] = aw2[n];
    }
    #pragma unroll
    for (int mf = 0; mf < 2; ++mf)
        #pragma unroll
        for (int r = 0; r < 4; ++r) {
            float s = 0.0f;
            #pragma unroll
            for (int nfr = 0; nfr < 4; ++nfr) {
                float v = acc[mf][nfr][r] + ab1v[nfr];
                v = (v > 0.0f) ? v : 0.2f * v;
                s = fmaf(v, aw2v[nfr], s);
            }
            s += __shfl_xor(s, 1, 64);
            s += __shfl_xor(s, 2, 64);
            s += __shfl_xor(s, 4, 64);
            s += __shfl_xor(s, 8, 64);
            if (lm == 0) RED[wm * 32 + mf * 16 + lk * 4 + r][wn] = s;
        }
    __syncthreads();

    if (t < 64) {
        float raw = RED[t][0] + RED[t][1] + ab2[0];
        int e = e0 + t;
        attn_raw[e] = raw;
        atomic_max_float(&attn_max[dst[e]], raw);
    }
}

// ---------------- segment softmax: exp-sum ----------------
__global__ void k_expsum(const float* __restrict__ attn_raw, const int* __restrict__ dst,
                         const float* __restrict__ attn_max, float* __restrict__ attn_sum)
{
    int e = blockIdx.x * 256 + threadIdx.x;
    if (e < NE) {
        int d = dst[e];
        atomicAdd(&attn_sum[d], expf(attn_raw[e] - attn_max[d]));
    }
}

// ---------------- scatter: aggr += attn_w * messages ----------------
__global__ __launch_bounds__(128) void k_scatter(
    const unsigned short* __restrict__ msg, const float* __restrict__ attn_raw,
    const float* __restrict__ attn_max, const float* __restrict__ attn_sum,
    const int* __restrict__ dst, float* __restrict__ aggr)
{
    const int t = threadIdx.x;
    const int e0 = blockIdx.x * 8;
    #pragma unroll
    for (int e = 0; e < 8; ++e) {
        int eg = e0 + e;
        int d = dst[eg];
        float w = expf(attn_raw[eg] - attn_max[d]) / (attn_sum[d] + 1e-8f);
        unsigned short mb = msg[(size_t)eg * DD + t];
        unsigned int bits = ((unsigned int)mb) << 16;
        float m = __builtin_bit_cast(float, bits);
        atomicAdd(&aggr[(size_t)d * DD + t], w * m);
    }
}

// ---------------- node kernel: LN1 + MFMA FFN + LN2 ----------------
// block = 256 thr (4 waves, 2x2), 64 nodes/block.
// XB: [64 rows][16 chunks of 8 bf16], slot = chunk ^ (row&7)  (16 KB)
// HB: [64 rows][32 chunks of 8 bf16], slot = chunk ^ (row&7)  (32 KB)
__global__ __launch_bounds__(256) void k_node(
    const float* __restrict__ nf, const float* __restrict__ aggr,
    const float* __restrict__ g1, const float* __restrict__ b1,
    const unsigned short* __restrict__ fw1p, const float* __restrict__ fb1,
    const unsigned short* __restrict__ fw2p, const float* __restrict__ fb2,
    const float* __restrict__ g2, const float* __restrict__ b2,
    float* __restrict__ out)
{
    __shared__ alignas(16) unsigned short XB[64 * 128]; // 16 KB
    __shared__ alignas(16) unsigned short HB[64 * 256]; // 32 KB

    const int t = threadIdx.x;
    const int w = t >> 6, l = t & 63;
    const int wm = w >> 1, wn = w & 1;
    const int lm = l & 15, lk = l >> 4;
    const int row = t >> 2;  // 0..63
    const int q = t & 3;     // 32-col quarter
    const long n0 = (long)blockIdx.x * 64;
    const long rg = n0 + row;
    const long rc = (rg < NN) ? rg : (NN - 1);

    // ---- LN1: x = nf + aggr, quad-reduce, normalize -> xr (fp32) + XB (bf16)
    float xr[32];
    float s = 0.0f, ss = 0.0f;
    {
        const float* xp = nf + rc * DD + q * 32;
        const float* ap = aggr + rc * DD + q * 32;
        #pragma unroll
        for (int i = 0; i < 8; ++i) {
            float4 a = *reinterpret_cast<const float4*>(xp + i * 4);
            float4 b = *reinterpret_cast<const float4*>(ap + i * 4);
            float v0 = a.x + b.x, v1 = a.y + b.y, v2 = a.z + b.z, v3 = a.w + b.w;
            xr[i * 4 + 0] = v0; xr[i * 4 + 1] = v1; xr[i * 4 + 2] = v2; xr[i * 4 + 3] = v3;
            s += v0 + v1 + v2 + v3;
            ss = fmaf(v0, v0, ss); ss = fmaf(v1, v1, ss);
            ss = fmaf(v2, v2, ss); ss = fmaf(v3, v3, ss);
        }
    }
    s  += __shfl_xor(s, 1, 64);  s  += __shfl_xor(s, 2, 64);
    ss += __shfl_xor(ss, 1, 64); ss += __shfl_xor(ss, 2, 64);
    {
        float mu = s * (1.0f / DD);
        float var = ss * (1.0f / DD) - mu * mu;
        float rstd = rsqrtf(var + 1e-5f);
        #pragma unroll
        for (int i = 0; i < 8; ++i) {
            float4 gv = *reinterpret_cast<const float4*>(g1 + q * 32 + i * 4);
            float4 bv = *reinterpret_cast<const float4*>(b1 + q * 32 + i * 4);
            xr[i * 4 + 0] = (xr[i * 4 + 0] - mu) * rstd * gv.x + bv.x;
            xr[i * 4 + 1] = (xr[i * 4 + 1] - mu) * rstd * gv.y + bv.y;
            xr[i * 4 + 2] = (xr[i * 4 + 2] - mu) * rstd * gv.z + bv.z;
            xr[i * 4 + 3] = (xr[i * 4 + 3] - mu) * rstd * gv.w + bv.w;
        }
        #pragma unroll
        for (int i = 0; i < 4; ++i) {
            int c = q * 4 + i, slot = c ^ (row & 7);
            uint4 v;
            v.x = pk2(xr[i * 8 + 0], xr[i * 8 + 1]);
            v.y = pk2(xr[i * 8 + 2], xr[i * 8 + 3]);
            v.z = pk2(xr[i * 8 + 4], xr[i * 8 + 5]);
            v.w = pk2(xr[i * 8 + 6], xr[i * 8 + 7]);
            *reinterpret_cast<uint4*>(&XB[row * 128 + slot * 8]) = v;
        }
    }
    __syncthreads();

    // ---- FFN via MFMA, hidden processed in two 256-col halves ----
    f32x4 acc2[2][4];
    #pragma unroll
    for (int mf = 0; mf < 2; ++mf)
        #pragma unroll
        for (int nfr = 0; nfr < 4; ++nfr) acc2[mf][nfr] = (f32x4){0.f, 0.f, 0.f, 0.f};

    #pragma unroll
    for (int half = 0; half < 2; ++half) {
        // GEMM1: [64,128] @ fw1[:, half*256 : half*256+256]
        f32x4 acc[2][8];
        #pragma unroll
        for (int mf = 0; mf < 2; ++mf)
            #pragma unroll
            for (int nfr = 0; nfr < 8; ++nfr) acc[mf][nfr] = (f32x4){0.f, 0.f, 0.f, 0.f};

        #pragma unroll
        for (int ks = 0; ks < 4; ++ks) {
            bf16x8 a[2];
            #pragma unroll
            for (int mf = 0; mf < 2; ++mf) {
                int m = wm * 32 + mf * 16 + lm;
                int slot = (ks * 4 + lk) ^ (m & 7);
                a[mf] = *reinterpret_cast<const bf16x8*>(&XB[m * 128 + slot * 8]);
            }
            #pragma unroll
            for (int nfr = 0; nfr < 8; ++nfr) {
                int nt = half * 16 + wn * 8 + nfr;
                bf16x8 b = *reinterpret_cast<const bf16x8*>(&fw1p[((nt * 4 + ks) * 64 + l) * 8]);
                acc[0][nfr] = __builtin_amdgcn_mfma_f32_16x16x32_bf16(a[0], b, acc[0][nfr], 0, 0, 0);
                acc[1][nfr] = __builtin_amdgcn_mfma_f32_16x16x32_bf16(a[1], b, acc[1][nfr], 0, 0, 0);
            }
        }
        // epilogue: bias + gelu(sigmoid form) -> HB bf16
        #pragma unroll
        for (int nfr = 0; nfr < 8; ++nfr) {
            int nl = wn * 128 + nfr * 16 + lm;         // col within half
            float bv = fb1[half * 256 + nl];
            #pragma unroll
            for (int mf = 0; mf < 2; ++mf)
                #pragma unroll
                for (int r = 0; r < 4; ++r) {
                    int m = wm * 32 + mf * 16 + lk * 4 + r;
                    float h = acc[mf][nfr][r] + bv;
                    float e = __expf(h * -1.702f);
                    float gvv = h * __builtin_amdgcn_rcpf(1.0f + e);
                    HB[m * 256 + (((nl >> 3) ^ (m & 7)) * 8) + (nl & 7)] = bf16s(gvv);
                }
        }
        __syncthreads(); // HB ready

        // GEMM2 partial: K-range half*256 .. +256
        #pragma unroll
        for (int ks = 0; ks < 8; ++ks) {
            bf16x8 a[2];
            #pragma unroll
            for (int mf = 0; mf < 2; ++mf) {
                int m = wm * 32 + mf * 16 + lm;
                int slot = (ks * 4 + lk) ^ (m & 7);
                a[mf] = *reinterpret_cast<const bf16x8*>(&HB[m * 256 + slot * 8]);
            }
            #pragma unroll
            for (int nfr = 0; nfr < 4; ++nfr) {
                int nt = wn * 4 + nfr;
                int kg = half * 8 + ks;
                bf16x8 b = *reinterpret_cast<const bf16x8*>(&fw2p[((nt * 16 + kg) * 64 + l) * 8]);
                acc2[0][nfr] = __builtin_amdgcn_mfma_f32_16x16x32_bf16(a[0], b, acc2[0][nfr], 0, 0, 0);
                acc2[1][nfr] = __builtin_amdgcn_mfma_f32_16x16x32_bf16(a[1], b, acc2[1][nfr], 0, 0, 0);
            }
        }
        __syncthreads(); // HB consumed before next half overwrites
    }

    // ---- GEMM2 epilogue: ffn -> XB (bf16) ----
    #pragma unroll
    for (int nfr = 0; nfr < 4; ++nfr) {
        int n = wn * 64 + nfr * 16 + lm;
        float bv = fb2[n];
        #pragma unroll
        for (int mf = 0; mf < 2; ++mf)
            #pragma unroll
            for (int r = 0; r < 4; ++r) {
                int m = wm * 32 + mf * 16 + lk * 4 + r;
                XB[m * 128 + (((n >> 3) ^ (m & 7)) * 8) + (n & 7)] = bf16s(acc2[mf][nfr][r] + bv);
            }
    }
    __syncthreads();

    // ---- residual + LN2 ----
    float s2 = 0.0f, ss2 = 0.0f;
    #pragma unroll
    for (int i = 0; i < 4; ++i) {
        int c = q * 4 + i, slot = c ^ (row & 7);
        uint4 v = *reinterpret_cast<const uint4*>(&XB[row * 128 + slot * 8]);
        float f[8];
        f[0] = unlo(v.x); f[1] = unhi(v.x); f[2] = unlo(v.y); f[3] = unhi(v.y);
        f[4] = unlo(v.z); f[5] = unhi(v.z); f[6] = unlo(v.w); f[7] = unhi(v.w);
        #pragma unroll
        for (int j = 0; j < 8; ++j) {
            float vv = xr[i * 8 + j] + f[j];
            xr[i * 8 + j] = vv;
            s2 += vv;
            ss2 = fmaf(vv, vv, ss2);
        }
    }
    s2  += __shfl_xor(s2, 1, 64);  s2  += __shfl_xor(s2, 2, 64);
    ss2 += __shfl_xor(ss2, 1, 64); ss2 += __shfl_xor(ss2, 2, 64);
    {
        float mu = s2 * (1.0f / DD);
        float var = ss2 * (1.0f / DD) - mu * mu;
        float rstd = rsqrtf(var + 1e-5f);
        if (rg < NN) {
            float* op = out + rg * DD + q * 32;
            #pragma unroll
            for (int i = 0; i < 8; ++i) {
                float4 gv = *reinterpret_cast<const float4*>(g2 + q * 32 + i * 4);
                float4 bv = *reinterpret_cast<const float4*>(b2 + q * 32 + i * 4);
                float4 o;
                o.x = (xr[i * 4 + 0] - mu) * rstd * gv.x + bv.x;
                o.y = (xr[i * 4 + 1] - mu) * rstd * gv.y + bv.y;
                o.z = (xr[i * 4 + 2] - mu) * rstd * gv.z + bv.z;
                o.w = (xr[i * 4 + 3] - mu) * rstd * gv.w + bv.w;
                *reinterpret_cast<float4*>(op + i * 4) = o;
            }
        }
    }
}

extern "C" void kernel_launch(void* const* d_in, const int* in_sizes, int n_in,
                              void* d_out, int out_size, void* d_ws, size_t ws_size,
                              hipStream_t stream)
{
    const float* nf  = (const float*)d_in[0];
    const int*   ei  = (const int*)d_in[1];
    const int*   et  = (const int*)d_in[2];
    const float* rel = (const float*)d_in[3];
    const float* mw1 = (const float*)d_in[4];
    const float* mb1 = (const float*)d_in[5];
    const float* mw2 = (const float*)d_in[6];
    const float* mb2 = (const float*)d_in[7];
    const float* aw1 = (const float*)d_in[8];
    const float* ab1 = (const float*)d_in[9];
    const float* aw2 = (const float*)d_in[10];
    const float* ab2 = (const float*)d_in[11];
    const float* g1  = (const float*)d_in[12];
    const float* b1  = (const float*)d_in[13];
    const float* fw1 = (const float*)d_in[14];
    const float* fb1 = (const float*)d_in[15];
    const float* fw2 = (const float*)d_in[16];
    const float* fb2 = (const float*)d_in[17];
    const float* g2  = (const float*)d_in[18];
    const float* b2  = (const float*)d_in[19];
    float* out = (float*)d_out;

    char* ws = (char*)d_ws;
    size_t off = 0;
    auto alloc = [&](size_t bytes) -> char* {
        char* p = ws + off;
        off += (bytes + 255) & ~(size_t)255;
        return p;
    };
    unsigned short* msg = (unsigned short*)alloc((size_t)NE * DD * 2);
    float* attn_raw = (float*)alloc((size_t)NE * 4);
    float* attn_max = (float*)alloc((size_t)NN * 4);
    float* attn_sum = (float*)alloc((size_t)NN * 4);
    float* aggr     = (float*)alloc((size_t)NN * DD * 4);
    unsigned short* mw1p = (unsigned short*)alloc(32768 * 2);
    unsigned short* mw2p = (unsigned short*)alloc(16384 * 2);
    unsigned short* aw1p = (unsigned short*)alloc(32768 * 2);
    unsigned short* fw1p = (unsigned short*)alloc(65536 * 2);
    unsigned short* fw2p = (unsigned short*)alloc(65536 * 2);

    const int* srcp = ei;
    const int* dstp = ei + NE;

    hipLaunchKernelGGL(k_init, dim3(2048), dim3(256), 0, stream,
                       aggr, attn_sum, (unsigned int*)attn_max);
    hipLaunchKernelGGL(k_pack, dim3(832), dim3(256), 0, stream,
                       mw1, mw2, aw1, fw1, fw2, mw1p, mw2p, aw1p, fw1p, fw2p);
    hipLaunchKernelGGL(k_edge, dim3(NE / 64), dim3(256), 0, stream,
                       nf, srcp, dstp, et, rel,
                       mw1p, mb1, mw2p, mb2, aw1p, ab1, aw2, ab2,
                       msg, attn_raw, attn_max);
    hipLaunchKernelGGL(k_expsum, dim3((NE + 255) / 256), dim3(256), 0, stream,
                       attn_raw, dstp, attn_max, attn_sum);
    hipLaunchKernelGGL(k_scatter, dim3(NE / 8), dim3(128), 0, stream,
                       msg, attn_raw, attn_max, attn_sum, dstp, aggr);
    hipLaunchKernelGGL(k_node, dim3((NN + 63) / 64), dim3(256), 0, stream,
                       nf, aggr, g1, b1, fw1p, fb1, fw2p, fb2, g2, b2, out);
}

// Round 4
// 682.008 us; speedup vs baseline: 4.0628x; 1.2877x over previous
//
#include <hip/hip_runtime.h>
#include <hip/hip_bf16.h>

#define NN 100000
#define NE 600000
#define DD 128
#define RR 200

typedef __attribute__((ext_vector_type(8))) short bf16x8;
typedef __attribute__((ext_vector_type(4))) float f32x4;

__device__ __forceinline__ unsigned int bfbits(float x) {
    return (unsigned int)__builtin_bit_cast(unsigned short, __float2bfloat16(x));
}
__device__ __forceinline__ unsigned int pk2(float a, float b) {
    return bfbits(a) | (bfbits(b) << 16);
}
__device__ __forceinline__ unsigned short bf16s(float x) {
    return __builtin_bit_cast(unsigned short, __float2bfloat16(x));
}
__device__ __forceinline__ float unlo(unsigned int u) {
    return __builtin_bit_cast(float, u << 16);
}
__device__ __forceinline__ float unhi(unsigned int u) {
    return __builtin_bit_cast(float, u & 0xffff0000u);
}

__device__ __forceinline__ void atomic_max_float(float* addr, float val) {
    if (val >= 0.0f) {
        atomicMax((int*)addr, __float_as_int(val));
    } else {
        atomicMin((unsigned int*)addr, __float_as_uint(val));
    }
}

// ---------------- init ----------------
__global__ void k_init(float* __restrict__ aggr, float* __restrict__ attn_sum,
                       unsigned int* __restrict__ attn_max_bits) {
    int i = blockIdx.x * blockDim.x + threadIdx.x;
    int stride = gridDim.x * blockDim.x;
    for (int idx = i; idx < NN * DD; idx += stride) aggr[idx] = 0.0f;
    for (int idx = i; idx < NN; idx += stride) {
        attn_sum[idx] = 0.0f;
        attn_max_bits[idx] = 0xFF800000u; // -inf
    }
}

// ---------------- prep: bf16 copies of node features and rel embeddings -----
__global__ void k_prep(const float* __restrict__ nf, const float* __restrict__ rel,
                       unsigned short* __restrict__ nfb, unsigned short* __restrict__ relb) {
    int i = blockIdx.x * 256 + threadIdx.x;           // each handles 8 elems
    const int total = (NN + RR) * DD / 8;             // 1603200
    if (i >= total) return;
    size_t base = (size_t)i * 8;
    const float* sp;
    unsigned short* dp;
    if (base < (size_t)NN * DD) { sp = nf + base; dp = nfb + base; }
    else { sp = rel + (base - (size_t)NN * DD); dp = relb + (base - (size_t)NN * DD); }
    float4 f0 = *reinterpret_cast<const float4*>(sp);
    float4 f1 = *reinterpret_cast<const float4*>(sp + 4);
    uint4 v;
    v.x = pk2(f0.x, f0.y); v.y = pk2(f0.z, f0.w);
    v.z = pk2(f1.x, f1.y); v.w = pk2(f1.z, f1.w);
    *reinterpret_cast<uint4*>(dp) = v;
}

// ---------------- pack weights into MFMA B-fragment order (bf16) ------------
__global__ void k_pack(const float* __restrict__ mw1, const float* __restrict__ mw2,
                       const float* __restrict__ aw1,
                       const float* __restrict__ fw1, const float* __restrict__ fw2,
                       unsigned short* __restrict__ mw1p,
                       unsigned short* __restrict__ mw2p,
                       unsigned short* __restrict__ aw1p,
                       unsigned short* __restrict__ fw1p,
                       unsigned short* __restrict__ fw2p) {
    int idx = blockIdx.x * 256 + threadIdx.x; // 212992 total
    if (idx < 32768) { // mw1: K=256 (KS=8), N=128
        int i = idx & 7, l = (idx >> 3) & 63, ks = (idx >> 9) & 7, nt = idx >> 12;
        int k = ks * 32 + (l >> 4) * 8 + i, n = nt * 16 + (l & 15);
        mw1p[idx] = bf16s(mw1[k * 128 + n]);
    } else if (idx < 49152) { // mw2: K=128 (KS=4), N=128
        int j = idx - 32768;
        int i = j & 7, l = (j >> 3) & 63, ks = (j >> 9) & 3, nt = j >> 11;
        int k = ks * 32 + (l >> 4) * 8 + i, n = nt * 16 + (l & 15);
        mw2p[j] = bf16s(mw2[k * 128 + n]);
    } else if (idx < 81920) { // aw1: K=256 (KS=8), N=128
        int j = idx - 49152;
        int i = j & 7, l = (j >> 3) & 63, ks = (j >> 9) & 7, nt = j >> 12;
        int k = ks * 32 + (l >> 4) * 8 + i, n = nt * 16 + (l & 15);
        aw1p[j] = bf16s(aw1[k * 128 + n]);
    } else if (idx < 147456) { // fw1: K=128 (KS=4), N=512
        int j = idx - 81920;
        int i = j & 7, l = (j >> 3) & 63, ks = (j >> 9) & 3, nt = j >> 11;
        int k = ks * 32 + (l >> 4) * 8 + i, n = nt * 16 + (l & 15);
        fw1p[j] = bf16s(fw1[k * 512 + n]);
    } else if (idx < 212992) { // fw2: K=512 (KS=16), N=128
        int j = idx - 147456;
        int i = j & 7, l = (j >> 3) & 63, ks = (j >> 9) & 15, nt = j >> 13;
        int k = ks * 32 + (l >> 4) * 8 + i, n = nt * 16 + (l & 15);
        fw2p[j] = bf16s(fw2[k * 128 + n]);
    }
}

// ---------------- edge kernel: MFMA msg MLP + attn MLP + segment max --------
// block = 512 thr (8 waves, 2x4), 64 edges/block.
// A1: [64 rows][32 chunks of 8 bf16], slot = chunk ^ (row&7)
__global__ __launch_bounds__(512) void k_edge(
    const unsigned short* __restrict__ nfb, const int* __restrict__ src,
    const int* __restrict__ dst, const int* __restrict__ etype,
    const unsigned short* __restrict__ relb,
    const unsigned short* __restrict__ mw1p, const float* __restrict__ mb1,
    const unsigned short* __restrict__ mw2p, const float* __restrict__ mb2,
    const unsigned short* __restrict__ aw1p, const float* __restrict__ ab1,
    const float* __restrict__ aw2, const float* __restrict__ ab2,
    unsigned short* __restrict__ msg_out,
    float* __restrict__ attn_raw, float* __restrict__ attn_max)
{
    __shared__ alignas(16) unsigned short A1[64 * 256]; // 32 KB
    __shared__ alignas(16) unsigned short HID[64 * 128]; // 16 KB
    __shared__ float RED[64][4];                         // 1 KB

    const int t = threadIdx.x;
    const int w = t >> 6, l = t & 63;
    const int wm = w >> 2, wn = w & 3;
    const int lm = l & 15, lk = l >> 4;
    const int e0 = blockIdx.x * 64;

    // ---- stage A1 = [nfb[src] || relb[etype]] (bf16 rows, direct copy) ----
    #pragma unroll
    for (int it = 0; it < 4; ++it) {
        int q = w * 256 + it * 64 + l;      // 0..2047: 64 rows x 32 slots
        int row = q >> 5, s = q & 31;
        int c = s ^ (row & 7);
        int e = e0 + row;
        const unsigned short* rowp = (c < 16)
            ? (nfb + (size_t)src[e] * DD + c * 8)
            : (relb + (size_t)etype[e] * DD + (c - 16) * 8);
        *reinterpret_cast<uint4*>(&A1[row * 256 + s * 8]) =
            *reinterpret_cast<const uint4*>(rowp);
    }
    __syncthreads();

    // ---- GEMM1: hidden = relu(A1 @ mw1 + mb1), K=256 ----
    f32x4 acc[2][2];
    #pragma unroll
    for (int mf = 0; mf < 2; ++mf)
        #pragma unroll
        for (int nfr = 0; nfr < 2; ++nfr) acc[mf][nfr] = (f32x4){0.f, 0.f, 0.f, 0.f};

    #pragma unroll
    for (int ks = 0; ks < 8; ++ks) {
        bf16x8 a[2];
        #pragma unroll
        for (int mf = 0; mf < 2; ++mf) {
            int m = wm * 32 + mf * 16 + lm;
            int slot = (ks * 4 + lk) ^ (m & 7);
            a[mf] = *reinterpret_cast<const bf16x8*>(&A1[m * 256 + slot * 8]);
        }
        #pragma unroll
        for (int nfr = 0; nfr < 2; ++nfr) {
            int nt = wn * 2 + nfr;
            bf16x8 b = *reinterpret_cast<const bf16x8*>(&mw1p[((nt * 8 + ks) * 64 + l) * 8]);
            acc[0][nfr] = __builtin_amdgcn_mfma_f32_16x16x32_bf16(a[0], b, acc[0][nfr], 0, 0, 0);
            acc[1][nfr] = __builtin_amdgcn_mfma_f32_16x16x32_bf16(a[1], b, acc[1][nfr], 0, 0, 0);
        }
    }
    #pragma unroll
    for (int nfr = 0; nfr < 2; ++nfr) {
        int n = (wn * 2 + nfr) * 16 + lm;
        float bv = mb1[n];
        #pragma unroll
        for (int mf = 0; mf < 2; ++mf)
            #pragma unroll
            for (int r = 0; r < 4; ++r) {
                int m = wm * 32 + mf * 16 + lk * 4 + r;
                float v = fmaxf(acc[mf][nfr][r] + bv, 0.0f);
                HID[m * 128 + ((n >> 3) ^ (m & 7)) * 8 + (n & 7)] = bf16s(v);
            }
    }
    __syncthreads(); // A1 reads done everywhere; HID valid

    // ---- stage nfb[dst] into A1 chunks 0..15 (overlaps GEMM2) ----
    #pragma unroll
    for (int it = 0; it < 2; ++it) {
        int q = w * 128 + it * 64 + l;      // 0..1023: 64 rows x 16 slots
        int row = q >> 4, s = q & 15;
        int c = s ^ (row & 7);
        *reinterpret_cast<uint4*>(&A1[row * 256 + s * 8]) =
            *reinterpret_cast<const uint4*>(nfb + (size_t)dst[e0 + row] * DD + c * 8);
    }

    // ---- GEMM2: msg = HID @ mw2 + mb2, K=128 ----
    #pragma unroll
    for (int mf = 0; mf < 2; ++mf)
        #pragma unroll
        for (int nfr = 0; nfr < 2; ++nfr) acc[mf][nfr] = (f32x4){0.f, 0.f, 0.f, 0.f};

    #pragma unroll
    for (int ks = 0; ks < 4; ++ks) {
        bf16x8 a[2];
        #pragma unroll
        for (int mf = 0; mf < 2; ++mf) {
            int m = wm * 32 + mf * 16 + lm;
            int slot = (ks * 4 + lk) ^ (m & 7);
            a[mf] = *reinterpret_cast<const bf16x8*>(&HID[m * 128 + slot * 8]);
        }
        #pragma unroll
        for (int nfr = 0; nfr < 2; ++nfr) {
            int nt = wn * 2 + nfr;
            bf16x8 b = *reinterpret_cast<const bf16x8*>(&mw2p[((nt * 4 + ks) * 64 + l) * 8]);
            acc[0][nfr] = __builtin_amdgcn_mfma_f32_16x16x32_bf16(a[0], b, acc[0][nfr], 0, 0, 0);
            acc[1][nfr] = __builtin_amdgcn_mfma_f32_16x16x32_bf16(a[1], b, acc[1][nfr], 0, 0, 0);
        }
    }
    // epilogue: bias -> msg bf16 into A1 chunks 16..31
    #pragma unroll
    for (int nfr = 0; nfr < 2; ++nfr) {
        int n = (wn * 2 + nfr) * 16 + lm;
        float bv = mb2[n];
        #pragma unroll
        for (int mf = 0; mf < 2; ++mf)
            #pragma unroll
            for (int r = 0; r < 4; ++r) {
                int m = wm * 32 + mf * 16 + lk * 4 + r;
                float v = acc[mf][nfr][r] + bv;
                A1[m * 256 + (16 + ((n >> 3) ^ (m & 7))) * 8 + (n & 7)] = bf16s(v);
            }
    }
    __syncthreads(); // dst staged + msg written

    // ---- copy msg half -> global (coalesced) ----
    #pragma unroll
    for (int j = 0; j < 2; ++j) {
        int q = j * 512 + t;                // 64 rows x 16 chunks
        int row = q >> 4, c16 = q & 15;
        int slot = 16 + (c16 ^ (row & 7));
        uint4 v = *reinterpret_cast<const uint4*>(&A1[row * 256 + slot * 8]);
        *reinterpret_cast<uint4*>(&msg_out[(size_t)(e0 + row) * DD + c16 * 8]) = v;
    }

    // ---- GEMM3: z = leaky(A1 @ aw1 + ab1), logits = z . aw2 + ab2 ----
    #pragma unroll
    for (int mf = 0; mf < 2; ++mf)
        #pragma unroll
        for (int nfr = 0; nfr < 2; ++nfr) acc[mf][nfr] = (f32x4){0.f, 0.f, 0.f, 0.f};

    #pragma unroll
    for (int ks = 0; ks < 8; ++ks) {
        bf16x8 a[2];
        #pragma unroll
        for (int mf = 0; mf < 2; ++mf) {
            int m = wm * 32 + mf * 16 + lm;
            int slot = (ks * 4 + lk) ^ (m & 7);
            a[mf] = *reinterpret_cast<const bf16x8*>(&A1[m * 256 + slot * 8]);
        }
        #pragma unroll
        for (int nfr = 0; nfr < 2; ++nfr) {
            int nt = wn * 2 + nfr;
            bf16x8 b = *reinterpret_cast<const bf16x8*>(&aw1p[((nt * 8 + ks) * 64 + l) * 8]);
            acc[0][nfr] = __builtin_amdgcn_mfma_f32_16x16x32_bf16(a[0], b, acc[0][nfr], 0, 0, 0);
            acc[1][nfr] = __builtin_amdgcn_mfma_f32_16x16x32_bf16(a[1], b, acc[1][nfr], 0, 0, 0);
        }
    }
    float ab1v[2], aw2v[2];
    #pragma unroll
    for (int nfr = 0; nfr < 2; ++nfr) {
        int n = (wn * 2 + nfr) * 16 + lm;
        ab1v[nfr] = ab1[n]; aw2v[nfr] = aw2[n];
    }
    #pragma unroll
    for (int mf = 0; mf < 2; ++mf)
        #pragma unroll
        for (int r = 0; r < 4; ++r) {
            float s = 0.0f;
            #pragma unroll
            for (int nfr = 0; nfr < 2; ++nfr) {
                float v = acc[mf][nfr][r] + ab1v[nfr];
                v = (v > 0.0f) ? v : 0.2f * v;
                s = fmaf(v, aw2v[nfr], s);
            }
            s += __shfl_xor(s, 1, 64);
            s += __shfl_xor(s, 2, 64);
            s += __shfl_xor(s, 4, 64);
            s += __shfl_xor(s, 8, 64);
            if (lm == 0) RED[wm * 32 + mf * 16 + lk * 4 + r][wn] = s;
        }
    __syncthreads();

    if (t < 64) {
        float raw = RED[t][0] + RED[t][1] + RED[t][2] + RED[t][3] + ab2[0];
        int e = e0 + t;
        attn_raw[e] = raw;
        atomic_max_float(&attn_max[dst[e]], raw);
    }
}

// ---------------- segment softmax: exp-sum ----------------
__global__ void k_expsum(const float* __restrict__ attn_raw, const int* __restrict__ dst,
                         const float* __restrict__ attn_max, float* __restrict__ attn_sum)
{
    int e = blockIdx.x * 256 + threadIdx.x;
    if (e < NE) {
        int d = dst[e];
        atomicAdd(&attn_sum[d], expf(attn_raw[e] - attn_max[d]));
    }
}

// ---------------- scatter: aggr += attn_w * messages ----------------
__global__ __launch_bounds__(128) void k_scatter(
    const unsigned short* __restrict__ msg, const float* __restrict__ attn_raw,
    const float* __restrict__ attn_max, const float* __restrict__ attn_sum,
    const int* __restrict__ dst, float* __restrict__ aggr)
{
    const int t = threadIdx.x;
    const int e0 = blockIdx.x * 8;
    #pragma unroll
    for (int e = 0; e < 8; ++e) {
        int eg = e0 + e;
        int d = dst[eg];
        float w = expf(attn_raw[eg] - attn_max[d]) / (attn_sum[d] + 1e-8f);
        unsigned short mb = msg[(size_t)eg * DD + t];
        unsigned int bits = ((unsigned int)mb) << 16;
        float m = __builtin_bit_cast(float, bits);
        atomicAdd(&aggr[(size_t)d * DD + t], w * m);
    }
}

// ---------------- node kernel: LN1 + MFMA FFN + LN2 ----------------
__global__ __launch_bounds__(256) void k_node(
    const float* __restrict__ nf, const float* __restrict__ aggr,
    const float* __restrict__ g1, const float* __restrict__ b1,
    const unsigned short* __restrict__ fw1p, const float* __restrict__ fb1,
    const unsigned short* __restrict__ fw2p, const float* __restrict__ fb2,
    const float* __restrict__ g2, const float* __restrict__ b2,
    float* __restrict__ out)
{
    __shared__ alignas(16) unsigned short XB[64 * 128]; // 16 KB
    __shared__ alignas(16) unsigned short HB[64 * 256]; // 32 KB

    const int t = threadIdx.x;
    const int w = t >> 6, l = t & 63;
    const int wm = w >> 1, wn = w & 1;
    const int lm = l & 15, lk = l >> 4;
    const int row = t >> 2;
    const int q = t & 3;
    const long n0 = (long)blockIdx.x * 64;
    const long rg = n0 + row;
    const long rc = (rg < NN) ? rg : (NN - 1);

    float xr[32];
    float s = 0.0f, ss = 0.0f;
    {
        const float* xp = nf + rc * DD + q * 32;
        const float* ap = aggr + rc * DD + q * 32;
        #pragma unroll
        for (int i = 0; i < 8; ++i) {
            float4 a = *reinterpret_cast<const float4*>(xp + i * 4);
            float4 b = *reinterpret_cast<const float4*>(ap + i * 4);
            float v0 = a.x + b.x, v1 = a.y + b.y, v2 = a.z + b.z, v3 = a.w + b.w;
            xr[i * 4 + 0] = v0; xr[i * 4 + 1] = v1; xr[i * 4 + 2] = v2; xr[i * 4 + 3] = v3;
            s += v0 + v1 + v2 + v3;
            ss = fmaf(v0, v0, ss); ss = fmaf(v1, v1, ss);
            ss = fmaf(v2, v2, ss); ss = fmaf(v3, v3, ss);
        }
    }
    s  += __shfl_xor(s, 1, 64);  s  += __shfl_xor(s, 2, 64);
    ss += __shfl_xor(ss, 1, 64); ss += __shfl_xor(ss, 2, 64);
    {
        float mu = s * (1.0f / DD);
        float var = ss * (1.0f / DD) - mu * mu;
        float rstd = rsqrtf(var + 1e-5f);
        #pragma unroll
        for (int i = 0; i < 8; ++i) {
            float4 gv = *reinterpret_cast<const float4*>(g1 + q * 32 + i * 4);
            float4 bv = *reinterpret_cast<const float4*>(b1 + q * 32 + i * 4);
            xr[i * 4 + 0] = (xr[i * 4 + 0] - mu) * rstd * gv.x + bv.x;
            xr[i * 4 + 1] = (xr[i * 4 + 1] - mu) * rstd * gv.y + bv.y;
            xr[i * 4 + 2] = (xr[i * 4 + 2] - mu) * rstd * gv.z + bv.z;
            xr[i * 4 + 3] = (xr[i * 4 + 3] - mu) * rstd * gv.w + bv.w;
        }
        #pragma unroll
        for (int i = 0; i < 4; ++i) {
            int c = q * 4 + i, slot = c ^ (row & 7);
            uint4 v;
            v.x = pk2(xr[i * 8 + 0], xr[i * 8 + 1]);
            v.y = pk2(xr[i * 8 + 2], xr[i * 8 + 3]);
            v.z = pk2(xr[i * 8 + 4], xr[i * 8 + 5]);
            v.w = pk2(xr[i * 8 + 6], xr[i * 8 + 7]);
            *reinterpret_cast<uint4*>(&XB[row * 128 + slot * 8]) = v;
        }
    }
    __syncthreads();

    f32x4 acc2[2][4];
    #pragma unroll
    for (int mf = 0; mf < 2; ++mf)
        #pragma unroll
        for (int nfr = 0; nfr < 4; ++nfr) acc2[mf][nfr] = (f32x4){0.f, 0.f, 0.f, 0.f};

    #pragma unroll
    for (int half = 0; half < 2; ++half) {
        f32x4 acc[2][8];
        #pragma unroll
        for (int mf = 0; mf < 2; ++mf)
            #pragma unroll
            for (int nfr = 0; nfr < 8; ++nfr) acc[mf][nfr] = (f32x4){0.f, 0.f, 0.f, 0.f};

        #pragma unroll
        for (int ks = 0; ks < 4; ++ks) {
            bf16x8 a[2];
            #pragma unroll
            for (int mf = 0; mf < 2; ++mf) {
                int m = wm * 32 + mf * 16 + lm;
                int slot = (ks * 4 + lk) ^ (m & 7);
                a[mf] = *reinterpret_cast<const bf16x8*>(&XB[m * 128 + slot * 8]);
            }
            #pragma unroll
            for (int nfr = 0; nfr < 8; ++nfr) {
                int nt = half * 16 + wn * 8 + nfr;
                bf16x8 b = *reinterpret_cast<const bf16x8*>(&fw1p[((nt * 4 + ks) * 64 + l) * 8]);
                acc[0][nfr] = __builtin_amdgcn_mfma_f32_16x16x32_bf16(a[0], b, acc[0][nfr], 0, 0, 0);
                acc[1][nfr] = __builtin_amdgcn_mfma_f32_16x16x32_bf16(a[1], b, acc[1][nfr], 0, 0, 0);
            }
        }
        #pragma unroll
        for (int nfr = 0; nfr < 8; ++nfr) {
            int nl = wn * 128 + nfr * 16 + lm;
            float bv = fb1[half * 256 + nl];
            #pragma unroll
            for (int mf = 0; mf < 2; ++mf)
                #pragma unroll
                for (int r = 0; r < 4; ++r) {
                    int m = wm * 32 + mf * 16 + lk * 4 + r;
                    float h = acc[mf][nfr][r] + bv;
                    float e = __expf(h * -1.702f);
                    float gvv = h * __builtin_amdgcn_rcpf(1.0f + e);
                    HB[m * 256 + (((nl >> 3) ^ (m & 7)) * 8) + (nl & 7)] = bf16s(gvv);
                }
        }
        __syncthreads();

        #pragma unroll
        for (int ks = 0; ks < 8; ++ks) {
            bf16x8 a[2];
            #pragma unroll
            for (int mf = 0; mf < 2; ++mf) {
                int m = wm * 32 + mf * 16 + lm;
                int slot = (ks * 4 + lk) ^ (m & 7);
                a[mf] = *reinterpret_cast<const bf16x8*>(&HB[m * 256 + slot * 8]);
            }
            #pragma unroll
            for (int nfr = 0; nfr < 4; ++nfr) {
                int nt = wn * 4 + nfr;
                int kg = half * 8 + ks;
                bf16x8 b = *reinterpret_cast<const bf16x8*>(&fw2p[((nt * 16 + kg) * 64 + l) * 8]);
                acc2[0][nfr] = __builtin_amdgcn_mfma_f32_16x16x32_bf16(a[0], b, acc2[0][nfr], 0, 0, 0);
                acc2[1][nfr] = __builtin_amdgcn_mfma_f32_16x16x32_bf16(a[1], b, acc2[1][nfr], 0, 0, 0);
            }
        }
        __syncthreads();
    }

    #pragma unroll
    for (int nfr = 0; nfr < 4; ++nfr) {
        int n = wn * 64 + nfr * 16 + lm;
        float bv = fb2[n];
        #pragma unroll
        for (int mf = 0; mf < 2; ++mf)
            #pragma unroll
            for (int r = 0; r < 4; ++r) {
                int m = wm * 32 + mf * 16 + lk * 4 + r;
                XB[m * 128 + (((n >> 3) ^ (m & 7)) * 8) + (n & 7)] = bf16s(acc2[mf][nfr][r] + bv);
            }
    }
    __syncthreads();

    float s2 = 0.0f, ss2 = 0.0f;
    #pragma unroll
    for (int i = 0; i < 4; ++i) {
        int c = q * 4 + i, slot = c ^ (row & 7);
        uint4 v = *reinterpret_cast<const uint4*>(&XB[row * 128 + slot * 8]);
        float f[8];
        f[0] = unlo(v.x); f[1] = unhi(v.x); f[2] = unlo(v.y); f[3] = unhi(v.y);
        f[4] = unlo(v.z); f[5] = unhi(v.z); f[6] = unlo(v.w); f[7] = unhi(v.w);
        #pragma unroll
        for (int j = 0; j < 8; ++j) {
            float vv = xr[i * 8 + j] + f[j];
            xr[i * 8 + j] = vv;
            s2 += vv;
            ss2 = fmaf(vv, vv, ss2);
        }
    }
    s2  += __shfl_xor(s2, 1, 64);  s2  += __shfl_xor(s2, 2, 64);
    ss2 += __shfl_xor(ss2, 1, 64); ss2 += __shfl_xor(ss2, 2, 64);
    {
        float mu = s2 * (1.0f / DD);
        float var = ss2 * (1.0f / DD) - mu * mu;
        float rstd = rsqrtf(var + 1e-5f);
        if (rg < NN) {
            float* op = out + rg * DD + q * 32;
            #pragma unroll
            for (int i = 0; i < 8; ++i) {
                float4 gv = *reinterpret_cast<const float4*>(g2 + q * 32 + i * 4);
                float4 bv = *reinterpret_cast<const float4*>(b2 + q * 32 + i * 4);
                float4 o;
                o.x = (xr[i * 4 + 0] - mu) * rstd * gv.x + bv.x;
                o.y = (xr[i * 4 + 1] - mu) * rstd * gv.y + bv.y;
                o.z = (xr[i * 4 + 2] - mu) * rstd * gv.z + bv.z;
                o.w = (xr[i * 4 + 3] - mu) * rstd * gv.w + bv.w;
                *reinterpret_cast<float4*>(op + i * 4) = o;
            }
        }
    }
}

extern "C" void kernel_launch(void* const* d_in, const int* in_sizes, int n_in,
                              void* d_out, int out_size, void* d_ws, size_t ws_size,
                              hipStream_t stream)
{
    const float* nf  = (const float*)d_in[0];
    const int*   ei  = (const int*)d_in[1];
    const int*   et  = (const int*)d_in[2];
    const float* rel = (const float*)d_in[3];
    const float* mw1 = (const float*)d_in[4];
    const float* mb1 = (const float*)d_in[5];
    const float* mw2 = (const float*)d_in[6];
    const float* mb2 = (const float*)d_in[7];
    const float* aw1 = (const float*)d_in[8];
    const float* ab1 = (const float*)d_in[9];
    const float* aw2 = (const float*)d_in[10];
    const float* ab2 = (const float*)d_in[11];
    const float* g1  = (const float*)d_in[12];
    const float* b1  = (const float*)d_in[13];
    const float* fw1 = (const float*)d_in[14];
    const float* fb1 = (const float*)d_in[15];
    const float* fw2 = (const float*)d_in[16];
    const float* fb2 = (const float*)d_in[17];
    const float* g2  = (const float*)d_in[18];
    const float* b2  = (const float*)d_in[19];
    float* out = (float*)d_out;

    char* ws = (char*)d_ws;
    size_t off = 0;
    auto alloc = [&](size_t bytes) -> char* {
        char* p = ws + off;
        off += (bytes + 255) & ~(size_t)255;
        return p;
    };
    unsigned short* msg = (unsigned short*)alloc((size_t)NE * DD * 2);
    float* attn_raw = (float*)alloc((size_t)NE * 4);
    float* attn_max = (float*)alloc((size_t)NN * 4);
    float* attn_sum = (float*)alloc((size_t)NN * 4);
    float* aggr     = (float*)alloc((size_t)NN * DD * 4);
    unsigned short* nfb  = (unsigned short*)alloc((size_t)NN * DD * 2);
    unsigned short* relb = (unsigned short*)alloc((size_t)RR * DD * 2);
    unsigned short* mw1p = (unsigned short*)alloc(32768 * 2);
    unsigned short* mw2p = (unsigned short*)alloc(16384 * 2);
    unsigned short* aw1p = (unsigned short*)alloc(32768 * 2);
    unsigned short* fw1p = (unsigned short*)alloc(65536 * 2);
    unsigned short* fw2p = (unsigned short*)alloc(65536 * 2);

    const int* srcp = ei;
    const int* dstp = ei + NE;

    hipLaunchKernelGGL(k_init, dim3(2048), dim3(256), 0, stream,
                       aggr, attn_sum, (unsigned int*)attn_max);
    hipLaunchKernelGGL(k_prep, dim3(((NN + RR) * DD / 8 + 255) / 256), dim3(256), 0, stream,
                       nf, rel, nfb, relb);
    hipLaunchKernelGGL(k_pack, dim3(832), dim3(256), 0, stream,
                       mw1, mw2, aw1, fw1, fw2, mw1p, mw2p, aw1p, fw1p, fw2p);
    hipLaunchKernelGGL(k_edge, dim3(NE / 64), dim3(512), 0, stream,
                       nfb, srcp, dstp, et, relb,
                       mw1p, mb1, mw2p, mb2, aw1p, ab1, aw2, ab2,
                       msg, attn_raw, attn_max);
    hipLaunchKernelGGL(k_expsum, dim3((NE + 255) / 256), dim3(256), 0, stream,
                       attn_raw, dstp, attn_max, attn_sum);
    hipLaunchKernelGGL(k_scatter, dim3(NE / 8), dim3(128), 0, stream,
                       msg, attn_raw, attn_max, attn_sum, dstp, aggr);
    hipLaunchKernelGGL(k_node, dim3((NN + 63) / 64), dim3(256), 0, stream,
                       nf, aggr, g1, b1, fw1p, fb1, fw2p, fb2, g2, b2, out);
}

// Round 5
// 648.610 us; speedup vs baseline: 4.2720x; 1.0515x over previous
//
#include <hip/hip_runtime.h>
#include <hip/hip_bf16.h>

#define NN 100000
#define NE 600000
#define DD 128
#define RR 200

typedef __attribute__((ext_vector_type(8))) short bf16x8;
typedef __attribute__((ext_vector_type(4))) float f32x4;

__device__ __forceinline__ unsigned int bfbits(float x) {
    return (unsigned int)__builtin_bit_cast(unsigned short, __float2bfloat16(x));
}
__device__ __forceinline__ unsigned int pk2(float a, float b) {
    return bfbits(a) | (bfbits(b) << 16);
}
__device__ __forceinline__ unsigned short bf16s(float x) {
    return __builtin_bit_cast(unsigned short, __float2bfloat16(x));
}
__device__ __forceinline__ float unbf(unsigned short u) {
    return __builtin_bit_cast(float, ((unsigned int)u) << 16);
}
__device__ __forceinline__ float unlo(unsigned int u) {
    return __builtin_bit_cast(float, u << 16);
}
__device__ __forceinline__ float unhi(unsigned int u) {
    return __builtin_bit_cast(float, u & 0xffff0000u);
}

__device__ __forceinline__ void gload_lds16(const void* g, void* l) {
    __builtin_amdgcn_global_load_lds(
        (const __attribute__((address_space(1))) void*)g,
        (__attribute__((address_space(3))) void*)l, 16, 0, 0);
}

__device__ __forceinline__ void atomic_max_float(float* addr, float val) {
    if (val >= 0.0f) {
        atomicMax((int*)addr, __float_as_int(val));
    } else {
        atomicMin((unsigned int*)addr, __float_as_uint(val));
    }
}

// ---------------- init1: attn_sum = 0, attn_max = -inf ----------------
__global__ void k_init1(float* __restrict__ attn_sum,
                        unsigned int* __restrict__ attn_max_bits) {
    int i = blockIdx.x * 256 + threadIdx.x;
    if (i < NN) {
        attn_sum[i] = 0.0f;
        attn_max_bits[i] = 0xFF800000u;
    }
}

// ---------------- zero aggr (runs AFTER k_edge; aggr aliases nfa) -----------
__global__ void k_zero(float4* __restrict__ aggr4) {
    int i = blockIdx.x * 256 + threadIdx.x;
    int stride = gridDim.x * 256;
    for (int idx = i; idx < NN * DD / 4; idx += stride)
        aggr4[idx] = float4{0.f, 0.f, 0.f, 0.f};
}

// ---------------- prep: bf16 copy of node features ----------------
__global__ void k_prep(const float* __restrict__ nf, unsigned short* __restrict__ nfb) {
    int i = blockIdx.x * 256 + threadIdx.x;        // 1.6M threads, 8 elems each
    if (i >= NN * DD / 8) return;
    const float* sp = nf + (size_t)i * 8;
    float4 f0 = *reinterpret_cast<const float4*>(sp);
    float4 f1 = *reinterpret_cast<const float4*>(sp + 4);
    uint4 v;
    v.x = pk2(f0.x, f0.y); v.y = pk2(f0.z, f0.w);
    v.z = pk2(f1.x, f1.y); v.w = pk2(f1.z, f1.w);
    *reinterpret_cast<uint4*>(nfb + (size_t)i * 8) = v;
}

// ---------------- relc = rel @ mw1_bot + mb1 (fp32, 200x128) ----------------
__global__ void k_relc(const float* __restrict__ rel, const float* __restrict__ mw1,
                       const float* __restrict__ mb1, float* __restrict__ relc) {
    int idx = blockIdx.x * 256 + threadIdx.x;      // 25600
    if (idx >= RR * DD) return;
    int r = idx >> 7, n = idx & 127;
    float s = mb1[n];
    for (int k = 0; k < 128; ++k)
        s = fmaf(rel[r * 128 + k], mw1[(128 + k) * 128 + n], s);
    relc[idx] = s;
}

// ---------------- pack weights into MFMA B-fragment order (bf16) ------------
// packed[((ntile*KS + kstep)*64 + lane)*8 + i]:
//   n = ntile*16 + (lane&15), k = kstep*32 + (lane>>4)*8 + i
__global__ void k_pack(const float* __restrict__ mw1, const float* __restrict__ mw2,
                       const float* __restrict__ aw1,
                       const float* __restrict__ fw1, const float* __restrict__ fw2,
                       unsigned short* __restrict__ mw1p,
                       unsigned short* __restrict__ mw2p,
                       unsigned short* __restrict__ awTp,
                       unsigned short* __restrict__ awBp,
                       unsigned short* __restrict__ fw1p,
                       unsigned short* __restrict__ fw2p) {
    int idx = blockIdx.x * 256 + threadIdx.x;      // 196608 total
    if (idx < 16384) {            // mw1 TOP half: K=128 (KS=4), N=128
        int i = idx & 7, l = (idx >> 3) & 63, ks = (idx >> 9) & 3, nt = idx >> 11;
        int k = ks * 32 + (l >> 4) * 8 + i, n = nt * 16 + (l & 15);
        mw1p[idx] = bf16s(mw1[k * 128 + n]);
    } else if (idx < 32768) {     // mw2: K=128
        int j = idx - 16384;
        int i = j & 7, l = (j >> 3) & 63, ks = (j >> 9) & 3, nt = j >> 11;
        int k = ks * 32 + (l >> 4) * 8 + i, n = nt * 16 + (l & 15);
        mw2p[j] = bf16s(mw2[k * 128 + n]);
    } else if (idx < 49152) {     // aw1 TOP half
        int j = idx - 32768;
        int i = j & 7, l = (j >> 3) & 63, ks = (j >> 9) & 3, nt = j >> 11;
        int k = ks * 32 + (l >> 4) * 8 + i, n = nt * 16 + (l & 15);
        awTp[j] = bf16s(aw1[k * 128 + n]);
    } else if (idx < 65536) {     // aw1 BOTTOM half
        int j = idx - 49152;
        int i = j & 7, l = (j >> 3) & 63, ks = (j >> 9) & 3, nt = j >> 11;
        int k = ks * 32 + (l >> 4) * 8 + i, n = nt * 16 + (l & 15);
        awBp[j] = bf16s(aw1[(128 + k) * 128 + n]);
    } else if (idx < 131072) {    // fw1: K=128 (KS=4), N=512
        int j = idx - 65536;
        int i = j & 7, l = (j >> 3) & 63, ks = (j >> 9) & 3, nt = j >> 11;
        int k = ks * 32 + (l >> 4) * 8 + i, n = nt * 16 + (l & 15);
        fw1p[j] = bf16s(fw1[k * 512 + n]);
    } else if (idx < 196608) {    // fw2: K=512 (KS=16), N=128
        int j = idx - 131072;
        int i = j & 7, l = (j >> 3) & 63, ks = (j >> 9) & 15, nt = j >> 13;
        int k = ks * 32 + (l >> 4) * 8 + i, n = nt * 16 + (l & 15);
        fw2p[j] = bf16s(fw2[k * 128 + n]);
    }
}

// ---------------- nfa = nf @ aw1_top + ab1 (bf16, MFMA) ----------------
// block = 256 thr (4 waves 2x2), 64 rows.
__global__ __launch_bounds__(256) void k_nfa(
    const unsigned short* __restrict__ nfb, const unsigned short* __restrict__ awTp,
    const float* __restrict__ ab1, unsigned short* __restrict__ nfa)
{
    __shared__ alignas(16) unsigned short XB[64 * 128]; // 16 KB
    const int t = threadIdx.x;
    const int w = t >> 6, l = t & 63;
    const int wm = w >> 1, wn = w & 1;
    const int lm = l & 15, lk = l >> 4;
    const int lrow = l >> 4, lslot = l & 15;
    const int n0 = blockIdx.x * 64;

    #pragma unroll
    for (int it = 0; it < 4; ++it) {
        int rb = w * 16 + it * 4;
        int row = rb + lrow;
        long grow = n0 + row; if (grow >= NN) grow = NN - 1;
        int c = lslot ^ (row & 7);
        gload_lds16(nfb + grow * DD + c * 8, &XB[rb * 128]);
    }
    __syncthreads();

    f32x4 acc[2][4];
    #pragma unroll
    for (int mf = 0; mf < 2; ++mf)
        #pragma unroll
        for (int nfr = 0; nfr < 4; ++nfr) acc[mf][nfr] = (f32x4){0.f, 0.f, 0.f, 0.f};

    #pragma unroll
    for (int ks = 0; ks < 4; ++ks) {
        bf16x8 a[2];
        #pragma unroll
        for (int mf = 0; mf < 2; ++mf) {
            int m = wm * 32 + mf * 16 + lm;
            int slot = (ks * 4 + lk) ^ (m & 7);
            a[mf] = *reinterpret_cast<const bf16x8*>(&XB[m * 128 + slot * 8]);
        }
        #pragma unroll
        for (int nfr = 0; nfr < 4; ++nfr) {
            int nt = wn * 4 + nfr;
            bf16x8 b = *reinterpret_cast<const bf16x8*>(&awTp[((nt * 4 + ks) * 64 + l) * 8]);
            acc[0][nfr] = __builtin_amdgcn_mfma_f32_16x16x32_bf16(a[0], b, acc[0][nfr], 0, 0, 0);
            acc[1][nfr] = __builtin_amdgcn_mfma_f32_16x16x32_bf16(a[1], b, acc[1][nfr], 0, 0, 0);
        }
    }
    __syncthreads(); // XB reads done; reuse as output staging (linear)

    #pragma unroll
    for (int nfr = 0; nfr < 4; ++nfr) {
        int n = wn * 64 + nfr * 16 + lm;
        float bv = ab1[n];
        #pragma unroll
        for (int mf = 0; mf < 2; ++mf)
            #pragma unroll
            for (int r = 0; r < 4; ++r) {
                int m = wm * 32 + mf * 16 + lk * 4 + r;
                XB[m * 128 + n] = bf16s(acc[mf][nfr][r] + bv);
            }
    }
    __syncthreads();

    #pragma unroll
    for (int j = 0; j < 4; ++j) {
        int q = j * 256 + t;
        int row = q >> 4, c16 = q & 15;
        if (n0 + row < NN)
            *reinterpret_cast<uint4*>(&nfa[(size_t)(n0 + row) * DD + c16 * 8]) =
                *reinterpret_cast<const uint4*>(&XB[row * 128 + c16 * 8]);
    }
}

// ---------------- edge kernel: 3x K=128 MFMA GEMMs + segment max ------------
// block = 512 thr (8 waves, 2m x 4n), 64 edges/block.
// S/H: [64 rows][16 chunks of 8 bf16], chunk c stored at slot c^(row&7)
__global__ __launch_bounds__(512) void k_edge(
    const unsigned short* __restrict__ nfb, const int* __restrict__ src,
    const int* __restrict__ dst, const int* __restrict__ etype,
    const unsigned short* __restrict__ nfa, const float* __restrict__ relc,
    const unsigned short* __restrict__ mw1p,
    const unsigned short* __restrict__ mw2p, const float* __restrict__ mb2,
    const unsigned short* __restrict__ awBp,
    const float* __restrict__ aw2, const float* __restrict__ ab2,
    unsigned short* __restrict__ msg_out,
    float* __restrict__ attn_raw, float* __restrict__ attn_max)
{
    __shared__ alignas(16) unsigned short S[64 * 128]; // 16 KB
    __shared__ alignas(16) unsigned short H[64 * 128]; // 16 KB
    __shared__ float RED[64][4];
    __shared__ int sET[64];

    const int t = threadIdx.x;
    const int w = t >> 6, l = t & 63;
    const int wm = w >> 2, wn = w & 3;
    const int lm = l & 15, lk = l >> 4;
    const int lrow = l >> 4, lslot = l & 15;
    const int e0 = blockIdx.x * 64;

    // ---- phase 0: stage src rows -> S via global_load_lds (swizzled src) ----
    #pragma unroll
    for (int it = 0; it < 2; ++it) {
        int rb = w * 8 + it * 4;
        int row = rb + lrow;
        int c = lslot ^ (row & 7);
        gload_lds16(nfb + (size_t)src[e0 + row] * DD + c * 8, &S[rb * 128]);
    }
    if (t < 64) sET[t] = etype[e0 + t];
    __syncthreads();

    // ---- GEMM1: hidden = relu(src @ mw1_top + relc[etype]), K=128 ----
    f32x4 acc[2][2];
    #pragma unroll
    for (int mf = 0; mf < 2; ++mf)
        #pragma unroll
        for (int nfr = 0; nfr < 2; ++nfr) acc[mf][nfr] = (f32x4){0.f, 0.f, 0.f, 0.f};

    #pragma unroll
    for (int ks = 0; ks < 4; ++ks) {
        bf16x8 a[2];
        #pragma unroll
        for (int mf = 0; mf < 2; ++mf) {
            int m = wm * 32 + mf * 16 + lm;
            int slot = (ks * 4 + lk) ^ (m & 7);
            a[mf] = *reinterpret_cast<const bf16x8*>(&S[m * 128 + slot * 8]);
        }
        #pragma unroll
        for (int nfr = 0; nfr < 2; ++nfr) {
            int nt = wn * 2 + nfr;
            bf16x8 b = *reinterpret_cast<const bf16x8*>(&mw1p[((nt * 4 + ks) * 64 + l) * 8]);
            acc[0][nfr] = __builtin_amdgcn_mfma_f32_16x16x32_bf16(a[0], b, acc[0][nfr], 0, 0, 0);
            acc[1][nfr] = __builtin_amdgcn_mfma_f32_16x16x32_bf16(a[1], b, acc[1][nfr], 0, 0, 0);
        }
    }
    #pragma unroll
    for (int nfr = 0; nfr < 2; ++nfr) {
        int n = (wn * 2 + nfr) * 16 + lm;
        #pragma unroll
        for (int mf = 0; mf < 2; ++mf)
            #pragma unroll
            for (int r = 0; r < 4; ++r) {
                int m = wm * 32 + mf * 16 + lk * 4 + r;
                float v = acc[mf][nfr][r] + relc[sET[m] * DD + n];
                v = fmaxf(v, 0.0f);
                H[m * 128 + ((n >> 3) ^ (m & 7)) * 8 + (n & 7)] = bf16s(v);
            }
    }
    __syncthreads(); // S reads + H writes complete

    // ---- GEMM2: msg = H @ mw2 + mb2, K=128; write msg -> S ----
    #pragma unroll
    for (int mf = 0; mf < 2; ++mf)
        #pragma unroll
        for (int nfr = 0; nfr < 2; ++nfr) acc[mf][nfr] = (f32x4){0.f, 0.f, 0.f, 0.f};

    #pragma unroll
    for (int ks = 0; ks < 4; ++ks) {
        bf16x8 a[2];
        #pragma unroll
        for (int mf = 0; mf < 2; ++mf) {
            int m = wm * 32 + mf * 16 + lm;
            int slot = (ks * 4 + lk) ^ (m & 7);
            a[mf] = *reinterpret_cast<const bf16x8*>(&H[m * 128 + slot * 8]);
        }
        #pragma unroll
        for (int nfr = 0; nfr < 2; ++nfr) {
            int nt = wn * 2 + nfr;
            bf16x8 b = *reinterpret_cast<const bf16x8*>(&mw2p[((nt * 4 + ks) * 64 + l) * 8]);
            acc[0][nfr] = __builtin_amdgcn_mfma_f32_16x16x32_bf16(a[0], b, acc[0][nfr], 0, 0, 0);
            acc[1][nfr] = __builtin_amdgcn_mfma_f32_16x16x32_bf16(a[1], b, acc[1][nfr], 0, 0, 0);
        }
    }
    #pragma unroll
    for (int nfr = 0; nfr < 2; ++nfr) {
        int n = (wn * 2 + nfr) * 16 + lm;
        float bv = mb2[n];
        #pragma unroll
        for (int mf = 0; mf < 2; ++mf)
            #pragma unroll
            for (int r = 0; r < 4; ++r) {
                int m = wm * 32 + mf * 16 + lk * 4 + r;
                S[m * 128 + ((n >> 3) ^ (m & 7)) * 8 + (n & 7)] = bf16s(acc[mf][nfr][r] + bv);
            }
    }
    __syncthreads(); // msg in S complete; H reads complete

    // ---- phase 3: stage nfa[dst] -> H, copy msg -> global, GEMM3 on S ----
    #pragma unroll
    for (int it = 0; it < 2; ++it) {
        int rb = w * 8 + it * 4;
        int row = rb + lrow;
        int c = lslot ^ (row & 7);
        gload_lds16(nfa + (size_t)dst[e0 + row] * DD + c * 8, &H[rb * 128]);
    }
    #pragma unroll
    for (int j = 0; j < 2; ++j) {
        int q = j * 512 + t;
        int row = q >> 4, c16 = q & 15;
        int slot = c16 ^ (row & 7);
        *reinterpret_cast<uint4*>(&msg_out[(size_t)(e0 + row) * DD + c16 * 8]) =
            *reinterpret_cast<const uint4*>(&S[row * 128 + slot * 8]);
    }

    #pragma unroll
    for (int mf = 0; mf < 2; ++mf)
        #pragma unroll
        for (int nfr = 0; nfr < 2; ++nfr) acc[mf][nfr] = (f32x4){0.f, 0.f, 0.f, 0.f};

    #pragma unroll
    for (int ks = 0; ks < 4; ++ks) {
        bf16x8 a[2];
        #pragma unroll
        for (int mf = 0; mf < 2; ++mf) {
            int m = wm * 32 + mf * 16 + lm;
            int slot = (ks * 4 + lk) ^ (m & 7);
            a[mf] = *reinterpret_cast<const bf16x8*>(&S[m * 128 + slot * 8]);
        }
        #pragma unroll
        for (int nfr = 0; nfr < 2; ++nfr) {
            int nt = wn * 2 + nfr;
            bf16x8 b = *reinterpret_cast<const bf16x8*>(&awBp[((nt * 4 + ks) * 64 + l) * 8]);
            acc[0][nfr] = __builtin_amdgcn_mfma_f32_16x16x32_bf16(a[0], b, acc[0][nfr], 0, 0, 0);
            acc[1][nfr] = __builtin_amdgcn_mfma_f32_16x16x32_bf16(a[1], b, acc[1][nfr], 0, 0, 0);
        }
    }
    __syncthreads(); // nfa staged (vmcnt drained by barrier)

    // ---- epilogue: z = leaky(acc + nfa[dst]); raw = z . aw2 + ab2 ----
    float aw2v[2];
    #pragma unroll
    for (int nfr = 0; nfr < 2; ++nfr) aw2v[nfr] = aw2[(wn * 2 + nfr) * 16 + lm];
    #pragma unroll
    for (int mf = 0; mf < 2; ++mf)
        #pragma unroll
        for (int r = 0; r < 4; ++r) {
            int m = wm * 32 + mf * 16 + lk * 4 + r;
            float s = 0.0f;
            #pragma unroll
            for (int nfr = 0; nfr < 2; ++nfr) {
                int n = (wn * 2 + nfr) * 16 + lm;
                float v = acc[mf][nfr][r] + unbf(H[m * 128 + ((n >> 3) ^ (m & 7)) * 8 + (n & 7)]);
                v = (v > 0.0f) ? v : 0.2f * v;
                s = fmaf(v, aw2v[nfr], s);
            }
            s += __shfl_xor(s, 1, 64);
            s += __shfl_xor(s, 2, 64);
            s += __shfl_xor(s, 4, 64);
            s += __shfl_xor(s, 8, 64);
            if (lm == 0) RED[m][wn] = s;
        }
    __syncthreads();

    if (t < 64) {
        float raw = RED[t][0] + RED[t][1] + RED[t][2] + RED[t][3] + ab2[0];
        int e = e0 + t;
        attn_raw[e] = raw;
        atomic_max_float(&attn_max[dst[e]], raw);
    }
}

// ---------------- segment softmax: exp-sum ----------------
__global__ void k_expsum(const float* __restrict__ attn_raw, const int* __restrict__ dst,
                         const float* __restrict__ attn_max, float* __restrict__ attn_sum)
{
    int e = blockIdx.x * 256 + threadIdx.x;
    if (e < NE) {
        int d = dst[e];
        atomicAdd(&attn_sum[d], expf(attn_raw[e] - attn_max[d]));
    }
}

// ---------------- scatter: aggr += attn_w * messages ----------------
__global__ __launch_bounds__(128) void k_scatter(
    const unsigned short* __restrict__ msg, const float* __restrict__ attn_raw,
    const float* __restrict__ attn_max, const float* __restrict__ attn_sum,
    const int* __restrict__ dst, float* __restrict__ aggr)
{
    const int t = threadIdx.x;
    const int e0 = blockIdx.x * 8;
    #pragma unroll
    for (int e = 0; e < 8; ++e) {
        int eg = e0 + e;
        int d = dst[eg];
        float w = expf(attn_raw[eg] - attn_max[d]) / (attn_sum[d] + 1e-8f);
        float m = unbf(msg[(size_t)eg * DD + t]);
        atomicAdd(&aggr[(size_t)d * DD + t], w * m);
    }
}

// ---------------- node kernel: LN1 + MFMA FFN + LN2 ----------------
__global__ __launch_bounds__(256) void k_node(
    const float* __restrict__ nf, const float* __restrict__ aggr,
    const float* __restrict__ g1, const float* __restrict__ b1,
    const unsigned short* __restrict__ fw1p, const float* __restrict__ fb1,
    const unsigned short* __restrict__ fw2p, const float* __restrict__ fb2,
    const float* __restrict__ g2, const float* __restrict__ b2,
    float* __restrict__ out)
{
    __shared__ alignas(16) unsigned short XB[64 * 128]; // 16 KB
    __shared__ alignas(16) unsigned short HB[64 * 256]; // 32 KB

    const int t = threadIdx.x;
    const int w = t >> 6, l = t & 63;
    const int wm = w >> 1, wn = w & 1;
    const int lm = l & 15, lk = l >> 4;
    const int row = t >> 2;
    const int q = t & 3;
    const long n0 = (long)blockIdx.x * 64;
    const long rg = n0 + row;
    const long rc = (rg < NN) ? rg : (NN - 1);

    float xr[32];
    float s = 0.0f, ss = 0.0f;
    {
        const float* xp = nf + rc * DD + q * 32;
        const float* ap = aggr + rc * DD + q * 32;
        #pragma unroll
        for (int i = 0; i < 8; ++i) {
            float4 a = *reinterpret_cast<const float4*>(xp + i * 4);
            float4 b = *reinterpret_cast<const float4*>(ap + i * 4);
            float v0 = a.x + b.x, v1 = a.y + b.y, v2 = a.z + b.z, v3 = a.w + b.w;
            xr[i * 4 + 0] = v0; xr[i * 4 + 1] = v1; xr[i * 4 + 2] = v2; xr[i * 4 + 3] = v3;
            s += v0 + v1 + v2 + v3;
            ss = fmaf(v0, v0, ss); ss = fmaf(v1, v1, ss);
            ss = fmaf(v2, v2, ss); ss = fmaf(v3, v3, ss);
        }
    }
    s  += __shfl_xor(s, 1, 64);  s  += __shfl_xor(s, 2, 64);
    ss += __shfl_xor(ss, 1, 64); ss += __shfl_xor(ss, 2, 64);
    {
        float mu = s * (1.0f / DD);
        float var = ss * (1.0f / DD) - mu * mu;
        float rstd = rsqrtf(var + 1e-5f);
        #pragma unroll
        for (int i = 0; i < 8; ++i) {
            float4 gv = *reinterpret_cast<const float4*>(g1 + q * 32 + i * 4);
            float4 bv = *reinterpret_cast<const float4*>(b1 + q * 32 + i * 4);
            xr[i * 4 + 0] = (xr[i * 4 + 0] - mu) * rstd * gv.x + bv.x;
            xr[i * 4 + 1] = (xr[i * 4 + 1] - mu) * rstd * gv.y + bv.y;
            xr[i * 4 + 2] = (xr[i * 4 + 2] - mu) * rstd * gv.z + bv.z;
            xr[i * 4 + 3] = (xr[i * 4 + 3] - mu) * rstd * gv.w + bv.w;
        }
        #pragma unroll
        for (int i = 0; i < 4; ++i) {
            int c = q * 4 + i, slot = c ^ (row & 7);
            uint4 v;
            v.x = pk2(xr[i * 8 + 0], xr[i * 8 + 1]);
            v.y = pk2(xr[i * 8 + 2], xr[i * 8 + 3]);
            v.z = pk2(xr[i * 8 + 4], xr[i * 8 + 5]);
            v.w = pk2(xr[i * 8 + 6], xr[i * 8 + 7]);
            *reinterpret_cast<uint4*>(&XB[row * 128 + slot * 8]) = v;
        }
    }
    __syncthreads();

    f32x4 acc2[2][4];
    #pragma unroll
    for (int mf = 0; mf < 2; ++mf)
        #pragma unroll
        for (int nfr = 0; nfr < 4; ++nfr) acc2[mf][nfr] = (f32x4){0.f, 0.f, 0.f, 0.f};

    #pragma unroll
    for (int half = 0; half < 2; ++half) {
        f32x4 acc[2][8];
        #pragma unroll
        for (int mf = 0; mf < 2; ++mf)
            #pragma unroll
            for (int nfr = 0; nfr < 8; ++nfr) acc[mf][nfr] = (f32x4){0.f, 0.f, 0.f, 0.f};

        #pragma unroll
        for (int ks = 0; ks < 4; ++ks) {
            bf16x8 a[2];
            #pragma unroll
            for (int mf = 0; mf < 2; ++mf) {
                int m = wm * 32 + mf * 16 + lm;
                int slot = (ks * 4 + lk) ^ (m & 7);
                a[mf] = *reinterpret_cast<const bf16x8*>(&XB[m * 128 + slot * 8]);
            }
            #pragma unroll
            for (int nfr = 0; nfr < 8; ++nfr) {
                int nt = half * 16 + wn * 8 + nfr;
                bf16x8 b = *reinterpret_cast<const bf16x8*>(&fw1p[((nt * 4 + ks) * 64 + l) * 8]);
                acc[0][nfr] = __builtin_amdgcn_mfma_f32_16x16x32_bf16(a[0], b, acc[0][nfr], 0, 0, 0);
                acc[1][nfr] = __builtin_amdgcn_mfma_f32_16x16x32_bf16(a[1], b, acc[1][nfr], 0, 0, 0);
            }
        }
        #pragma unroll
        for (int nfr = 0; nfr < 8; ++nfr) {
            int nl = wn * 128 + nfr * 16 + lm;
            float bv = fb1[half * 256 + nl];
            #pragma unroll
            for (int mf = 0; mf < 2; ++mf)
                #pragma unroll
                for (int r = 0; r < 4; ++r) {
                    int m = wm * 32 + mf * 16 + lk * 4 + r;
                    float h = acc[mf][nfr][r] + bv;
                    float e = __expf(h * -1.702f);
                    float gvv = h * __builtin_amdgcn_rcpf(1.0f + e);
                    HB[m * 256 + (((nl >> 3) ^ (m & 7)) * 8) + (nl & 7)] = bf16s(gvv);
                }
        }
        __syncthreads();

        #pragma unroll
        for (int ks = 0; ks < 8; ++ks) {
            bf16x8 a[2];
            #pragma unroll
            for (int mf = 0; mf < 2; ++mf) {
                int m = wm * 32 + mf * 16 + lm;
                int slot = (ks * 4 + lk) ^ (m & 7);
                a[mf] = *reinterpret_cast<const bf16x8*>(&HB[m * 256 + slot * 8]);
            }
            #pragma unroll
            for (int nfr = 0; nfr < 4; ++nfr) {
                int nt = wn * 4 + nfr;
                int kg = half * 8 + ks;
                bf16x8 b = *reinterpret_cast<const bf16x8*>(&fw2p[((nt * 16 + kg) * 64 + l) * 8]);
                acc2[0][nfr] = __builtin_amdgcn_mfma_f32_16x16x32_bf16(a[0], b, acc2[0][nfr], 0, 0, 0);
                acc2[1][nfr] = __builtin_amdgcn_mfma_f32_16x16x32_bf16(a[1], b, acc2[1][nfr], 0, 0, 0);
            }
        }
        __syncthreads();
    }

    #pragma unroll
    for (int nfr = 0; nfr < 4; ++nfr) {
        int n = wn * 64 + nfr * 16 + lm;
        float bv = fb2[n];
        #pragma unroll
        for (int mf = 0; mf < 2; ++mf)
            #pragma unroll
            for (int r = 0; r < 4; ++r) {
                int m = wm * 32 + mf * 16 + lk * 4 + r;
                XB[m * 128 + (((n >> 3) ^ (m & 7)) * 8) + (n & 7)] = bf16s(acc2[mf][nfr][r] + bv);
            }
    }
    __syncthreads();

    float s2 = 0.0f, ss2 = 0.0f;
    #pragma unroll
    for (int i = 0; i < 4; ++i) {
        int c = q * 4 + i, slot = c ^ (row & 7);
        uint4 v = *reinterpret_cast<const uint4*>(&XB[row * 128 + slot * 8]);
        float f[8];
        f[0] = unlo(v.x); f[1] = unhi(v.x); f[2] = unlo(v.y); f[3] = unhi(v.y);
        f[4] = unlo(v.z); f[5] = unhi(v.z); f[6] = unlo(v.w); f[7] = unhi(v.w);
        #pragma unroll
        for (int j = 0; j < 8; ++j) {
            float vv = xr[i * 8 + j] + f[j];
            xr[i * 8 + j] = vv;
            s2 += vv;
            ss2 = fmaf(vv, vv, ss2);
        }
    }
    s2  += __shfl_xor(s2, 1, 64);  s2  += __shfl_xor(s2, 2, 64);
    ss2 += __shfl_xor(ss2, 1, 64); ss2 += __shfl_xor(ss2, 2, 64);
    {
        float mu = s2 * (1.0f / DD);
        float var = ss2 * (1.0f / DD) - mu * mu;
        float rstd = rsqrtf(var + 1e-5f);
        if (rg < NN) {
            float* op = out + rg * DD + q * 32;
            #pragma unroll
            for (int i = 0; i < 8; ++i) {
                float4 gv = *reinterpret_cast<const float4*>(g2 + q * 32 + i * 4);
                float4 bv = *reinterpret_cast<const float4*>(b2 + q * 32 + i * 4);
                float4 o;
                o.x = (xr[i * 4 + 0] - mu) * rstd * gv.x + bv.x;
                o.y = (xr[i * 4 + 1] - mu) * rstd * gv.y + bv.y;
                o.z = (xr[i * 4 + 2] - mu) * rstd * gv.z + bv.z;
                o.w = (xr[i * 4 + 3] - mu) * rstd * gv.w + bv.w;
                *reinterpret_cast<float4*>(op + i * 4) = o;
            }
        }
    }
}

extern "C" void kernel_launch(void* const* d_in, const int* in_sizes, int n_in,
                              void* d_out, int out_size, void* d_ws, size_t ws_size,
                              hipStream_t stream)
{
    const float* nf  = (const float*)d_in[0];
    const int*   ei  = (const int*)d_in[1];
    const int*   et  = (const int*)d_in[2];
    const float* rel = (const float*)d_in[3];
    const float* mw1 = (const float*)d_in[4];
    const float* mb1 = (const float*)d_in[5];
    const float* mw2 = (const float*)d_in[6];
    const float* mb2 = (const float*)d_in[7];
    const float* aw1 = (const float*)d_in[8];
    const float* ab1 = (const float*)d_in[9];
    const float* aw2 = (const float*)d_in[10];
    const float* ab2 = (const float*)d_in[11];
    const float* g1  = (const float*)d_in[12];
    const float* b1  = (const float*)d_in[13];
    const float* fw1 = (const float*)d_in[14];
    const float* fb1 = (const float*)d_in[15];
    const float* fw2 = (const float*)d_in[16];
    const float* fb2 = (const float*)d_in[17];
    const float* g2  = (const float*)d_in[18];
    const float* b2  = (const float*)d_in[19];
    float* out = (float*)d_out;

    char* ws = (char*)d_ws;
    size_t off = 0;
    auto alloc = [&](size_t bytes) -> char* {
        char* p = ws + off;
        off += (bytes + 255) & ~(size_t)255;
        return p;
    };
    unsigned short* msg = (unsigned short*)alloc((size_t)NE * DD * 2);
    float* attn_raw = (float*)alloc((size_t)NE * 4);
    float* attn_max = (float*)alloc((size_t)NN * 4);
    float* attn_sum = (float*)alloc((size_t)NN * 4);
    float* aggr     = (float*)alloc((size_t)NN * DD * 4);
    unsigned short* nfb  = (unsigned short*)alloc((size_t)NN * DD * 2);
    float* relc = (float*)alloc((size_t)RR * DD * 4);
    unsigned short* mw1p = (unsigned short*)alloc(16384 * 2);
    unsigned short* mw2p = (unsigned short*)alloc(16384 * 2);
    unsigned short* awTp = (unsigned short*)alloc(16384 * 2);
    unsigned short* awBp = (unsigned short*)alloc(16384 * 2);
    unsigned short* fw1p = (unsigned short*)alloc(65536 * 2);
    unsigned short* fw2p = (unsigned short*)alloc(65536 * 2);

    // nfa aliases aggr (nfa dead after k_edge; aggr zeroed after k_edge)
    unsigned short* nfa = (unsigned short*)aggr;

    const int* srcp = ei;
    const int* dstp = ei + NE;

    hipLaunchKernelGGL(k_init1, dim3((NN + 255) / 256), dim3(256), 0, stream,
                       attn_sum, (unsigned int*)attn_max);
    hipLaunchKernelGGL(k_prep, dim3(NN * DD / 8 / 256), dim3(256), 0, stream, nf, nfb);
    hipLaunchKernelGGL(k_pack, dim3(768), dim3(256), 0, stream,
                       mw1, mw2, aw1, fw1, fw2, mw1p, mw2p, awTp, awBp, fw1p, fw2p);
    hipLaunchKernelGGL(k_relc, dim3(100), dim3(256), 0, stream, rel, mw1, mb1, relc);
    hipLaunchKernelGGL(k_nfa, dim3((NN + 63) / 64), dim3(256), 0, stream,
                       nfb, awTp, ab1, nfa);
    hipLaunchKernelGGL(k_edge, dim3(NE / 64), dim3(512), 0, stream,
                       nfb, srcp, dstp, et, nfa, relc,
                       mw1p, mw2p, mb2, awBp, aw2, ab2,
                       msg, attn_raw, attn_max);
    hipLaunchKernelGGL(k_zero, dim3(2048), dim3(256), 0, stream, (float4*)aggr);
    hipLaunchKernelGGL(k_expsum, dim3((NE + 255) / 256), dim3(256), 0, stream,
                       attn_raw, dstp, attn_max, attn_sum);
    hipLaunchKernelGGL(k_scatter, dim3(NE / 8), dim3(128), 0, stream,
                       msg, attn_raw, attn_max, attn_sum, dstp, aggr);
    hipLaunchKernelGGL(k_node, dim3((NN + 63) / 64), dim3(256), 0, stream,
                       nf, aggr, g1, b1, fw1p, fb1, fw2p, fb2, g2, b2, out);
}

// Round 6
// 510.603 us; speedup vs baseline: 5.4266x; 1.2703x over previous
//
#include <hip/hip_runtime.h>
#include <hip/hip_bf16.h>

#define NN 100000
#define NE 600000
#define DD 128
#define RR 200
#define SCAN_NB ((NN + 255) / 256)   // 391

typedef __attribute__((ext_vector_type(8))) short bf16x8;
typedef __attribute__((ext_vector_type(4))) float f32x4;

__device__ __forceinline__ unsigned int bfbits(float x) {
    return (unsigned int)__builtin_bit_cast(unsigned short, __float2bfloat16(x));
}
__device__ __forceinline__ unsigned int pk2(float a, float b) {
    return bfbits(a) | (bfbits(b) << 16);
}
__device__ __forceinline__ unsigned short bf16s(float x) {
    return __builtin_bit_cast(unsigned short, __float2bfloat16(x));
}
__device__ __forceinline__ float unbf(unsigned short u) {
    return __builtin_bit_cast(float, ((unsigned int)u) << 16);
}
__device__ __forceinline__ float unlo(unsigned int u) {
    return __builtin_bit_cast(float, u << 16);
}
__device__ __forceinline__ float unhi(unsigned int u) {
    return __builtin_bit_cast(float, u & 0xffff0000u);
}

__device__ __forceinline__ void gload_lds16(const void* g, void* l) {
    __builtin_amdgcn_global_load_lds(
        (const __attribute__((address_space(1))) void*)g,
        (__attribute__((address_space(3))) void*)l, 16, 0, 0);
}

// ---------------- zero edge-count histogram ----------------
__global__ void k_initc(int* __restrict__ cnt) {
    int i = blockIdx.x * 256 + threadIdx.x;
    if (i < NN) cnt[i] = 0;
}

// ---------------- histogram of dst ----------------
__global__ void k_hist(const int* __restrict__ dst, int* __restrict__ cnt) {
    int e = blockIdx.x * 256 + threadIdx.x;
    if (e < NE) atomicAdd(&cnt[dst[e]], 1);
}

// ---------------- 3-kernel exclusive scan over cnt[NN] ----------------
__global__ void k_scanA(const int* __restrict__ cnt, int* __restrict__ bsum) {
    __shared__ int red[256];
    int i = blockIdx.x * 256 + threadIdx.x;
    red[threadIdx.x] = (i < NN) ? cnt[i] : 0;
    __syncthreads();
    for (int off = 128; off >= 1; off >>= 1) {
        if (threadIdx.x < off) red[threadIdx.x] += red[threadIdx.x + off];
        __syncthreads();
    }
    if (threadIdx.x == 0) bsum[blockIdx.x] = red[0];
}

__global__ void k_scanB(int* __restrict__ bsum) {
    __shared__ int sh[512];
    int t = threadIdx.x;
    int v = (t < SCAN_NB) ? bsum[t] : 0;
    sh[t] = v;
    __syncthreads();
    for (int off = 1; off < 512; off <<= 1) {
        int add = (t >= off) ? sh[t - off] : 0;
        __syncthreads();
        sh[t] += add;
        __syncthreads();
    }
    if (t < SCAN_NB) bsum[t] = sh[t] - v;   // exclusive
}

__global__ void k_scanC(const int* __restrict__ cnt, const int* __restrict__ bsum,
                        int* __restrict__ row_start, int* __restrict__ cursor) {
    __shared__ int sh[256];
    int i = blockIdx.x * 256 + threadIdx.x;
    int t = threadIdx.x;
    int v = (i < NN) ? cnt[i] : 0;
    sh[t] = v;
    __syncthreads();
    for (int off = 1; off < 256; off <<= 1) {
        int add = (t >= off) ? sh[t - off] : 0;
        __syncthreads();
        sh[t] += add;
        __syncthreads();
    }
    if (i < NN) {
        int ex = bsum[blockIdx.x] + sh[t] - v;
        row_start[i] = ex;
        cursor[i] = ex;
    }
}

// ---------------- bucket: eid_sorted grouped by dst ----------------
__global__ void k_bucket(const int* __restrict__ dst, int* __restrict__ cursor,
                         int* __restrict__ eid) {
    int e = blockIdx.x * 256 + threadIdx.x;
    if (e < NE) {
        int p = atomicAdd(&cursor[dst[e]], 1);
        eid[p] = e;
    }
}

// ---------------- prep: bf16 copy of node features ----------------
__global__ void k_prep(const float* __restrict__ nf, unsigned short* __restrict__ nfb) {
    int i = blockIdx.x * 256 + threadIdx.x;
    if (i >= NN * DD / 8) return;
    const float* sp = nf + (size_t)i * 8;
    float4 f0 = *reinterpret_cast<const float4*>(sp);
    float4 f1 = *reinterpret_cast<const float4*>(sp + 4);
    uint4 v;
    v.x = pk2(f0.x, f0.y); v.y = pk2(f0.z, f0.w);
    v.z = pk2(f1.x, f1.y); v.w = pk2(f1.z, f1.w);
    *reinterpret_cast<uint4*>(nfb + (size_t)i * 8) = v;
}

// ---------------- relc = rel @ mw1_bot + mb1 (fp32, 200x128) ----------------
__global__ void k_relc(const float* __restrict__ rel, const float* __restrict__ mw1,
                       const float* __restrict__ mb1, float* __restrict__ relc) {
    int idx = blockIdx.x * 256 + threadIdx.x;
    if (idx >= RR * DD) return;
    int r = idx >> 7, n = idx & 127;
    float s = mb1[n];
    for (int k = 0; k < 128; ++k)
        s = fmaf(rel[r * 128 + k], mw1[(128 + k) * 128 + n], s);
    relc[idx] = s;
}

// ---------------- pack weights into MFMA B-fragment order (bf16) ------------
__global__ void k_pack(const float* __restrict__ mw1, const float* __restrict__ mw2,
                       const float* __restrict__ aw1,
                       const float* __restrict__ fw1, const float* __restrict__ fw2,
                       unsigned short* __restrict__ mw1p,
                       unsigned short* __restrict__ mw2p,
                       unsigned short* __restrict__ awTp,
                       unsigned short* __restrict__ awBp,
                       unsigned short* __restrict__ fw1p,
                       unsigned short* __restrict__ fw2p) {
    int idx = blockIdx.x * 256 + threadIdx.x;      // 196608 total
    if (idx < 16384) {            // mw1 TOP half: K=128 (KS=4), N=128
        int i = idx & 7, l = (idx >> 3) & 63, ks = (idx >> 9) & 3, nt = idx >> 11;
        int k = ks * 32 + (l >> 4) * 8 + i, n = nt * 16 + (l & 15);
        mw1p[idx] = bf16s(mw1[k * 128 + n]);
    } else if (idx < 32768) {     // mw2: K=128
        int j = idx - 16384;
        int i = j & 7, l = (j >> 3) & 63, ks = (j >> 9) & 3, nt = j >> 11;
        int k = ks * 32 + (l >> 4) * 8 + i, n = nt * 16 + (l & 15);
        mw2p[j] = bf16s(mw2[k * 128 + n]);
    } else if (idx < 49152) {     // aw1 TOP half
        int j = idx - 32768;
        int i = j & 7, l = (j >> 3) & 63, ks = (j >> 9) & 3, nt = j >> 11;
        int k = ks * 32 + (l >> 4) * 8 + i, n = nt * 16 + (l & 15);
        awTp[j] = bf16s(aw1[k * 128 + n]);
    } else if (idx < 65536) {     // aw1 BOTTOM half
        int j = idx - 49152;
        int i = j & 7, l = (j >> 3) & 63, ks = (j >> 9) & 3, nt = j >> 11;
        int k = ks * 32 + (l >> 4) * 8 + i, n = nt * 16 + (l & 15);
        awBp[j] = bf16s(aw1[(128 + k) * 128 + n]);
    } else if (idx < 131072) {    // fw1: K=128 (KS=4), N=512
        int j = idx - 65536;
        int i = j & 7, l = (j >> 3) & 63, ks = (j >> 9) & 3, nt = j >> 11;
        int k = ks * 32 + (l >> 4) * 8 + i, n = nt * 16 + (l & 15);
        fw1p[j] = bf16s(fw1[k * 512 + n]);
    } else if (idx < 196608) {    // fw2: K=512 (KS=16), N=128
        int j = idx - 131072;
        int i = j & 7, l = (j >> 3) & 63, ks = (j >> 9) & 15, nt = j >> 13;
        int k = ks * 32 + (l >> 4) * 8 + i, n = nt * 16 + (l & 15);
        fw2p[j] = bf16s(fw2[k * 128 + n]);
    }
}

// ---------------- nfa = nf @ aw1_top + ab1 (bf16, MFMA) ----------------
__global__ __launch_bounds__(256) void k_nfa(
    const unsigned short* __restrict__ nfb, const unsigned short* __restrict__ awTp,
    const float* __restrict__ ab1, unsigned short* __restrict__ nfa)
{
    __shared__ alignas(16) unsigned short XB[64 * 128]; // 16 KB
    const int t = threadIdx.x;
    const int w = t >> 6, l = t & 63;
    const int wm = w >> 1, wn = w & 1;
    const int lm = l & 15, lk = l >> 4;
    const int lrow = l >> 4, lslot = l & 15;
    const int n0 = blockIdx.x * 64;

    #pragma unroll
    for (int it = 0; it < 4; ++it) {
        int rb = w * 16 + it * 4;
        int row = rb + lrow;
        long grow = n0 + row; if (grow >= NN) grow = NN - 1;
        int c = lslot ^ (row & 7);
        gload_lds16(nfb + grow * DD + c * 8, &XB[rb * 128]);
    }
    __syncthreads();

    f32x4 acc[2][4];
    #pragma unroll
    for (int mf = 0; mf < 2; ++mf)
        #pragma unroll
        for (int nfr = 0; nfr < 4; ++nfr) acc[mf][nfr] = (f32x4){0.f, 0.f, 0.f, 0.f};

    #pragma unroll
    for (int ks = 0; ks < 4; ++ks) {
        bf16x8 a[2];
        #pragma unroll
        for (int mf = 0; mf < 2; ++mf) {
            int m = wm * 32 + mf * 16 + lm;
            int slot = (ks * 4 + lk) ^ (m & 7);
            a[mf] = *reinterpret_cast<const bf16x8*>(&XB[m * 128 + slot * 8]);
        }
        #pragma unroll
        for (int nfr = 0; nfr < 4; ++nfr) {
            int nt = wn * 4 + nfr;
            bf16x8 b = *reinterpret_cast<const bf16x8*>(&awTp[((nt * 4 + ks) * 64 + l) * 8]);
            acc[0][nfr] = __builtin_amdgcn_mfma_f32_16x16x32_bf16(a[0], b, acc[0][nfr], 0, 0, 0);
            acc[1][nfr] = __builtin_amdgcn_mfma_f32_16x16x32_bf16(a[1], b, acc[1][nfr], 0, 0, 0);
        }
    }
    __syncthreads();

    #pragma unroll
    for (int nfr = 0; nfr < 4; ++nfr) {
        int n = wn * 64 + nfr * 16 + lm;
        float bv = ab1[n];
        #pragma unroll
        for (int mf = 0; mf < 2; ++mf)
            #pragma unroll
            for (int r = 0; r < 4; ++r) {
                int m = wm * 32 + mf * 16 + lk * 4 + r;
                XB[m * 128 + n] = bf16s(acc[mf][nfr][r] + bv);
            }
    }
    __syncthreads();

    #pragma unroll
    for (int j = 0; j < 4; ++j) {
        int q = j * 256 + t;
        int row = q >> 4, c16 = q & 15;
        if (n0 + row < NN)
            *reinterpret_cast<uint4*>(&nfa[(size_t)(n0 + row) * DD + c16 * 8]) =
                *reinterpret_cast<const uint4*>(&XB[row * 128 + c16 * 8]);
    }
}

// ---------------- edge kernel: 3x K=128 MFMA GEMMs ------------
__global__ __launch_bounds__(512) void k_edge(
    const unsigned short* __restrict__ nfb, const int* __restrict__ src,
    const int* __restrict__ dst, const int* __restrict__ etype,
    const unsigned short* __restrict__ nfa, const float* __restrict__ relc,
    const unsigned short* __restrict__ mw1p,
    const unsigned short* __restrict__ mw2p, const float* __restrict__ mb2,
    const unsigned short* __restrict__ awBp,
    const float* __restrict__ aw2, const float* __restrict__ ab2,
    unsigned short* __restrict__ msg_out, float* __restrict__ attn_raw)
{
    __shared__ alignas(16) unsigned short S[64 * 128]; // 16 KB
    __shared__ alignas(16) unsigned short H[64 * 128]; // 16 KB
    __shared__ float RED[64][4];
    __shared__ int sET[64];

    const int t = threadIdx.x;
    const int w = t >> 6, l = t & 63;
    const int wm = w >> 2, wn = w & 3;
    const int lm = l & 15, lk = l >> 4;
    const int lrow = l >> 4, lslot = l & 15;
    const int e0 = blockIdx.x * 64;

    #pragma unroll
    for (int it = 0; it < 2; ++it) {
        int rb = w * 8 + it * 4;
        int row = rb + lrow;
        int c = lslot ^ (row & 7);
        gload_lds16(nfb + (size_t)src[e0 + row] * DD + c * 8, &S[rb * 128]);
    }
    if (t < 64) sET[t] = etype[e0 + t];
    __syncthreads();

    f32x4 acc[2][2];
    #pragma unroll
    for (int mf = 0; mf < 2; ++mf)
        #pragma unroll
        for (int nfr = 0; nfr < 2; ++nfr) acc[mf][nfr] = (f32x4){0.f, 0.f, 0.f, 0.f};

    #pragma unroll
    for (int ks = 0; ks < 4; ++ks) {
        bf16x8 a[2];
        #pragma unroll
        for (int mf = 0; mf < 2; ++mf) {
            int m = wm * 32 + mf * 16 + lm;
            int slot = (ks * 4 + lk) ^ (m & 7);
            a[mf] = *reinterpret_cast<const bf16x8*>(&S[m * 128 + slot * 8]);
        }
        #pragma unroll
        for (int nfr = 0; nfr < 2; ++nfr) {
            int nt = wn * 2 + nfr;
            bf16x8 b = *reinterpret_cast<const bf16x8*>(&mw1p[((nt * 4 + ks) * 64 + l) * 8]);
            acc[0][nfr] = __builtin_amdgcn_mfma_f32_16x16x32_bf16(a[0], b, acc[0][nfr], 0, 0, 0);
            acc[1][nfr] = __builtin_amdgcn_mfma_f32_16x16x32_bf16(a[1], b, acc[1][nfr], 0, 0, 0);
        }
    }
    #pragma unroll
    for (int nfr = 0; nfr < 2; ++nfr) {
        int n = (wn * 2 + nfr) * 16 + lm;
        #pragma unroll
        for (int mf = 0; mf < 2; ++mf)
            #pragma unroll
            for (int r = 0; r < 4; ++r) {
                int m = wm * 32 + mf * 16 + lk * 4 + r;
                float v = acc[mf][nfr][r] + relc[sET[m] * DD + n];
                v = fmaxf(v, 0.0f);
                H[m * 128 + ((n >> 3) ^ (m & 7)) * 8 + (n & 7)] = bf16s(v);
            }
    }
    __syncthreads();

    #pragma unroll
    for (int mf = 0; mf < 2; ++mf)
        #pragma unroll
        for (int nfr = 0; nfr < 2; ++nfr) acc[mf][nfr] = (f32x4){0.f, 0.f, 0.f, 0.f};

    #pragma unroll
    for (int ks = 0; ks < 4; ++ks) {
        bf16x8 a[2];
        #pragma unroll
        for (int mf = 0; mf < 2; ++mf) {
            int m = wm * 32 + mf * 16 + lm;
            int slot = (ks * 4 + lk) ^ (m & 7);
            a[mf] = *reinterpret_cast<const bf16x8*>(&H[m * 128 + slot * 8]);
        }
        #pragma unroll
        for (int nfr = 0; nfr < 2; ++nfr) {
            int nt = wn * 2 + nfr;
            bf16x8 b = *reinterpret_cast<const bf16x8*>(&mw2p[((nt * 4 + ks) * 64 + l) * 8]);
            acc[0][nfr] = __builtin_amdgcn_mfma_f32_16x16x32_bf16(a[0], b, acc[0][nfr], 0, 0, 0);
            acc[1][nfr] = __builtin_amdgcn_mfma_f32_16x16x32_bf16(a[1], b, acc[1][nfr], 0, 0, 0);
        }
    }
    #pragma unroll
    for (int nfr = 0; nfr < 2; ++nfr) {
        int n = (wn * 2 + nfr) * 16 + lm;
        float bv = mb2[n];
        #pragma unroll
        for (int mf = 0; mf < 2; ++mf)
            #pragma unroll
            for (int r = 0; r < 4; ++r) {
                int m = wm * 32 + mf * 16 + lk * 4 + r;
                S[m * 128 + ((n >> 3) ^ (m & 7)) * 8 + (n & 7)] = bf16s(acc[mf][nfr][r] + bv);
            }
    }
    __syncthreads();

    #pragma unroll
    for (int it = 0; it < 2; ++it) {
        int rb = w * 8 + it * 4;
        int row = rb + lrow;
        int c = lslot ^ (row & 7);
        gload_lds16(nfa + (size_t)dst[e0 + row] * DD + c * 8, &H[rb * 128]);
    }
    #pragma unroll
    for (int j = 0; j < 2; ++j) {
        int q = j * 512 + t;
        int row = q >> 4, c16 = q & 15;
        int slot = c16 ^ (row & 7);
        *reinterpret_cast<uint4*>(&msg_out[(size_t)(e0 + row) * DD + c16 * 8]) =
            *reinterpret_cast<const uint4*>(&S[row * 128 + slot * 8]);
    }

    #pragma unroll
    for (int mf = 0; mf < 2; ++mf)
        #pragma unroll
        for (int nfr = 0; nfr < 2; ++nfr) acc[mf][nfr] = (f32x4){0.f, 0.f, 0.f, 0.f};

    #pragma unroll
    for (int ks = 0; ks < 4; ++ks) {
        bf16x8 a[2];
        #pragma unroll
        for (int mf = 0; mf < 2; ++mf) {
            int m = wm * 32 + mf * 16 + lm;
            int slot = (ks * 4 + lk) ^ (m & 7);
            a[mf] = *reinterpret_cast<const bf16x8*>(&S[m * 128 + slot * 8]);
        }
        #pragma unroll
        for (int nfr = 0; nfr < 2; ++nfr) {
            int nt = wn * 2 + nfr;
            bf16x8 b = *reinterpret_cast<const bf16x8*>(&awBp[((nt * 4 + ks) * 64 + l) * 8]);
            acc[0][nfr] = __builtin_amdgcn_mfma_f32_16x16x32_bf16(a[0], b, acc[0][nfr], 0, 0, 0);
            acc[1][nfr] = __builtin_amdgcn_mfma_f32_16x16x32_bf16(a[1], b, acc[1][nfr], 0, 0, 0);
        }
    }
    __syncthreads();

    float aw2v[2];
    #pragma unroll
    for (int nfr = 0; nfr < 2; ++nfr) aw2v[nfr] = aw2[(wn * 2 + nfr) * 16 + lm];
    #pragma unroll
    for (int mf = 0; mf < 2; ++mf)
        #pragma unroll
        for (int r = 0; r < 4; ++r) {
            int m = wm * 32 + mf * 16 + lk * 4 + r;
            float s = 0.0f;
            #pragma unroll
            for (int nfr = 0; nfr < 2; ++nfr) {
                int n = (wn * 2 + nfr) * 16 + lm;
                float v = acc[mf][nfr][r] + unbf(H[m * 128 + ((n >> 3) ^ (m & 7)) * 8 + (n & 7)]);
                v = (v > 0.0f) ? v : 0.2f * v;
                s = fmaf(v, aw2v[nfr], s);
            }
            s += __shfl_xor(s, 1, 64);
            s += __shfl_xor(s, 2, 64);
            s += __shfl_xor(s, 4, 64);
            s += __shfl_xor(s, 8, 64);
            if (lm == 0) RED[m][wn] = s;
        }
    __syncthreads();

    if (t < 64) {
        attn_raw[e0 + t] = RED[t][0] + RED[t][1] + RED[t][2] + RED[t][3] + ab2[0];
    }
}

// ---------------- fused per-node softmax + weighted aggregate ---------------
// block = 256 thr = 4 waves; one wave per node.
__global__ __launch_bounds__(256) void k_aggr(
    const unsigned short* __restrict__ msg, const float* __restrict__ raw,
    const int* __restrict__ row_start, const int* __restrict__ cnt,
    const int* __restrict__ eid, float* __restrict__ aggr)
{
    const int l = threadIdx.x & 63;
    const int n = blockIdx.x * 4 + (threadIdx.x >> 6);
    if (n >= NN) return;
    const int rs = row_start[n], deg = cnt[n];

    float m = -INFINITY;
    for (int j = l; j < deg; j += 64) m = fmaxf(m, raw[eid[rs + j]]);
    #pragma unroll
    for (int off = 32; off >= 1; off >>= 1) m = fmaxf(m, __shfl_xor(m, off, 64));

    float s = 0.0f;
    for (int j = l; j < deg; j += 64) s += expf(raw[eid[rs + j]] - m);
    #pragma unroll
    for (int off = 32; off >= 1; off >>= 1) s += __shfl_xor(s, off, 64);
    const float rinv = 1.0f / (s + 1e-8f);

    float a0 = 0.0f, a1 = 0.0f;
    for (int base = 0; base < deg; base += 64) {
        int nt = min(64, deg - base);
        int e_l = 0; float w_l = 0.0f;
        if (l < nt) {
            e_l = eid[rs + base + l];
            w_l = expf(raw[e_l] - m) * rinv;
        }
        for (int j = 0; j < nt; ++j) {
            int e = __shfl(e_l, j, 64);
            float w = __shfl(w_l, j, 64);
            unsigned int v = *reinterpret_cast<const unsigned int*>(&msg[(size_t)e * DD + l * 2]);
            a0 = fmaf(w, unlo(v), a0);
            a1 = fmaf(w, unhi(v), a1);
        }
    }
    float2 o = {a0, a1};
    *reinterpret_cast<float2*>(&aggr[(size_t)n * DD + l * 2]) = o;
}

// ---------------- node kernel: LN1 + MFMA FFN + LN2 ----------------
__global__ __launch_bounds__(256) void k_node(
    const float* __restrict__ nf, const float* __restrict__ aggr,
    const float* __restrict__ g1, const float* __restrict__ b1,
    const unsigned short* __restrict__ fw1p, const float* __restrict__ fb1,
    const unsigned short* __restrict__ fw2p, const float* __restrict__ fb2,
    const float* __restrict__ g2, const float* __restrict__ b2,
    float* __restrict__ out)
{
    __shared__ alignas(16) unsigned short XB[64 * 128]; // 16 KB
    __shared__ alignas(16) unsigned short HB[64 * 256]; // 32 KB

    const int t = threadIdx.x;
    const int w = t >> 6, l = t & 63;
    const int wm = w >> 1, wn = w & 1;
    const int lm = l & 15, lk = l >> 4;
    const int row = t >> 2;
    const int q = t & 3;
    const long n0 = (long)blockIdx.x * 64;
    const long rg = n0 + row;
    const long rc = (rg < NN) ? rg : (NN - 1);

    float xr[32];
    float s = 0.0f, ss = 0.0f;
    {
        const float* xp = nf + rc * DD + q * 32;
        const float* ap = aggr + rc * DD + q * 32;
        #pragma unroll
        for (int i = 0; i < 8; ++i) {
            float4 a = *reinterpret_cast<const float4*>(xp + i * 4);
            float4 b = *reinterpret_cast<const float4*>(ap + i * 4);
            float v0 = a.x + b.x, v1 = a.y + b.y, v2 = a.z + b.z, v3 = a.w + b.w;
            xr[i * 4 + 0] = v0; xr[i * 4 + 1] = v1; xr[i * 4 + 2] = v2; xr[i * 4 + 3] = v3;
            s += v0 + v1 + v2 + v3;
            ss = fmaf(v0, v0, ss); ss = fmaf(v1, v1, ss);
            ss = fmaf(v2, v2, ss); ss = fmaf(v3, v3, ss);
        }
    }
    s  += __shfl_xor(s, 1, 64);  s  += __shfl_xor(s, 2, 64);
    ss += __shfl_xor(ss, 1, 64); ss += __shfl_xor(ss, 2, 64);
    {
        float mu = s * (1.0f / DD);
        float var = ss * (1.0f / DD) - mu * mu;
        float rstd = rsqrtf(var + 1e-5f);
        #pragma unroll
        for (int i = 0; i < 8; ++i) {
            float4 gv = *reinterpret_cast<const float4*>(g1 + q * 32 + i * 4);
            float4 bv = *reinterpret_cast<const float4*>(b1 + q * 32 + i * 4);
            xr[i * 4 + 0] = (xr[i * 4 + 0] - mu) * rstd * gv.x + bv.x;
            xr[i * 4 + 1] = (xr[i * 4 + 1] - mu) * rstd * gv.y + bv.y;
            xr[i * 4 + 2] = (xr[i * 4 + 2] - mu) * rstd * gv.z + bv.z;
            xr[i * 4 + 3] = (xr[i * 4 + 3] - mu) * rstd * gv.w + bv.w;
        }
        #pragma unroll
        for (int i = 0; i < 4; ++i) {
            int c = q * 4 + i, slot = c ^ (row & 7);
            uint4 v;
            v.x = pk2(xr[i * 8 + 0], xr[i * 8 + 1]);
            v.y = pk2(xr[i * 8 + 2], xr[i * 8 + 3]);
            v.z = pk2(xr[i * 8 + 4], xr[i * 8 + 5]);
            v.w = pk2(xr[i * 8 + 6], xr[i * 8 + 7]);
            *reinterpret_cast<uint4*>(&XB[row * 128 + slot * 8]) = v;
        }
    }
    __syncthreads();

    f32x4 acc2[2][4];
    #pragma unroll
    for (int mf = 0; mf < 2; ++mf)
        #pragma unroll
        for (int nfr = 0; nfr < 4; ++nfr) acc2[mf][nfr] = (f32x4){0.f, 0.f, 0.f, 0.f};

    #pragma unroll
    for (int half = 0; half < 2; ++half) {
        f32x4 acc[2][8];
        #pragma unroll
        for (int mf = 0; mf < 2; ++mf)
            #pragma unroll
            for (int nfr = 0; nfr < 8; ++nfr) acc[mf][nfr] = (f32x4){0.f, 0.f, 0.f, 0.f};

        #pragma unroll
        for (int ks = 0; ks < 4; ++ks) {
            bf16x8 a[2];
            #pragma unroll
            for (int mf = 0; mf < 2; ++mf) {
                int m = wm * 32 + mf * 16 + lm;
                int slot = (ks * 4 + lk) ^ (m & 7);
                a[mf] = *reinterpret_cast<const bf16x8*>(&XB[m * 128 + slot * 8]);
            }
            #pragma unroll
            for (int nfr = 0; nfr < 8; ++nfr) {
                int nt = half * 16 + wn * 8 + nfr;
                bf16x8 b = *reinterpret_cast<const bf16x8*>(&fw1p[((nt * 4 + ks) * 64 + l) * 8]);
                acc[0][nfr] = __builtin_amdgcn_mfma_f32_16x16x32_bf16(a[0], b, acc[0][nfr], 0, 0, 0);
                acc[1][nfr] = __builtin_amdgcn_mfma_f32_16x16x32_bf16(a[1], b, acc[1][nfr], 0, 0, 0);
            }
        }
        #pragma unroll
        for (int nfr = 0; nfr < 8; ++nfr) {
            int nl = wn * 128 + nfr * 16 + lm;
            float bv = fb1[half * 256 + nl];
            #pragma unroll
            for (int mf = 0; mf < 2; ++mf)
                #pragma unroll
                for (int r = 0; r < 4; ++r) {
                    int m = wm * 32 + mf * 16 + lk * 4 + r;
                    float h = acc[mf][nfr][r] + bv;
                    float e = __expf(h * -1.702f);
                    float gvv = h * __builtin_amdgcn_rcpf(1.0f + e);
                    HB[m * 256 + (((nl >> 3) ^ (m & 7)) * 8) + (nl & 7)] = bf16s(gvv);
                }
        }
        __syncthreads();

        #pragma unroll
        for (int ks = 0; ks < 8; ++ks) {
            bf16x8 a[2];
            #pragma unroll
            for (int mf = 0; mf < 2; ++mf) {
                int m = wm * 32 + mf * 16 + lm;
                int slot = (ks * 4 + lk) ^ (m & 7);
                a[mf] = *reinterpret_cast<const bf16x8*>(&HB[m * 256 + slot * 8]);
            }
            #pragma unroll
            for (int nfr = 0; nfr < 4; ++nfr) {
                int nt = wn * 4 + nfr;
                int kg = half * 8 + ks;
                bf16x8 b = *reinterpret_cast<const bf16x8*>(&fw2p[((nt * 16 + kg) * 64 + l) * 8]);
                acc2[0][nfr] = __builtin_amdgcn_mfma_f32_16x16x32_bf16(a[0], b, acc2[0][nfr], 0, 0, 0);
                acc2[1][nfr] = __builtin_amdgcn_mfma_f32_16x16x32_bf16(a[1], b, acc2[1][nfr], 0, 0, 0);
            }
        }
        __syncthreads();
    }

    #pragma unroll
    for (int nfr = 0; nfr < 4; ++nfr) {
        int n = wn * 64 + nfr * 16 + lm;
        float bv = fb2[n];
        #pragma unroll
        for (int mf = 0; mf < 2; ++mf)
            #pragma unroll
            for (int r = 0; r < 4; ++r) {
                int m = wm * 32 + mf * 16 + lk * 4 + r;
                XB[m * 128 + (((n >> 3) ^ (m & 7)) * 8) + (n & 7)] = bf16s(acc2[mf][nfr][r] + bv);
            }
    }
    __syncthreads();

    float s2 = 0.0f, ss2 = 0.0f;
    #pragma unroll
    for (int i = 0; i < 4; ++i) {
        int c = q * 4 + i, slot = c ^ (row & 7);
        uint4 v = *reinterpret_cast<const uint4*>(&XB[row * 128 + slot * 8]);
        float f[8];
        f[0] = unlo(v.x); f[1] = unhi(v.x); f[2] = unlo(v.y); f[3] = unhi(v.y);
        f[4] = unlo(v.z); f[5] = unhi(v.z); f[6] = unlo(v.w); f[7] = unhi(v.w);
        #pragma unroll
        for (int j = 0; j < 8; ++j) {
            float vv = xr[i * 8 + j] + f[j];
            xr[i * 8 + j] = vv;
            s2 += vv;
            ss2 = fmaf(vv, vv, ss2);
        }
    }
    s2  += __shfl_xor(s2, 1, 64);  s2  += __shfl_xor(s2, 2, 64);
    ss2 += __shfl_xor(ss2, 1, 64); ss2 += __shfl_xor(ss2, 2, 64);
    {
        float mu = s2 * (1.0f / DD);
        float var = ss2 * (1.0f / DD) - mu * mu;
        float rstd = rsqrtf(var + 1e-5f);
        if (rg < NN) {
            float* op = out + rg * DD + q * 32;
            #pragma unroll
            for (int i = 0; i < 8; ++i) {
                float4 gv = *reinterpret_cast<const float4*>(g2 + q * 32 + i * 4);
                float4 bv = *reinterpret_cast<const float4*>(b2 + q * 32 + i * 4);
                float4 o;
                o.x = (xr[i * 4 + 0] - mu) * rstd * gv.x + bv.x;
                o.y = (xr[i * 4 + 1] - mu) * rstd * gv.y + bv.y;
                o.z = (xr[i * 4 + 2] - mu) * rstd * gv.z + bv.z;
                o.w = (xr[i * 4 + 3] - mu) * rstd * gv.w + bv.w;
                *reinterpret_cast<float4*>(op + i * 4) = o;
            }
        }
    }
}

extern "C" void kernel_launch(void* const* d_in, const int* in_sizes, int n_in,
                              void* d_out, int out_size, void* d_ws, size_t ws_size,
                              hipStream_t stream)
{
    const float* nf  = (const float*)d_in[0];
    const int*   ei  = (const int*)d_in[1];
    const int*   et  = (const int*)d_in[2];
    const float* rel = (const float*)d_in[3];
    const float* mw1 = (const float*)d_in[4];
    const float* mb1 = (const float*)d_in[5];
    const float* mw2 = (const float*)d_in[6];
    const float* mb2 = (const float*)d_in[7];
    const float* aw1 = (const float*)d_in[8];
    const float* ab1 = (const float*)d_in[9];
    const float* aw2 = (const float*)d_in[10];
    const float* ab2 = (const float*)d_in[11];
    const float* g1  = (const float*)d_in[12];
    const float* b1  = (const float*)d_in[13];
    const float* fw1 = (const float*)d_in[14];
    const float* fb1 = (const float*)d_in[15];
    const float* fw2 = (const float*)d_in[16];
    const float* fb2 = (const float*)d_in[17];
    const float* g2  = (const float*)d_in[18];
    const float* b2  = (const float*)d_in[19];
    float* out = (float*)d_out;

    char* ws = (char*)d_ws;
    size_t off = 0;
    auto alloc = [&](size_t bytes) -> char* {
        char* p = ws + off;
        off += (bytes + 255) & ~(size_t)255;
        return p;
    };
    unsigned short* msg = (unsigned short*)alloc((size_t)NE * DD * 2);
    float* attn_raw = (float*)alloc((size_t)NE * 4);
    float* aggr     = (float*)alloc((size_t)NN * DD * 4);
    unsigned short* nfb  = (unsigned short*)alloc((size_t)NN * DD * 2);
    float* relc = (float*)alloc((size_t)RR * DD * 4);
    int* cnt       = (int*)alloc((size_t)NN * 4);
    int* row_start = (int*)alloc((size_t)NN * 4);
    int* cursor    = (int*)alloc((size_t)NN * 4);
    int* eid       = (int*)alloc((size_t)NE * 4);
    int* bsum      = (int*)alloc((size_t)SCAN_NB * 4);
    unsigned short* mw1p = (unsigned short*)alloc(16384 * 2);
    unsigned short* mw2p = (unsigned short*)alloc(16384 * 2);
    unsigned short* awTp = (unsigned short*)alloc(16384 * 2);
    unsigned short* awBp = (unsigned short*)alloc(16384 * 2);
    unsigned short* fw1p = (unsigned short*)alloc(65536 * 2);
    unsigned short* fw2p = (unsigned short*)alloc(65536 * 2);

    // nfa aliases aggr (nfa dead after k_edge; aggr fully overwritten by k_aggr)
    unsigned short* nfa = (unsigned short*)aggr;

    const int* srcp = ei;
    const int* dstp = ei + NE;

    hipLaunchKernelGGL(k_initc, dim3(SCAN_NB), dim3(256), 0, stream, cnt);
    hipLaunchKernelGGL(k_hist, dim3((NE + 255) / 256), dim3(256), 0, stream, dstp, cnt);
    hipLaunchKernelGGL(k_scanA, dim3(SCAN_NB), dim3(256), 0, stream, cnt, bsum);
    hipLaunchKernelGGL(k_scanB, dim3(1), dim3(512), 0, stream, bsum);
    hipLaunchKernelGGL(k_scanC, dim3(SCAN_NB), dim3(256), 0, stream, cnt, bsum, row_start, cursor);
    hipLaunchKernelGGL(k_bucket, dim3((NE + 255) / 256), dim3(256), 0, stream, dstp, cursor, eid);
    hipLaunchKernelGGL(k_prep, dim3(NN * DD / 8 / 256), dim3(256), 0, stream, nf, nfb);
    hipLaunchKernelGGL(k_pack, dim3(768), dim3(256), 0, stream,
                       mw1, mw2, aw1, fw1, fw2, mw1p, mw2p, awTp, awBp, fw1p, fw2p);
    hipLaunchKernelGGL(k_relc, dim3(100), dim3(256), 0, stream, rel, mw1, mb1, relc);
    hipLaunchKernelGGL(k_nfa, dim3((NN + 63) / 64), dim3(256), 0, stream,
                       nfb, awTp, ab1, nfa);
    hipLaunchKernelGGL(k_edge, dim3(NE / 64), dim3(512), 0, stream,
                       nfb, srcp, dstp, et, nfa, relc,
                       mw1p, mw2p, mb2, awBp, aw2, ab2,
                       msg, attn_raw);
    hipLaunchKernelGGL(k_aggr, dim3((NN + 3) / 4), dim3(256), 0, stream,
                       msg, attn_raw, row_start, cnt, eid, aggr);
    hipLaunchKernelGGL(k_node, dim3((NN + 63) / 64), dim3(256), 0, stream,
                       nf, aggr, g1, b1, fw1p, fb1, fw2p, fb2, g2, b2, out);
}

// Round 7
// 482.153 us; speedup vs baseline: 5.7468x; 1.0590x over previous
//
#include <hip/hip_runtime.h>
#include <hip/hip_bf16.h>

#define NN 100000
#define NE 600000
#define DD 128
#define RR 200
#define SCAN_NB ((NN + 255) / 256)   // 391

typedef __attribute__((ext_vector_type(8))) short bf16x8;
typedef __attribute__((ext_vector_type(4))) float f32x4;

__device__ __forceinline__ unsigned int bfbits(float x) {
    return (unsigned int)__builtin_bit_cast(unsigned short, __float2bfloat16(x));
}
__device__ __forceinline__ unsigned int pk2(float a, float b) {
    return bfbits(a) | (bfbits(b) << 16);
}
__device__ __forceinline__ unsigned short bf16s(float x) {
    return __builtin_bit_cast(unsigned short, __float2bfloat16(x));
}
__device__ __forceinline__ float unbf(unsigned short u) {
    return __builtin_bit_cast(float, ((unsigned int)u) << 16);
}
__device__ __forceinline__ float unlo(unsigned int u) {
    return __builtin_bit_cast(float, u << 16);
}
__device__ __forceinline__ float unhi(unsigned int u) {
    return __builtin_bit_cast(float, u & 0xffff0000u);
}

__device__ __forceinline__ void gload_lds16(const void* g, void* l) {
    __builtin_amdgcn_global_load_lds(
        (const __attribute__((address_space(1))) void*)g,
        (__attribute__((address_space(3))) void*)l, 16, 0, 0);
}

// ---------------- zero edge-count histogram ----------------
__global__ void k_initc(int* __restrict__ cnt) {
    int i = blockIdx.x * 256 + threadIdx.x;
    if (i < NN) cnt[i] = 0;
}

// ---------------- histogram of dst ----------------
__global__ void k_hist(const int* __restrict__ dst, int* __restrict__ cnt) {
    int e = blockIdx.x * 256 + threadIdx.x;
    if (e < NE) atomicAdd(&cnt[dst[e]], 1);
}

// ---------------- 3-kernel exclusive scan over cnt[NN] ----------------
__global__ void k_scanA(const int* __restrict__ cnt, int* __restrict__ bsum) {
    __shared__ int red[256];
    int i = blockIdx.x * 256 + threadIdx.x;
    red[threadIdx.x] = (i < NN) ? cnt[i] : 0;
    __syncthreads();
    for (int off = 128; off >= 1; off >>= 1) {
        if (threadIdx.x < off) red[threadIdx.x] += red[threadIdx.x + off];
        __syncthreads();
    }
    if (threadIdx.x == 0) bsum[blockIdx.x] = red[0];
}

__global__ void k_scanB(int* __restrict__ bsum) {
    __shared__ int sh[512];
    int t = threadIdx.x;
    int v = (t < SCAN_NB) ? bsum[t] : 0;
    sh[t] = v;
    __syncthreads();
    for (int off = 1; off < 512; off <<= 1) {
        int add = (t >= off) ? sh[t - off] : 0;
        __syncthreads();
        sh[t] += add;
        __syncthreads();
    }
    if (t < SCAN_NB) bsum[t] = sh[t] - v;   // exclusive
}

__global__ void k_scanC(const int* __restrict__ cnt, const int* __restrict__ bsum,
                        int* __restrict__ row_start, int* __restrict__ cursor) {
    __shared__ int sh[256];
    int i = blockIdx.x * 256 + threadIdx.x;
    int t = threadIdx.x;
    int v = (i < NN) ? cnt[i] : 0;
    sh[t] = v;
    __syncthreads();
    for (int off = 1; off < 256; off <<= 1) {
        int add = (t >= off) ? sh[t - off] : 0;
        __syncthreads();
        sh[t] += add;
        __syncthreads();
    }
    if (i < NN) {
        int ex = bsum[blockIdx.x] + sh[t] - v;
        row_start[i] = ex;
        cursor[i] = ex;
    }
}

// ---------------- bucket: eid_sorted grouped by dst ----------------
__global__ void k_bucket(const int* __restrict__ dst, int* __restrict__ cursor,
                         int* __restrict__ eid) {
    int e = blockIdx.x * 256 + threadIdx.x;
    if (e < NE) {
        int p = atomicAdd(&cursor[dst[e]], 1);
        eid[p] = e;
    }
}

// ---------------- prep: bf16 copy of node features ----------------
__global__ void k_prep(const float* __restrict__ nf, unsigned short* __restrict__ nfb) {
    int i = blockIdx.x * 256 + threadIdx.x;
    if (i >= NN * DD / 8) return;
    const float* sp = nf + (size_t)i * 8;
    float4 f0 = *reinterpret_cast<const float4*>(sp);
    float4 f1 = *reinterpret_cast<const float4*>(sp + 4);
    uint4 v;
    v.x = pk2(f0.x, f0.y); v.y = pk2(f0.z, f0.w);
    v.z = pk2(f1.x, f1.y); v.w = pk2(f1.z, f1.w);
    *reinterpret_cast<uint4*>(nfb + (size_t)i * 8) = v;
}

// ---------------- relcb = bf16(rel @ mw1_bot + mb1), 200x128 ----------------
__global__ void k_relc(const float* __restrict__ rel, const float* __restrict__ mw1,
                       const float* __restrict__ mb1, unsigned short* __restrict__ relcb) {
    int idx = blockIdx.x * 256 + threadIdx.x;
    if (idx >= RR * DD) return;
    int r = idx >> 7, n = idx & 127;
    float s = mb1[n];
    for (int k = 0; k < 128; ++k)
        s = fmaf(rel[r * 128 + k], mw1[(128 + k) * 128 + n], s);
    relcb[idx] = bf16s(s);
}

// ---------------- mwB = mw2 @ aw1_bot; zb = mb2 @ aw1_bot ----------------
__global__ void k_mwb(const float* __restrict__ mw2, const float* __restrict__ mb2,
                      const float* __restrict__ aw1,
                      float* __restrict__ mwB, float* __restrict__ zb) {
    int idx = blockIdx.x * 256 + threadIdx.x;   // 16512
    if (idx < 16384) {
        int k = idx >> 7, n = idx & 127;
        float s = 0.0f;
        for (int j = 0; j < 128; ++j)
            s = fmaf(mw2[k * 128 + j], aw1[(128 + j) * 128 + n], s);
        mwB[idx] = s;
    } else if (idx < 16512) {
        int n = idx - 16384;
        float s = 0.0f;
        for (int j = 0; j < 128; ++j)
            s = fmaf(mb2[j], aw1[(128 + j) * 128 + n], s);
        zb[n] = s;
    }
}

// ---------------- pack weights into MFMA B-fragment order (bf16) ------------
__global__ void k_pack(const float* __restrict__ mw1, const float* __restrict__ mw2,
                       const float* __restrict__ mwB,
                       const float* __restrict__ aw1,
                       const float* __restrict__ fw1, const float* __restrict__ fw2,
                       unsigned short* __restrict__ mw1p,
                       unsigned short* __restrict__ mwCp,
                       unsigned short* __restrict__ awTp,
                       unsigned short* __restrict__ fw1p,
                       unsigned short* __restrict__ fw2p) {
    int idx = blockIdx.x * 256 + threadIdx.x;      // 196608 total
    if (idx < 16384) {            // mw1 TOP half: K=128 (KS=4), N=128
        int i = idx & 7, l = (idx >> 3) & 63, ks = (idx >> 9) & 3, nt = idx >> 11;
        int k = ks * 32 + (l >> 4) * 8 + i, n = nt * 16 + (l & 15);
        mw1p[idx] = bf16s(mw1[k * 128 + n]);
    } else if (idx < 49152) {     // mwC = [mw2 | mwB]: K=128 (KS=4), N=256
        int j = idx - 16384;
        int i = j & 7, l = (j >> 3) & 63, ks = (j >> 9) & 3, nt = j >> 11; // nt 0..15
        int k = ks * 32 + (l >> 4) * 8 + i, n = nt * 16 + (l & 15);
        mwCp[j] = bf16s((n < 128) ? mw2[k * 128 + n] : mwB[k * 128 + (n - 128)]);
    } else if (idx < 65536) {     // aw1 TOP half: K=128, N=128
        int j = idx - 49152;
        int i = j & 7, l = (j >> 3) & 63, ks = (j >> 9) & 3, nt = j >> 11;
        int k = ks * 32 + (l >> 4) * 8 + i, n = nt * 16 + (l & 15);
        awTp[j] = bf16s(aw1[k * 128 + n]);
    } else if (idx < 131072) {    // fw1: K=128 (KS=4), N=512
        int j = idx - 65536;
        int i = j & 7, l = (j >> 3) & 63, ks = (j >> 9) & 3, nt = j >> 11;
        int k = ks * 32 + (l >> 4) * 8 + i, n = nt * 16 + (l & 15);
        fw1p[j] = bf16s(fw1[k * 512 + n]);
    } else if (idx < 196608) {    // fw2: K=512 (KS=16), N=128
        int j = idx - 131072;
        int i = j & 7, l = (j >> 3) & 63, ks = (j >> 9) & 15, nt = j >> 13;
        int k = ks * 32 + (l >> 4) * 8 + i, n = nt * 16 + (l & 15);
        fw2p[j] = bf16s(fw2[k * 128 + n]);
    }
}

// ---------------- nfa = nf @ aw1_top + ab1 (bf16, MFMA) ----------------
__global__ __launch_bounds__(256) void k_nfa(
    const unsigned short* __restrict__ nfb, const unsigned short* __restrict__ awTp,
    const float* __restrict__ ab1, unsigned short* __restrict__ nfa)
{
    __shared__ alignas(16) unsigned short XB[64 * 128]; // 16 KB
    const int t = threadIdx.x;
    const int w = t >> 6, l = t & 63;
    const int wm = w >> 1, wn = w & 1;
    const int lm = l & 15, lk = l >> 4;
    const int lrow = l >> 4, lslot = l & 15;
    const int n0 = blockIdx.x * 64;

    #pragma unroll
    for (int it = 0; it < 4; ++it) {
        int rb = w * 16 + it * 4;
        int row = rb + lrow;
        long grow = n0 + row; if (grow >= NN) grow = NN - 1;
        int c = lslot ^ (row & 7);
        gload_lds16(nfb + grow * DD + c * 8, &XB[rb * 128]);
    }
    __syncthreads();

    f32x4 acc[2][4];
    #pragma unroll
    for (int mf = 0; mf < 2; ++mf)
        #pragma unroll
        for (int nfr = 0; nfr < 4; ++nfr) acc[mf][nfr] = (f32x4){0.f, 0.f, 0.f, 0.f};

    #pragma unroll
    for (int ks = 0; ks < 4; ++ks) {
        bf16x8 a[2];
        #pragma unroll
        for (int mf = 0; mf < 2; ++mf) {
            int m = wm * 32 + mf * 16 + lm;
            int slot = (ks * 4 + lk) ^ (m & 7);
            a[mf] = *reinterpret_cast<const bf16x8*>(&XB[m * 128 + slot * 8]);
        }
        #pragma unroll
        for (int nfr = 0; nfr < 4; ++nfr) {
            int nt = wn * 4 + nfr;
            bf16x8 b = *reinterpret_cast<const bf16x8*>(&awTp[((nt * 4 + ks) * 64 + l) * 8]);
            acc[0][nfr] = __builtin_amdgcn_mfma_f32_16x16x32_bf16(a[0], b, acc[0][nfr], 0, 0, 0);
            acc[1][nfr] = __builtin_amdgcn_mfma_f32_16x16x32_bf16(a[1], b, acc[1][nfr], 0, 0, 0);
        }
    }
    __syncthreads();

    #pragma unroll
    for (int nfr = 0; nfr < 4; ++nfr) {
        int n = wn * 64 + nfr * 16 + lm;
        float bv = ab1[n];
        #pragma unroll
        for (int mf = 0; mf < 2; ++mf)
            #pragma unroll
            for (int r = 0; r < 4; ++r) {
                int m = wm * 32 + mf * 16 + lk * 4 + r;
                XB[m * 128 + n] = bf16s(acc[mf][nfr][r] + bv);
            }
    }
    __syncthreads();

    #pragma unroll
    for (int j = 0; j < 4; ++j) {
        int q = j * 256 + t;
        int row = q >> 4, c16 = q & 15;
        if (n0 + row < NN)
            *reinterpret_cast<uint4*>(&nfa[(size_t)(n0 + row) * DD + c16 * 8]) =
                *reinterpret_cast<const uint4*>(&XB[row * 128 + c16 * 8]);
    }
}

// ---------------- edge kernel: 2 MFMA GEMMs (merged msg+logit) --------------
// block = 512 thr (8 waves, wm=w>>2, wn=w&3), 64 edges/block.
__global__ __launch_bounds__(512) void k_edge(
    const unsigned short* __restrict__ nfb, const int* __restrict__ src,
    const int* __restrict__ dst, const int* __restrict__ etype,
    const unsigned short* __restrict__ nfa, const unsigned short* __restrict__ relcb,
    const unsigned short* __restrict__ mw1p, const unsigned short* __restrict__ mwCp,
    const float* __restrict__ mb2, const float* __restrict__ zb,
    const float* __restrict__ aw2, const float* __restrict__ ab2,
    unsigned short* __restrict__ msg_out, float* __restrict__ attn_raw)
{
    __shared__ alignas(16) unsigned short S[64 * 128];  // src rows, then nfa[dst]
    __shared__ alignas(16) unsigned short H[64 * 128];  // hidden
    __shared__ alignas(16) unsigned short MS[64 * 128]; // relc rows, then msg
    __shared__ float RED[64][2];

    const int t = threadIdx.x;
    const int w = t >> 6, l = t & 63;
    const int wm = w >> 2, wn = w & 3;
    const int lm = l & 15, lk = l >> 4;
    const int lrow = l >> 4, lslot = l & 15;
    const int e0 = blockIdx.x * 64;

    // ---- phase 0: S <- nfb[src], MS <- relcb[etype] (swizzled source) ----
    #pragma unroll
    for (int it = 0; it < 2; ++it) {
        int rb = w * 8 + it * 4;
        int row = rb + lrow;
        int c = lslot ^ (row & 7);
        gload_lds16(nfb + (size_t)src[e0 + row] * DD + c * 8, &S[rb * 128]);
    }
    #pragma unroll
    for (int it = 0; it < 2; ++it) {
        int rb = w * 8 + it * 4;
        int row = rb + lrow;
        int c = lslot ^ (row & 7);
        gload_lds16(relcb + (size_t)etype[e0 + row] * DD + c * 8, &MS[rb * 128]);
    }
    __syncthreads();

    // ---- GEMM1: hidden = relu(src @ mw1_top + relc[etype]), K=128 ----
    {
        f32x4 acc[2][2];
        #pragma unroll
        for (int mf = 0; mf < 2; ++mf)
            #pragma unroll
            for (int nfr = 0; nfr < 2; ++nfr) acc[mf][nfr] = (f32x4){0.f, 0.f, 0.f, 0.f};

        #pragma unroll
        for (int ks = 0; ks < 4; ++ks) {
            bf16x8 a[2];
            #pragma unroll
            for (int mf = 0; mf < 2; ++mf) {
                int m = wm * 32 + mf * 16 + lm;
                int slot = (ks * 4 + lk) ^ (m & 7);
                a[mf] = *reinterpret_cast<const bf16x8*>(&S[m * 128 + slot * 8]);
            }
            #pragma unroll
            for (int nfr = 0; nfr < 2; ++nfr) {
                int nt = wn * 2 + nfr;
                bf16x8 b = *reinterpret_cast<const bf16x8*>(&mw1p[((nt * 4 + ks) * 64 + l) * 8]);
                acc[0][nfr] = __builtin_amdgcn_mfma_f32_16x16x32_bf16(a[0], b, acc[0][nfr], 0, 0, 0);
                acc[1][nfr] = __builtin_amdgcn_mfma_f32_16x16x32_bf16(a[1], b, acc[1][nfr], 0, 0, 0);
            }
        }
        #pragma unroll
        for (int nfr = 0; nfr < 2; ++nfr) {
            int n = (wn * 2 + nfr) * 16 + lm;
            #pragma unroll
            for (int mf = 0; mf < 2; ++mf)
                #pragma unroll
                for (int r = 0; r < 4; ++r) {
                    int m = wm * 32 + mf * 16 + lk * 4 + r;
                    float v = acc[mf][nfr][r] + unbf(MS[m * 128 + ((n >> 3) ^ (m & 7)) * 8 + (n & 7)]);
                    v = fmaxf(v, 0.0f);
                    H[m * 128 + ((n >> 3) ^ (m & 7)) * 8 + (n & 7)] = bf16s(v);
                }
        }
    }
    __syncthreads(); // H ready; S & MS reads done

    // ---- phase 2: S <- nfa[dst] (overlaps GEMM2) ----
    #pragma unroll
    for (int it = 0; it < 2; ++it) {
        int rb = w * 8 + it * 4;
        int row = rb + lrow;
        int c = lslot ^ (row & 7);
        gload_lds16(nfa + (size_t)dst[e0 + row] * DD + c * 8, &S[rb * 128]);
    }

    // ---- GEMM2': [msg | zpre] = H @ mwC, K=128, N=256 ----
    f32x4 acc[2][4];
    #pragma unroll
    for (int mf = 0; mf < 2; ++mf)
        #pragma unroll
        for (int nfr = 0; nfr < 4; ++nfr) acc[mf][nfr] = (f32x4){0.f, 0.f, 0.f, 0.f};

    #pragma unroll
    for (int ks = 0; ks < 4; ++ks) {
        bf16x8 a[2];
        #pragma unroll
        for (int mf = 0; mf < 2; ++mf) {
            int m = wm * 32 + mf * 16 + lm;
            int slot = (ks * 4 + lk) ^ (m & 7);
            a[mf] = *reinterpret_cast<const bf16x8*>(&H[m * 128 + slot * 8]);
        }
        #pragma unroll
        for (int nfr = 0; nfr < 4; ++nfr) {
            int nt = wn * 4 + nfr;   // 0..15 over N=256
            bf16x8 b = *reinterpret_cast<const bf16x8*>(&mwCp[((nt * 4 + ks) * 64 + l) * 8]);
            acc[0][nfr] = __builtin_amdgcn_mfma_f32_16x16x32_bf16(a[0], b, acc[0][nfr], 0, 0, 0);
            acc[1][nfr] = __builtin_amdgcn_mfma_f32_16x16x32_bf16(a[1], b, acc[1][nfr], 0, 0, 0);
        }
    }
    __syncthreads(); // S (nfa) staged; MS relc reads done (pre-GEMM1-sync)

    if (wn < 2) {
        // ---- msg half: cols 0..127 -> MS (swizzled) ----
        #pragma unroll
        for (int nfr = 0; nfr < 4; ++nfr) {
            int n = (wn * 4 + nfr) * 16 + lm;
            float bv = mb2[n];
            #pragma unroll
            for (int mf = 0; mf < 2; ++mf)
                #pragma unroll
                for (int r = 0; r < 4; ++r) {
                    int m = wm * 32 + mf * 16 + lk * 4 + r;
                    MS[m * 128 + ((n >> 3) ^ (m & 7)) * 8 + (n & 7)] = bf16s(acc[mf][nfr][r] + bv);
                }
        }
    } else {
        // ---- z half: z = zpre + zb + nfa[dst]; leaky; dot aw2 ----
        float zbv[4], aw2v[4];
        #pragma unroll
        for (int nfr = 0; nfr < 4; ++nfr) {
            int nc = (wn - 2) * 64 + nfr * 16 + lm;
            zbv[nfr] = zb[nc];
            aw2v[nfr] = aw2[nc];
        }
        #pragma unroll
        for (int mf = 0; mf < 2; ++mf)
            #pragma unroll
            for (int r = 0; r < 4; ++r) {
                int m = wm * 32 + mf * 16 + lk * 4 + r;
                float s = 0.0f;
                #pragma unroll
                for (int nfr = 0; nfr < 4; ++nfr) {
                    int nc = (wn - 2) * 64 + nfr * 16 + lm;
                    float v = acc[mf][nfr][r] + zbv[nfr]
                            + unbf(S[m * 128 + ((nc >> 3) ^ (m & 7)) * 8 + (nc & 7)]);
                    v = (v > 0.0f) ? v : 0.2f * v;
                    s = fmaf(v, aw2v[nfr], s);
                }
                s += __shfl_xor(s, 1, 64);
                s += __shfl_xor(s, 2, 64);
                s += __shfl_xor(s, 4, 64);
                s += __shfl_xor(s, 8, 64);
                if (lm == 0) RED[m][wn - 2] = s;
            }
    }
    __syncthreads();

    // ---- copy msg -> global; logits -> global ----
    #pragma unroll
    for (int j = 0; j < 2; ++j) {
        int q = j * 512 + t;
        int row = q >> 4, c16 = q & 15;
        int slot = c16 ^ (row & 7);
        *reinterpret_cast<uint4*>(&msg_out[(size_t)(e0 + row) * DD + c16 * 8]) =
            *reinterpret_cast<const uint4*>(&MS[row * 128 + slot * 8]);
    }
    if (t < 64) {
        attn_raw[e0 + t] = RED[t][0] + RED[t][1] + ab2[0];
    }
}

// ---------------- fused per-node softmax + weighted aggregate ---------------
__global__ __launch_bounds__(256) void k_aggr(
    const unsigned short* __restrict__ msg, const float* __restrict__ raw,
    const int* __restrict__ row_start, const int* __restrict__ cnt,
    const int* __restrict__ eid, float* __restrict__ aggr)
{
    const int l = threadIdx.x & 63;
    const int n = blockIdx.x * 4 + (threadIdx.x >> 6);
    if (n >= NN) return;
    const int rs = row_start[n], deg = cnt[n];

    float m = -INFINITY;
    for (int j = l; j < deg; j += 64) m = fmaxf(m, raw[eid[rs + j]]);
    #pragma unroll
    for (int off = 32; off >= 1; off >>= 1) m = fmaxf(m, __shfl_xor(m, off, 64));

    float s = 0.0f;
    for (int j = l; j < deg; j += 64) s += expf(raw[eid[rs + j]] - m);
    #pragma unroll
    for (int off = 32; off >= 1; off >>= 1) s += __shfl_xor(s, off, 64);
    const float rinv = 1.0f / (s + 1e-8f);

    float a0 = 0.0f, a1 = 0.0f;
    for (int base = 0; base < deg; base += 64) {
        int nt = min(64, deg - base);
        int e_l = 0; float w_l = 0.0f;
        if (l < nt) {
            e_l = eid[rs + base + l];
            w_l = expf(raw[e_l] - m) * rinv;
        }
        for (int j = 0; j < nt; ++j) {
            int e = __shfl(e_l, j, 64);
            float w = __shfl(w_l, j, 64);
            unsigned int v = *reinterpret_cast<const unsigned int*>(&msg[(size_t)e * DD + l * 2]);
            a0 = fmaf(w, unlo(v), a0);
            a1 = fmaf(w, unhi(v), a1);
        }
    }
    float2 o = {a0, a1};
    *reinterpret_cast<float2*>(&aggr[(size_t)n * DD + l * 2]) = o;
}

// ---------------- node kernel: LN1 + MFMA FFN + LN2 (8 waves) ----------------
__global__ __launch_bounds__(512) void k_node(
    const float* __restrict__ nf, const float* __restrict__ aggr,
    const float* __restrict__ g1, const float* __restrict__ b1,
    const unsigned short* __restrict__ fw1p, const float* __restrict__ fb1,
    const unsigned short* __restrict__ fw2p, const float* __restrict__ fb2,
    const float* __restrict__ g2, const float* __restrict__ b2,
    float* __restrict__ out)
{
    __shared__ alignas(16) unsigned short XB[64 * 128]; // 16 KB
    __shared__ alignas(16) unsigned short HB[64 * 256]; // 32 KB

    const int t = threadIdx.x;
    const int w = t >> 6, l = t & 63;
    const int wm = w >> 2, wn = w & 3;
    const int lm = l & 15, lk = l >> 4;
    const int row = t >> 3;      // 0..63
    const int q = t & 7;         // 16-col segment
    const long n0 = (long)blockIdx.x * 64;
    const long rg = n0 + row;
    const long rc = (rg < NN) ? rg : (NN - 1);

    // ---- LN1 ----
    float xr[16];
    float s = 0.0f, ss = 0.0f;
    {
        const float* xp = nf + rc * DD + q * 16;
        const float* ap = aggr + rc * DD + q * 16;
        #pragma unroll
        for (int i = 0; i < 4; ++i) {
            float4 a = *reinterpret_cast<const float4*>(xp + i * 4);
            float4 b = *reinterpret_cast<const float4*>(ap + i * 4);
            float v0 = a.x + b.x, v1 = a.y + b.y, v2 = a.z + b.z, v3 = a.w + b.w;
            xr[i * 4 + 0] = v0; xr[i * 4 + 1] = v1; xr[i * 4 + 2] = v2; xr[i * 4 + 3] = v3;
            s += v0 + v1 + v2 + v3;
            ss = fmaf(v0, v0, ss); ss = fmaf(v1, v1, ss);
            ss = fmaf(v2, v2, ss); ss = fmaf(v3, v3, ss);
        }
    }
    s  += __shfl_xor(s, 1, 64);  s  += __shfl_xor(s, 2, 64);  s  += __shfl_xor(s, 4, 64);
    ss += __shfl_xor(ss, 1, 64); ss += __shfl_xor(ss, 2, 64); ss += __shfl_xor(ss, 4, 64);
    {
        float mu = s * (1.0f / DD);
        float var = ss * (1.0f / DD) - mu * mu;
        float rstd = rsqrtf(var + 1e-5f);
        #pragma unroll
        for (int i = 0; i < 4; ++i) {
            float4 gv = *reinterpret_cast<const float4*>(g1 + q * 16 + i * 4);
            float4 bv = *reinterpret_cast<const float4*>(b1 + q * 16 + i * 4);
            xr[i * 4 + 0] = (xr[i * 4 + 0] - mu) * rstd * gv.x + bv.x;
            xr[i * 4 + 1] = (xr[i * 4 + 1] - mu) * rstd * gv.y + bv.y;
            xr[i * 4 + 2] = (xr[i * 4 + 2] - mu) * rstd * gv.z + bv.z;
            xr[i * 4 + 3] = (xr[i * 4 + 3] - mu) * rstd * gv.w + bv.w;
        }
        #pragma unroll
        for (int i = 0; i < 2; ++i) {
            int c = q * 2 + i, slot = c ^ (row & 7);
            uint4 v;
            v.x = pk2(xr[i * 8 + 0], xr[i * 8 + 1]);
            v.y = pk2(xr[i * 8 + 2], xr[i * 8 + 3]);
            v.z = pk2(xr[i * 8 + 4], xr[i * 8 + 5]);
            v.w = pk2(xr[i * 8 + 6], xr[i * 8 + 7]);
            *reinterpret_cast<uint4*>(&XB[row * 128 + slot * 8]) = v;
        }
    }
    __syncthreads();

    // ---- FFN: two 256-col halves ----
    f32x4 acc2[2][2];
    #pragma unroll
    for (int mf = 0; mf < 2; ++mf)
        #pragma unroll
        for (int nfr = 0; nfr < 2; ++nfr) acc2[mf][nfr] = (f32x4){0.f, 0.f, 0.f, 0.f};

    #pragma unroll
    for (int half = 0; half < 2; ++half) {
        f32x4 acc[2][4];
        #pragma unroll
        for (int mf = 0; mf < 2; ++mf)
            #pragma unroll
            for (int nfr = 0; nfr < 4; ++nfr) acc[mf][nfr] = (f32x4){0.f, 0.f, 0.f, 0.f};

        #pragma unroll
        for (int ks = 0; ks < 4; ++ks) {
            bf16x8 a[2];
            #pragma unroll
            for (int mf = 0; mf < 2; ++mf) {
                int m = wm * 32 + mf * 16 + lm;
                int slot = (ks * 4 + lk) ^ (m & 7);
                a[mf] = *reinterpret_cast<const bf16x8*>(&XB[m * 128 + slot * 8]);
            }
            #pragma unroll
            for (int nfr = 0; nfr < 4; ++nfr) {
                int nt = half * 16 + wn * 4 + nfr;
                bf16x8 b = *reinterpret_cast<const bf16x8*>(&fw1p[((nt * 4 + ks) * 64 + l) * 8]);
                acc[0][nfr] = __builtin_amdgcn_mfma_f32_16x16x32_bf16(a[0], b, acc[0][nfr], 0, 0, 0);
                acc[1][nfr] = __builtin_amdgcn_mfma_f32_16x16x32_bf16(a[1], b, acc[1][nfr], 0, 0, 0);
            }
        }
        #pragma unroll
        for (int nfr = 0; nfr < 4; ++nfr) {
            int nl = (wn * 4 + nfr) * 16 + lm;   // col within half (0..255)
            float bv = fb1[half * 256 + nl];
            #pragma unroll
            for (int mf = 0; mf < 2; ++mf)
                #pragma unroll
                for (int r = 0; r < 4; ++r) {
                    int m = wm * 32 + mf * 16 + lk * 4 + r;
                    float h = acc[mf][nfr][r] + bv;
                    float e = __expf(h * -1.702f);
                    float gvv = h * __builtin_amdgcn_rcpf(1.0f + e);
                    HB[m * 256 + (((nl >> 3) ^ (m & 7)) * 8) + (nl & 7)] = bf16s(gvv);
                }
        }
        __syncthreads();

        #pragma unroll
        for (int ks = 0; ks < 8; ++ks) {
            bf16x8 a[2];
            #pragma unroll
            for (int mf = 0; mf < 2; ++mf) {
                int m = wm * 32 + mf * 16 + lm;
                int slot = (ks * 4 + lk) ^ (m & 7);
                a[mf] = *reinterpret_cast<const bf16x8*>(&HB[m * 256 + slot * 8]);
            }
            #pragma unroll
            for (int nfr = 0; nfr < 2; ++nfr) {
                int nt = wn * 2 + nfr;
                int kg = half * 8 + ks;
                bf16x8 b = *reinterpret_cast<const bf16x8*>(&fw2p[((nt * 16 + kg) * 64 + l) * 8]);
                acc2[0][nfr] = __builtin_amdgcn_mfma_f32_16x16x32_bf16(a[0], b, acc2[0][nfr], 0, 0, 0);
                acc2[1][nfr] = __builtin_amdgcn_mfma_f32_16x16x32_bf16(a[1], b, acc2[1][nfr], 0, 0, 0);
            }
        }
        __syncthreads();
    }

    // ---- ffn -> XB (bf16) ----
    #pragma unroll
    for (int nfr = 0; nfr < 2; ++nfr) {
        int n = (wn * 2 + nfr) * 16 + lm;
        float bv = fb2[n];
        #pragma unroll
        for (int mf = 0; mf < 2; ++mf)
            #pragma unroll
            for (int r = 0; r < 4; ++r) {
                int m = wm * 32 + mf * 16 + lk * 4 + r;
                XB[m * 128 + (((n >> 3) ^ (m & 7)) * 8) + (n & 7)] = bf16s(acc2[mf][nfr][r] + bv);
            }
    }
    __syncthreads();

    // ---- residual + LN2 ----
    float s2 = 0.0f, ss2 = 0.0f;
    #pragma unroll
    for (int i = 0; i < 2; ++i) {
        int c = q * 2 + i, slot = c ^ (row & 7);
        uint4 v = *reinterpret_cast<const uint4*>(&XB[row * 128 + slot * 8]);
        float f[8];
        f[0] = unlo(v.x); f[1] = unhi(v.x); f[2] = unlo(v.y); f[3] = unhi(v.y);
        f[4] = unlo(v.z); f[5] = unhi(v.z); f[6] = unlo(v.w); f[7] = unhi(v.w);
        #pragma unroll
        for (int j = 0; j < 8; ++j) {
            float vv = xr[i * 8 + j] + f[j];
            xr[i * 8 + j] = vv;
            s2 += vv;
            ss2 = fmaf(vv, vv, ss2);
        }
    }
    s2  += __shfl_xor(s2, 1, 64);  s2  += __shfl_xor(s2, 2, 64);  s2  += __shfl_xor(s2, 4, 64);
    ss2 += __shfl_xor(ss2, 1, 64); ss2 += __shfl_xor(ss2, 2, 64); ss2 += __shfl_xor(ss2, 4, 64);
    {
        float mu = s2 * (1.0f / DD);
        float var = ss2 * (1.0f / DD) - mu * mu;
        float rstd = rsqrtf(var + 1e-5f);
        if (rg < NN) {
            float* op = out + rg * DD + q * 16;
            #pragma unroll
            for (int i = 0; i < 4; ++i) {
                float4 gv = *reinterpret_cast<const float4*>(g2 + q * 16 + i * 4);
                float4 bv = *reinterpret_cast<const float4*>(b2 + q * 16 + i * 4);
                float4 o;
                o.x = (xr[i * 4 + 0] - mu) * rstd * gv.x + bv.x;
                o.y = (xr[i * 4 + 1] - mu) * rstd * gv.y + bv.y;
                o.z = (xr[i * 4 + 2] - mu) * rstd * gv.z + bv.z;
                o.w = (xr[i * 4 + 3] - mu) * rstd * gv.w + bv.w;
                *reinterpret_cast<float4*>(op + i * 4) = o;
            }
        }
    }
}

extern "C" void kernel_launch(void* const* d_in, const int* in_sizes, int n_in,
                              void* d_out, int out_size, void* d_ws, size_t ws_size,
                              hipStream_t stream)
{
    const float* nf  = (const float*)d_in[0];
    const int*   ei  = (const int*)d_in[1];
    const int*   et  = (const int*)d_in[2];
    const float* rel = (const float*)d_in[3];
    const float* mw1 = (const float*)d_in[4];
    const float* mb1 = (const float*)d_in[5];
    const float* mw2 = (const float*)d_in[6];
    const float* mb2 = (const float*)d_in[7];
    const float* aw1 = (const float*)d_in[8];
    const float* ab1 = (const float*)d_in[9];
    const float* aw2 = (const float*)d_in[10];
    const float* ab2 = (const float*)d_in[11];
    const float* g1  = (const float*)d_in[12];
    const float* b1  = (const float*)d_in[13];
    const float* fw1 = (const float*)d_in[14];
    const float* fb1 = (const float*)d_in[15];
    const float* fw2 = (const float*)d_in[16];
    const float* fb2 = (const float*)d_in[17];
    const float* g2  = (const float*)d_in[18];
    const float* b2  = (const float*)d_in[19];
    float* out = (float*)d_out;

    char* ws = (char*)d_ws;
    size_t off = 0;
    auto alloc = [&](size_t bytes) -> char* {
        char* p = ws + off;
        off += (bytes + 255) & ~(size_t)255;
        return p;
    };
    unsigned short* msg = (unsigned short*)alloc((size_t)NE * DD * 2);
    float* attn_raw = (float*)alloc((size_t)NE * 4);
    float* aggr     = (float*)alloc((size_t)NN * DD * 4);
    unsigned short* nfb  = (unsigned short*)alloc((size_t)NN * DD * 2);
    unsigned short* relcb = (unsigned short*)alloc((size_t)RR * DD * 2);
    float* mwB = (float*)alloc((size_t)16384 * 4);
    float* zb  = (float*)alloc((size_t)128 * 4);
    int* cnt       = (int*)alloc((size_t)NN * 4);
    int* row_start = (int*)alloc((size_t)NN * 4);
    int* cursor    = (int*)alloc((size_t)NN * 4);
    int* eid       = (int*)alloc((size_t)NE * 4);
    int* bsum      = (int*)alloc((size_t)SCAN_NB * 4);
    unsigned short* mw1p = (unsigned short*)alloc(16384 * 2);
    unsigned short* mwCp = (unsigned short*)alloc(32768 * 2);
    unsigned short* awTp = (unsigned short*)alloc(16384 * 2);
    unsigned short* fw1p = (unsigned short*)alloc(65536 * 2);
    unsigned short* fw2p = (unsigned short*)alloc(65536 * 2);

    // nfa aliases aggr (nfa dead after k_edge; aggr fully overwritten by k_aggr)
    unsigned short* nfa = (unsigned short*)aggr;

    const int* srcp = ei;
    const int* dstp = ei + NE;

    hipLaunchKernelGGL(k_initc, dim3(SCAN_NB), dim3(256), 0, stream, cnt);
    hipLaunchKernelGGL(k_hist, dim3((NE + 255) / 256), dim3(256), 0, stream, dstp, cnt);
    hipLaunchKernelGGL(k_scanA, dim3(SCAN_NB), dim3(256), 0, stream, cnt, bsum);
    hipLaunchKernelGGL(k_scanB, dim3(1), dim3(512), 0, stream, bsum);
    hipLaunchKernelGGL(k_scanC, dim3(SCAN_NB), dim3(256), 0, stream, cnt, bsum, row_start, cursor);
    hipLaunchKernelGGL(k_bucket, dim3((NE + 255) / 256), dim3(256), 0, stream, dstp, cursor, eid);
    hipLaunchKernelGGL(k_prep, dim3(NN * DD / 8 / 256), dim3(256), 0, stream, nf, nfb);
    hipLaunchKernelGGL(k_mwb, dim3(65), dim3(256), 0, stream, mw2, mb2, aw1, mwB, zb);
    hipLaunchKernelGGL(k_pack, dim3(768), dim3(256), 0, stream,
                       mw1, mw2, mwB, aw1, fw1, fw2, mw1p, mwCp, awTp, fw1p, fw2p);
    hipLaunchKernelGGL(k_relc, dim3(100), dim3(256), 0, stream, rel, mw1, mb1, relcb);
    hipLaunchKernelGGL(k_nfa, dim3((NN + 63) / 64), dim3(256), 0, stream,
                       nfb, awTp, ab1, nfa);
    hipLaunchKernelGGL(k_edge, dim3(NE / 64), dim3(512), 0, stream,
                       nfb, srcp, dstp, et, nfa, relcb,
                       mw1p, mwCp, mb2, zb, aw2, ab2,
                       msg, attn_raw);
    hipLaunchKernelGGL(k_aggr, dim3((NN + 3) / 4), dim3(256), 0, stream,
                       msg, attn_raw, row_start, cnt, eid, aggr);
    hipLaunchKernelGGL(k_node, dim3((NN + 63) / 64), dim3(512), 0, stream,
                       nf, aggr, g1, b1, fw1p, fb1, fw2p, fb2, g2, b2, out);
}

// Round 8
// 471.649 us; speedup vs baseline: 5.8748x; 1.0223x over previous
//
#include <hip/hip_runtime.h>
#include <hip/hip_bf16.h>

#define NN 100000
#define NE 600000
#define DD 128
#define RR 200
#define SCAN_NB ((NN + 255) / 256)   // 391

typedef __attribute__((ext_vector_type(8))) short bf16x8;
typedef __attribute__((ext_vector_type(4))) float f32x4;

__device__ __forceinline__ unsigned int bfbits(float x) {
    return (unsigned int)__builtin_bit_cast(unsigned short, __float2bfloat16(x));
}
__device__ __forceinline__ unsigned int pk2(float a, float b) {
    return bfbits(a) | (bfbits(b) << 16);
}
__device__ __forceinline__ unsigned short bf16s(float x) {
    return __builtin_bit_cast(unsigned short, __float2bfloat16(x));
}
__device__ __forceinline__ float unbf(unsigned short u) {
    return __builtin_bit_cast(float, ((unsigned int)u) << 16);
}
__device__ __forceinline__ float unlo(unsigned int u) {
    return __builtin_bit_cast(float, u << 16);
}
__device__ __forceinline__ float unhi(unsigned int u) {
    return __builtin_bit_cast(float, u & 0xffff0000u);
}

__device__ __forceinline__ void gload_lds16(const void* g, void* l) {
    __builtin_amdgcn_global_load_lds(
        (const __attribute__((address_space(1))) void*)g,
        (__attribute__((address_space(3))) void*)l, 16, 0, 0);
}

// ---------------- zero edge-count histogram ----------------
__global__ void k_initc(int* __restrict__ cnt) {
    int i = blockIdx.x * 256 + threadIdx.x;
    if (i < NN) cnt[i] = 0;
}

// ---------------- histogram of dst ----------------
__global__ void k_hist(const int* __restrict__ dst, int* __restrict__ cnt) {
    int e = blockIdx.x * 256 + threadIdx.x;
    if (e < NE) atomicAdd(&cnt[dst[e]], 1);
}

// ---------------- 3-kernel exclusive scan over cnt[NN] ----------------
__global__ void k_scanA(const int* __restrict__ cnt, int* __restrict__ bsum) {
    __shared__ int red[256];
    int i = blockIdx.x * 256 + threadIdx.x;
    red[threadIdx.x] = (i < NN) ? cnt[i] : 0;
    __syncthreads();
    for (int off = 128; off >= 1; off >>= 1) {
        if (threadIdx.x < off) red[threadIdx.x] += red[threadIdx.x + off];
        __syncthreads();
    }
    if (threadIdx.x == 0) bsum[blockIdx.x] = red[0];
}

__global__ void k_scanB(int* __restrict__ bsum) {
    __shared__ int sh[512];
    int t = threadIdx.x;
    int v = (t < SCAN_NB) ? bsum[t] : 0;
    sh[t] = v;
    __syncthreads();
    for (int off = 1; off < 512; off <<= 1) {
        int add = (t >= off) ? sh[t - off] : 0;
        __syncthreads();
        sh[t] += add;
        __syncthreads();
    }
    if (t < SCAN_NB) bsum[t] = sh[t] - v;   // exclusive
}

__global__ void k_scanC(const int* __restrict__ cnt, const int* __restrict__ bsum,
                        int* __restrict__ row_start, int* __restrict__ cursor) {
    __shared__ int sh[256];
    int i = blockIdx.x * 256 + threadIdx.x;
    int t = threadIdx.x;
    int v = (i < NN) ? cnt[i] : 0;
    sh[t] = v;
    __syncthreads();
    for (int off = 1; off < 256; off <<= 1) {
        int add = (t >= off) ? sh[t - off] : 0;
        __syncthreads();
        sh[t] += add;
        __syncthreads();
    }
    if (i < NN) {
        int ex = bsum[blockIdx.x] + sh[t] - v;
        row_start[i] = ex;
        cursor[i] = ex;
    }
}

// ---------------- bucket: permuted src/etype/dst grouped by dst ----------------
__global__ void k_bucket(const int* __restrict__ src, const int* __restrict__ dst,
                         const int* __restrict__ etype, int* __restrict__ cursor,
                         int* __restrict__ srcs, int* __restrict__ ets,
                         int* __restrict__ dsts) {
    int e = blockIdx.x * 256 + threadIdx.x;
    if (e < NE) {
        int d = dst[e];
        int p = atomicAdd(&cursor[d], 1);
        srcs[p] = src[e];
        ets[p]  = etype[e];
        dsts[p] = d;
    }
}

// ---------------- prep: bf16 copy of node features ----------------
__global__ void k_prep(const float* __restrict__ nf, unsigned short* __restrict__ nfb) {
    int i = blockIdx.x * 256 + threadIdx.x;
    if (i >= NN * DD / 8) return;
    const float* sp = nf + (size_t)i * 8;
    float4 f0 = *reinterpret_cast<const float4*>(sp);
    float4 f1 = *reinterpret_cast<const float4*>(sp + 4);
    uint4 v;
    v.x = pk2(f0.x, f0.y); v.y = pk2(f0.z, f0.w);
    v.z = pk2(f1.x, f1.y); v.w = pk2(f1.z, f1.w);
    *reinterpret_cast<uint4*>(nfb + (size_t)i * 8) = v;
}

// ---------------- relcb = bf16(rel @ mw1_bot + mb1), 200x128 ----------------
__global__ void k_relc(const float* __restrict__ rel, const float* __restrict__ mw1,
                       const float* __restrict__ mb1, unsigned short* __restrict__ relcb) {
    int idx = blockIdx.x * 256 + threadIdx.x;
    if (idx >= RR * DD) return;
    int r = idx >> 7, n = idx & 127;
    float s = mb1[n];
    for (int k = 0; k < 128; ++k)
        s = fmaf(rel[r * 128 + k], mw1[(128 + k) * 128 + n], s);
    relcb[idx] = bf16s(s);
}

// ---------------- mwB = mw2 @ aw1_bot; zb = mb2 @ aw1_bot ----------------
__global__ void k_mwb(const float* __restrict__ mw2, const float* __restrict__ mb2,
                      const float* __restrict__ aw1,
                      float* __restrict__ mwB, float* __restrict__ zb) {
    int idx = blockIdx.x * 256 + threadIdx.x;   // 16512
    if (idx < 16384) {
        int k = idx >> 7, n = idx & 127;
        float s = 0.0f;
        for (int j = 0; j < 128; ++j)
            s = fmaf(mw2[k * 128 + j], aw1[(128 + j) * 128 + n], s);
        mwB[idx] = s;
    } else if (idx < 16512) {
        int n = idx - 16384;
        float s = 0.0f;
        for (int j = 0; j < 128; ++j)
            s = fmaf(mb2[j], aw1[(128 + j) * 128 + n], s);
        zb[n] = s;
    }
}

// ---------------- pack weights into MFMA B-fragment order (bf16) ------------
__global__ void k_pack(const float* __restrict__ mw1, const float* __restrict__ mw2,
                       const float* __restrict__ mwB,
                       const float* __restrict__ aw1,
                       const float* __restrict__ fw1, const float* __restrict__ fw2,
                       unsigned short* __restrict__ mw1p,
                       unsigned short* __restrict__ mwCp,
                       unsigned short* __restrict__ awTp,
                       unsigned short* __restrict__ fw1p,
                       unsigned short* __restrict__ fw2p) {
    int idx = blockIdx.x * 256 + threadIdx.x;      // 196608 total
    if (idx < 16384) {            // mw1 TOP half: K=128 (KS=4), N=128
        int i = idx & 7, l = (idx >> 3) & 63, ks = (idx >> 9) & 3, nt = idx >> 11;
        int k = ks * 32 + (l >> 4) * 8 + i, n = nt * 16 + (l & 15);
        mw1p[idx] = bf16s(mw1[k * 128 + n]);
    } else if (idx < 49152) {     // mwC = [mw2 | mwB]: K=128 (KS=4), N=256
        int j = idx - 16384;
        int i = j & 7, l = (j >> 3) & 63, ks = (j >> 9) & 3, nt = j >> 11;
        int k = ks * 32 + (l >> 4) * 8 + i, n = nt * 16 + (l & 15);
        mwCp[j] = bf16s((n < 128) ? mw2[k * 128 + n] : mwB[k * 128 + (n - 128)]);
    } else if (idx < 65536) {     // aw1 TOP half: K=128, N=128
        int j = idx - 49152;
        int i = j & 7, l = (j >> 3) & 63, ks = (j >> 9) & 3, nt = j >> 11;
        int k = ks * 32 + (l >> 4) * 8 + i, n = nt * 16 + (l & 15);
        awTp[j] = bf16s(aw1[k * 128 + n]);
    } else if (idx < 131072) {    // fw1: K=128 (KS=4), N=512
        int j = idx - 65536;
        int i = j & 7, l = (j >> 3) & 63, ks = (j >> 9) & 3, nt = j >> 11;
        int k = ks * 32 + (l >> 4) * 8 + i, n = nt * 16 + (l & 15);
        fw1p[j] = bf16s(fw1[k * 512 + n]);
    } else if (idx < 196608) {    // fw2: K=512 (KS=16), N=128
        int j = idx - 131072;
        int i = j & 7, l = (j >> 3) & 63, ks = (j >> 9) & 15, nt = j >> 13;
        int k = ks * 32 + (l >> 4) * 8 + i, n = nt * 16 + (l & 15);
        fw2p[j] = bf16s(fw2[k * 128 + n]);
    }
}

// ---------------- nfa = nf @ aw1_top + ab1 (bf16, MFMA) ----------------
__global__ __launch_bounds__(256) void k_nfa(
    const unsigned short* __restrict__ nfb, const unsigned short* __restrict__ awTp,
    const float* __restrict__ ab1, unsigned short* __restrict__ nfa)
{
    __shared__ alignas(16) unsigned short XB[64 * 128]; // 16 KB
    const int t = threadIdx.x;
    const int w = t >> 6, l = t & 63;
    const int wm = w >> 1, wn = w & 1;
    const int lm = l & 15, lk = l >> 4;
    const int lrow = l >> 4, lslot = l & 15;
    const int n0 = blockIdx.x * 64;

    #pragma unroll
    for (int it = 0; it < 4; ++it) {
        int rb = w * 16 + it * 4;
        int row = rb + lrow;
        long grow = n0 + row; if (grow >= NN) grow = NN - 1;
        int c = lslot ^ (row & 7);
        gload_lds16(nfb + grow * DD + c * 8, &XB[rb * 128]);
    }
    __syncthreads();

    f32x4 acc[2][4];
    #pragma unroll
    for (int mf = 0; mf < 2; ++mf)
        #pragma unroll
        for (int nfr = 0; nfr < 4; ++nfr) acc[mf][nfr] = (f32x4){0.f, 0.f, 0.f, 0.f};

    #pragma unroll
    for (int ks = 0; ks < 4; ++ks) {
        bf16x8 a[2];
        #pragma unroll
        for (int mf = 0; mf < 2; ++mf) {
            int m = wm * 32 + mf * 16 + lm;
            int slot = (ks * 4 + lk) ^ (m & 7);
            a[mf] = *reinterpret_cast<const bf16x8*>(&XB[m * 128 + slot * 8]);
        }
        #pragma unroll
        for (int nfr = 0; nfr < 4; ++nfr) {
            int nt = wn * 4 + nfr;
            bf16x8 b = *reinterpret_cast<const bf16x8*>(&awTp[((nt * 4 + ks) * 64 + l) * 8]);
            acc[0][nfr] = __builtin_amdgcn_mfma_f32_16x16x32_bf16(a[0], b, acc[0][nfr], 0, 0, 0);
            acc[1][nfr] = __builtin_amdgcn_mfma_f32_16x16x32_bf16(a[1], b, acc[1][nfr], 0, 0, 0);
        }
    }
    __syncthreads();

    #pragma unroll
    for (int nfr = 0; nfr < 4; ++nfr) {
        int n = wn * 64 + nfr * 16 + lm;
        float bv = ab1[n];
        #pragma unroll
        for (int mf = 0; mf < 2; ++mf)
            #pragma unroll
            for (int r = 0; r < 4; ++r) {
                int m = wm * 32 + mf * 16 + lk * 4 + r;
                XB[m * 128 + n] = bf16s(acc[mf][nfr][r] + bv);
            }
    }
    __syncthreads();

    #pragma unroll
    for (int j = 0; j < 4; ++j) {
        int q = j * 256 + t;
        int row = q >> 4, c16 = q & 15;
        if (n0 + row < NN)
            *reinterpret_cast<uint4*>(&nfa[(size_t)(n0 + row) * DD + c16 * 8]) =
                *reinterpret_cast<const uint4*>(&XB[row * 128 + c16 * 8]);
    }
}

// ---------------- edge kernel (sorted order): 2 MFMA GEMMs, 2 LDS buffers ----
// block = 512 thr (8 waves, wm=w>>2, wn=w&3), 64 sorted-edge slots/block.
__global__ __launch_bounds__(512) void k_edge(
    const unsigned short* __restrict__ nfb, const int* __restrict__ srcs,
    const int* __restrict__ dsts, const int* __restrict__ ets,
    const unsigned short* __restrict__ nfa, const unsigned short* __restrict__ relcb,
    const unsigned short* __restrict__ mw1p, const unsigned short* __restrict__ mwCp,
    const float* __restrict__ mb2, const float* __restrict__ zb,
    const float* __restrict__ aw2, const float* __restrict__ ab2,
    unsigned short* __restrict__ msg_out, float* __restrict__ attn_raw)
{
    __shared__ alignas(16) unsigned short S[64 * 128];  // src rows, then nfa[dst]
    __shared__ alignas(16) unsigned short H[64 * 128];  // relc, then hidden, then msg
    __shared__ float RED[64][2];

    const int t = threadIdx.x;
    const int w = t >> 6, l = t & 63;
    const int wm = w >> 2, wn = w & 3;
    const int lm = l & 15, lk = l >> 4;
    const int lrow = l >> 4, lslot = l & 15;
    const int e0 = blockIdx.x * 64;

    // ---- phase 0: S <- nfb[srcs], H <- relcb[ets] (swizzled source) ----
    #pragma unroll
    for (int it = 0; it < 2; ++it) {
        int rb = w * 8 + it * 4;
        int row = rb + lrow;
        int c = lslot ^ (row & 7);
        gload_lds16(nfb + (size_t)srcs[e0 + row] * DD + c * 8, &S[rb * 128]);
    }
    #pragma unroll
    for (int it = 0; it < 2; ++it) {
        int rb = w * 8 + it * 4;
        int row = rb + lrow;
        int c = lslot ^ (row & 7);
        gload_lds16(relcb + (size_t)ets[e0 + row] * DD + c * 8, &H[rb * 128]);
    }
    __syncthreads();

    // ---- GEMM1: hidden = relu(src @ mw1_top + relc), K=128; H slot RMW ----
    {
        f32x4 acc[2][2];
        #pragma unroll
        for (int mf = 0; mf < 2; ++mf)
            #pragma unroll
            for (int nfr = 0; nfr < 2; ++nfr) acc[mf][nfr] = (f32x4){0.f, 0.f, 0.f, 0.f};

        #pragma unroll
        for (int ks = 0; ks < 4; ++ks) {
            bf16x8 a[2];
            #pragma unroll
            for (int mf = 0; mf < 2; ++mf) {
                int m = wm * 32 + mf * 16 + lm;
                int slot = (ks * 4 + lk) ^ (m & 7);
                a[mf] = *reinterpret_cast<const bf16x8*>(&S[m * 128 + slot * 8]);
            }
            #pragma unroll
            for (int nfr = 0; nfr < 2; ++nfr) {
                int nt = wn * 2 + nfr;
                bf16x8 b = *reinterpret_cast<const bf16x8*>(&mw1p[((nt * 4 + ks) * 64 + l) * 8]);
                acc[0][nfr] = __builtin_amdgcn_mfma_f32_16x16x32_bf16(a[0], b, acc[0][nfr], 0, 0, 0);
                acc[1][nfr] = __builtin_amdgcn_mfma_f32_16x16x32_bf16(a[1], b, acc[1][nfr], 0, 0, 0);
            }
        }
        // same-thread same-slot read(relc) -> relu -> write(hidden)
        #pragma unroll
        for (int nfr = 0; nfr < 2; ++nfr) {
            int n = (wn * 2 + nfr) * 16 + lm;
            #pragma unroll
            for (int mf = 0; mf < 2; ++mf)
                #pragma unroll
                for (int r = 0; r < 4; ++r) {
                    int m = wm * 32 + mf * 16 + lk * 4 + r;
                    int sl = m * 128 + ((n >> 3) ^ (m & 7)) * 8 + (n & 7);
                    float v = acc[mf][nfr][r] + unbf(H[sl]);
                    v = fmaxf(v, 0.0f);
                    H[sl] = bf16s(v);
                }
        }
    }
    __syncthreads(); // hidden complete; S (src) reads done

    // ---- phase 2: S <- nfa[dsts] (overlaps GEMM2'); GEMM2' reads H ----
    #pragma unroll
    for (int it = 0; it < 2; ++it) {
        int rb = w * 8 + it * 4;
        int row = rb + lrow;
        int c = lslot ^ (row & 7);
        gload_lds16(nfa + (size_t)dsts[e0 + row] * DD + c * 8, &S[rb * 128]);
    }

    f32x4 acc[2][4];
    #pragma unroll
    for (int mf = 0; mf < 2; ++mf)
        #pragma unroll
        for (int nfr = 0; nfr < 4; ++nfr) acc[mf][nfr] = (f32x4){0.f, 0.f, 0.f, 0.f};

    #pragma unroll
    for (int ks = 0; ks < 4; ++ks) {
        bf16x8 a[2];
        #pragma unroll
        for (int mf = 0; mf < 2; ++mf) {
            int m = wm * 32 + mf * 16 + lm;
            int slot = (ks * 4 + lk) ^ (m & 7);
            a[mf] = *reinterpret_cast<const bf16x8*>(&H[m * 128 + slot * 8]);
        }
        #pragma unroll
        for (int nfr = 0; nfr < 4; ++nfr) {
            int nt = wn * 4 + nfr;   // 0..15 over N=256
            bf16x8 b = *reinterpret_cast<const bf16x8*>(&mwCp[((nt * 4 + ks) * 64 + l) * 8]);
            acc[0][nfr] = __builtin_amdgcn_mfma_f32_16x16x32_bf16(a[0], b, acc[0][nfr], 0, 0, 0);
            acc[1][nfr] = __builtin_amdgcn_mfma_f32_16x16x32_bf16(a[1], b, acc[1][nfr], 0, 0, 0);
        }
    }
    __syncthreads(); // nfa staged into S; H A-reads done

    if (wn < 2) {
        // ---- msg half: cols 0..127 -> H (swizzled) ----
        #pragma unroll
        for (int nfr = 0; nfr < 4; ++nfr) {
            int n = (wn * 4 + nfr) * 16 + lm;
            float bv = mb2[n];
            #pragma unroll
            for (int mf = 0; mf < 2; ++mf)
                #pragma unroll
                for (int r = 0; r < 4; ++r) {
                    int m = wm * 32 + mf * 16 + lk * 4 + r;
                    H[m * 128 + ((n >> 3) ^ (m & 7)) * 8 + (n & 7)] = bf16s(acc[mf][nfr][r] + bv);
                }
        }
    } else {
        // ---- z half: z = zpre + zb + nfa[dst]; leaky; dot aw2 ----
        float zbv[4], aw2v[4];
        #pragma unroll
        for (int nfr = 0; nfr < 4; ++nfr) {
            int nc = (wn - 2) * 64 + nfr * 16 + lm;
            zbv[nfr] = zb[nc];
            aw2v[nfr] = aw2[nc];
        }
        #pragma unroll
        for (int mf = 0; mf < 2; ++mf)
            #pragma unroll
            for (int r = 0; r < 4; ++r) {
                int m = wm * 32 + mf * 16 + lk * 4 + r;
                float s = 0.0f;
                #pragma unroll
                for (int nfr = 0; nfr < 4; ++nfr) {
                    int nc = (wn - 2) * 64 + nfr * 16 + lm;
                    float v = acc[mf][nfr][r] + zbv[nfr]
                            + unbf(S[m * 128 + ((nc >> 3) ^ (m & 7)) * 8 + (nc & 7)]);
                    v = (v > 0.0f) ? v : 0.2f * v;
                    s = fmaf(v, aw2v[nfr], s);
                }
                s += __shfl_xor(s, 1, 64);
                s += __shfl_xor(s, 2, 64);
                s += __shfl_xor(s, 4, 64);
                s += __shfl_xor(s, 8, 64);
                if (lm == 0) RED[m][wn - 2] = s;
            }
    }
    __syncthreads();

    // ---- copy msg -> global (sorted position); logits -> global ----
    #pragma unroll
    for (int j = 0; j < 2; ++j) {
        int q = j * 512 + t;
        int row = q >> 4, c16 = q & 15;
        int slot = c16 ^ (row & 7);
        *reinterpret_cast<uint4*>(&msg_out[(size_t)(e0 + row) * DD + c16 * 8]) =
            *reinterpret_cast<const uint4*>(&H[row * 128 + slot * 8]);
    }
    if (t < 64) {
        attn_raw[e0 + t] = RED[t][0] + RED[t][1] + ab2[0];
    }
}

// ---------------- fused per-node softmax + aggregate (sequential rows) ------
__global__ __launch_bounds__(256) void k_aggr(
    const unsigned short* __restrict__ msg, const float* __restrict__ raw,
    const int* __restrict__ row_start, const int* __restrict__ cnt,
    float* __restrict__ aggr)
{
    const int l = threadIdx.x & 63;
    const int n = blockIdx.x * 4 + (threadIdx.x >> 6);
    if (n >= NN) return;
    const int rs = row_start[n], deg = cnt[n];

    float m = -INFINITY;
    for (int j = l; j < deg; j += 64) m = fmaxf(m, raw[rs + j]);
    #pragma unroll
    for (int off = 32; off >= 1; off >>= 1) m = fmaxf(m, __shfl_xor(m, off, 64));

    float s = 0.0f;
    for (int j = l; j < deg; j += 64) s += expf(raw[rs + j] - m);
    #pragma unroll
    for (int off = 32; off >= 1; off >>= 1) s += __shfl_xor(s, off, 64);
    const float rinv = 1.0f / (s + 1e-8f);

    float a0 = 0.0f, a1 = 0.0f;
    for (int j = 0; j < deg; ++j) {
        float w = expf(raw[rs + j] - m) * rinv;   // uniform across lanes
        unsigned int v = *reinterpret_cast<const unsigned int*>(
            &msg[(size_t)(rs + j) * DD + l * 2]);
        a0 = fmaf(w, unlo(v), a0);
        a1 = fmaf(w, unhi(v), a1);
    }
    float2 o = {a0, a1};
    *reinterpret_cast<float2*>(&aggr[(size_t)n * DD + l * 2]) = o;
}

// ---------------- node kernel: LN1 + MFMA FFN + LN2 (8 waves) ----------------
__global__ __launch_bounds__(512) void k_node(
    const float* __restrict__ nf, const float* __restrict__ aggr,
    const float* __restrict__ g1, const float* __restrict__ b1,
    const unsigned short* __restrict__ fw1p, const float* __restrict__ fb1,
    const unsigned short* __restrict__ fw2p, const float* __restrict__ fb2,
    const float* __restrict__ g2, const float* __restrict__ b2,
    float* __restrict__ out)
{
    __shared__ alignas(16) unsigned short XB[64 * 128]; // 16 KB
    __shared__ alignas(16) unsigned short HB[64 * 256]; // 32 KB

    const int t = threadIdx.x;
    const int w = t >> 6, l = t & 63;
    const int wm = w >> 2, wn = w & 3;
    const int lm = l & 15, lk = l >> 4;
    const int row = t >> 3;      // 0..63
    const int q = t & 7;         // 16-col segment
    const long n0 = (long)blockIdx.x * 64;
    const long rg = n0 + row;
    const long rc = (rg < NN) ? rg : (NN - 1);

    // ---- LN1 ----
    float xr[16];
    float s = 0.0f, ss = 0.0f;
    {
        const float* xp = nf + rc * DD + q * 16;
        const float* ap = aggr + rc * DD + q * 16;
        #pragma unroll
        for (int i = 0; i < 4; ++i) {
            float4 a = *reinterpret_cast<const float4*>(xp + i * 4);
            float4 b = *reinterpret_cast<const float4*>(ap + i * 4);
            float v0 = a.x + b.x, v1 = a.y + b.y, v2 = a.z + b.z, v3 = a.w + b.w;
            xr[i * 4 + 0] = v0; xr[i * 4 + 1] = v1; xr[i * 4 + 2] = v2; xr[i * 4 + 3] = v3;
            s += v0 + v1 + v2 + v3;
            ss = fmaf(v0, v0, ss); ss = fmaf(v1, v1, ss);
            ss = fmaf(v2, v2, ss); ss = fmaf(v3, v3, ss);
        }
    }
    s  += __shfl_xor(s, 1, 64);  s  += __shfl_xor(s, 2, 64);  s  += __shfl_xor(s, 4, 64);
    ss += __shfl_xor(ss, 1, 64); ss += __shfl_xor(ss, 2, 64); ss += __shfl_xor(ss, 4, 64);
    {
        float mu = s * (1.0f / DD);
        float var = ss * (1.0f / DD) - mu * mu;
        float rstd = rsqrtf(var + 1e-5f);
        #pragma unroll
        for (int i = 0; i < 4; ++i) {
            float4 gv = *reinterpret_cast<const float4*>(g1 + q * 16 + i * 4);
            float4 bv = *reinterpret_cast<const float4*>(b1 + q * 16 + i * 4);
            xr[i * 4 + 0] = (xr[i * 4 + 0] - mu) * rstd * gv.x + bv.x;
            xr[i * 4 + 1] = (xr[i * 4 + 1] - mu) * rstd * gv.y + bv.y;
            xr[i * 4 + 2] = (xr[i * 4 + 2] - mu) * rstd * gv.z + bv.z;
            xr[i * 4 + 3] = (xr[i * 4 + 3] - mu) * rstd * gv.w + bv.w;
        }
        #pragma unroll
        for (int i = 0; i < 2; ++i) {
            int c = q * 2 + i, slot = c ^ (row & 7);
            uint4 v;
            v.x = pk2(xr[i * 8 + 0], xr[i * 8 + 1]);
            v.y = pk2(xr[i * 8 + 2], xr[i * 8 + 3]);
            v.z = pk2(xr[i * 8 + 4], xr[i * 8 + 5]);
            v.w = pk2(xr[i * 8 + 6], xr[i * 8 + 7]);
            *reinterpret_cast<uint4*>(&XB[row * 128 + slot * 8]) = v;
        }
    }
    __syncthreads();

    // ---- FFN: two 256-col halves ----
    f32x4 acc2[2][2];
    #pragma unroll
    for (int mf = 0; mf < 2; ++mf)
        #pragma unroll
        for (int nfr = 0; nfr < 2; ++nfr) acc2[mf][nfr] = (f32x4){0.f, 0.f, 0.f, 0.f};

    #pragma unroll
    for (int half = 0; half < 2; ++half) {
        f32x4 acc[2][4];
        #pragma unroll
        for (int mf = 0; mf < 2; ++mf)
            #pragma unroll
            for (int nfr = 0; nfr < 4; ++nfr) acc[mf][nfr] = (f32x4){0.f, 0.f, 0.f, 0.f};

        #pragma unroll
        for (int ks = 0; ks < 4; ++ks) {
            bf16x8 a[2];
            #pragma unroll
            for (int mf = 0; mf < 2; ++mf) {
                int m = wm * 32 + mf * 16 + lm;
                int slot = (ks * 4 + lk) ^ (m & 7);
                a[mf] = *reinterpret_cast<const bf16x8*>(&XB[m * 128 + slot * 8]);
            }
            #pragma unroll
            for (int nfr = 0; nfr < 4; ++nfr) {
                int nt = half * 16 + wn * 4 + nfr;
                bf16x8 b = *reinterpret_cast<const bf16x8*>(&fw1p[((nt * 4 + ks) * 64 + l) * 8]);
                acc[0][nfr] = __builtin_amdgcn_mfma_f32_16x16x32_bf16(a[0], b, acc[0][nfr], 0, 0, 0);
                acc[1][nfr] = __builtin_amdgcn_mfma_f32_16x16x32_bf16(a[1], b, acc[1][nfr], 0, 0, 0);
            }
        }
        #pragma unroll
        for (int nfr = 0; nfr < 4; ++nfr) {
            int nl = (wn * 4 + nfr) * 16 + lm;   // col within half (0..255)
            float bv = fb1[half * 256 + nl];
            #pragma unroll
            for (int mf = 0; mf < 2; ++mf)
                #pragma unroll
                for (int r = 0; r < 4; ++r) {
                    int m = wm * 32 + mf * 16 + lk * 4 + r;
                    float h = acc[mf][nfr][r] + bv;
                    float e = __expf(h * -1.702f);
                    float gvv = h * __builtin_amdgcn_rcpf(1.0f + e);
                    HB[m * 256 + (((nl >> 3) ^ (m & 7)) * 8) + (nl & 7)] = bf16s(gvv);
                }
        }
        __syncthreads();

        #pragma unroll
        for (int ks = 0; ks < 8; ++ks) {
            bf16x8 a[2];
            #pragma unroll
            for (int mf = 0; mf < 2; ++mf) {
                int m = wm * 32 + mf * 16 + lm;
                int slot = (ks * 4 + lk) ^ (m & 7);
                a[mf] = *reinterpret_cast<const bf16x8*>(&HB[m * 256 + slot * 8]);
            }
            #pragma unroll
            for (int nfr = 0; nfr < 2; ++nfr) {
                int nt = wn * 2 + nfr;
                int kg = half * 8 + ks;
                bf16x8 b = *reinterpret_cast<const bf16x8*>(&fw2p[((nt * 16 + kg) * 64 + l) * 8]);
                acc2[0][nfr] = __builtin_amdgcn_mfma_f32_16x16x32_bf16(a[0], b, acc2[0][nfr], 0, 0, 0);
                acc2[1][nfr] = __builtin_amdgcn_mfma_f32_16x16x32_bf16(a[1], b, acc2[1][nfr], 0, 0, 0);
            }
        }
        __syncthreads();
    }

    // ---- ffn -> XB (bf16) ----
    #pragma unroll
    for (int nfr = 0; nfr < 2; ++nfr) {
        int n = (wn * 2 + nfr) * 16 + lm;
        float bv = fb2[n];
        #pragma unroll
        for (int mf = 0; mf < 2; ++mf)
            #pragma unroll
            for (int r = 0; r < 4; ++r) {
                int m = wm * 32 + mf * 16 + lk * 4 + r;
                XB[m * 128 + (((n >> 3) ^ (m & 7)) * 8) + (n & 7)] = bf16s(acc2[mf][nfr][r] + bv);
            }
    }
    __syncthreads();

    // ---- residual + LN2 ----
    float s2 = 0.0f, ss2 = 0.0f;
    #pragma unroll
    for (int i = 0; i < 2; ++i) {
        int c = q * 2 + i, slot = c ^ (row & 7);
        uint4 v = *reinterpret_cast<const uint4*>(&XB[row * 128 + slot * 8]);
        float f[8];
        f[0] = unlo(v.x); f[1] = unhi(v.x); f[2] = unlo(v.y); f[3] = unhi(v.y);
        f[4] = unlo(v.z); f[5] = unhi(v.z); f[6] = unlo(v.w); f[7] = unhi(v.w);
        #pragma unroll
        for (int j = 0; j < 8; ++j) {
            float vv = xr[i * 8 + j] + f[j];
            xr[i * 8 + j] = vv;
            s2 += vv;
            ss2 = fmaf(vv, vv, ss2);
        }
    }
    s2  += __shfl_xor(s2, 1, 64);  s2  += __shfl_xor(s2, 2, 64);  s2  += __shfl_xor(s2, 4, 64);
    ss2 += __shfl_xor(ss2, 1, 64); ss2 += __shfl_xor(ss2, 2, 64); ss2 += __shfl_xor(ss2, 4, 64);
    {
        float mu = s2 * (1.0f / DD);
        float var = ss2 * (1.0f / DD) - mu * mu;
        float rstd = rsqrtf(var + 1e-5f);
        if (rg < NN) {
            float* op = out + rg * DD + q * 16;
            #pragma unroll
            for (int i = 0; i < 4; ++i) {
                float4 gv = *reinterpret_cast<const float4*>(g2 + q * 16 + i * 4);
                float4 bv = *reinterpret_cast<const float4*>(b2 + q * 16 + i * 4);
                float4 o;
                o.x = (xr[i * 4 + 0] - mu) * rstd * gv.x + bv.x;
                o.y = (xr[i * 4 + 1] - mu) * rstd * gv.y + bv.y;
                o.z = (xr[i * 4 + 2] - mu) * rstd * gv.z + bv.z;
                o.w = (xr[i * 4 + 3] - mu) * rstd * gv.w + bv.w;
                *reinterpret_cast<float4*>(op + i * 4) = o;
            }
        }
    }
}

extern "C" void kernel_launch(void* const* d_in, const int* in_sizes, int n_in,
                              void* d_out, int out_size, void* d_ws, size_t ws_size,
                              hipStream_t stream)
{
    const float* nf  = (const float*)d_in[0];
    const int*   ei  = (const int*)d_in[1];
    const int*   et  = (const int*)d_in[2];
    const float* rel = (const float*)d_in[3];
    const float* mw1 = (const float*)d_in[4];
    const float* mb1 = (const float*)d_in[5];
    const float* mw2 = (const float*)d_in[6];
    const float* mb2 = (const float*)d_in[7];
    const float* aw1 = (const float*)d_in[8];
    const float* ab1 = (const float*)d_in[9];
    const float* aw2 = (const float*)d_in[10];
    const float* ab2 = (const float*)d_in[11];
    const float* g1  = (const float*)d_in[12];
    const float* b1  = (const float*)d_in[13];
    const float* fw1 = (const float*)d_in[14];
    const float* fb1 = (const float*)d_in[15];
    const float* fw2 = (const float*)d_in[16];
    const float* fb2 = (const float*)d_in[17];
    const float* g2  = (const float*)d_in[18];
    const float* b2  = (const float*)d_in[19];
    float* out = (float*)d_out;

    char* ws = (char*)d_ws;
    size_t off = 0;
    auto alloc = [&](size_t bytes) -> char* {
        char* p = ws + off;
        off += (bytes + 255) & ~(size_t)255;
        return p;
    };
    unsigned short* msg = (unsigned short*)alloc((size_t)NE * DD * 2);
    float* attn_raw = (float*)alloc((size_t)NE * 4);
    float* aggr     = (float*)alloc((size_t)NN * DD * 4);
    unsigned short* nfb  = (unsigned short*)alloc((size_t)NN * DD * 2);
    unsigned short* relcb = (unsigned short*)alloc((size_t)RR * DD * 2);
    float* mwB = (float*)alloc((size_t)16384 * 4);
    float* zb  = (float*)alloc((size_t)128 * 4);
    int* cnt       = (int*)alloc((size_t)NN * 4);
    int* row_start = (int*)alloc((size_t)NN * 4);
    int* cursor    = (int*)alloc((size_t)NN * 4);
    int* srcs      = (int*)alloc((size_t)NE * 4);
    int* ets       = (int*)alloc((size_t)NE * 4);
    int* dsts      = (int*)alloc((size_t)NE * 4);
    int* bsum      = (int*)alloc((size_t)SCAN_NB * 4);
    unsigned short* mw1p = (unsigned short*)alloc(16384 * 2);
    unsigned short* mwCp = (unsigned short*)alloc(32768 * 2);
    unsigned short* awTp = (unsigned short*)alloc(16384 * 2);
    unsigned short* fw1p = (unsigned short*)alloc(65536 * 2);
    unsigned short* fw2p = (unsigned short*)alloc(65536 * 2);

    // nfa aliases aggr (nfa dead after k_edge; aggr fully overwritten by k_aggr)
    unsigned short* nfa = (unsigned short*)aggr;

    const int* srcp = ei;
    const int* dstp = ei + NE;

    hipLaunchKernelGGL(k_initc, dim3(SCAN_NB), dim3(256), 0, stream, cnt);
    hipLaunchKernelGGL(k_hist, dim3((NE + 255) / 256), dim3(256), 0, stream, dstp, cnt);
    hipLaunchKernelGGL(k_scanA, dim3(SCAN_NB), dim3(256), 0, stream, cnt, bsum);
    hipLaunchKernelGGL(k_scanB, dim3(1), dim3(512), 0, stream, bsum);
    hipLaunchKernelGGL(k_scanC, dim3(SCAN_NB), dim3(256), 0, stream, cnt, bsum, row_start, cursor);
    hipLaunchKernelGGL(k_bucket, dim3((NE + 255) / 256), dim3(256), 0, stream,
                       srcp, dstp, et, cursor, srcs, ets, dsts);
    hipLaunchKernelGGL(k_prep, dim3(NN * DD / 8 / 256), dim3(256), 0, stream, nf, nfb);
    hipLaunchKernelGGL(k_mwb, dim3(65), dim3(256), 0, stream, mw2, mb2, aw1, mwB, zb);
    hipLaunchKernelGGL(k_pack, dim3(768), dim3(256), 0, stream,
                       mw1, mw2, mwB, aw1, fw1, fw2, mw1p, mwCp, awTp, fw1p, fw2p);
    hipLaunchKernelGGL(k_relc, dim3(100), dim3(256), 0, stream, rel, mw1, mb1, relcb);
    hipLaunchKernelGGL(k_nfa, dim3((NN + 63) / 64), dim3(256), 0, stream,
                       nfb, awTp, ab1, nfa);
    hipLaunchKernelGGL(k_edge, dim3(NE / 64), dim3(512), 0, stream,
                       nfb, srcs, dsts, ets, nfa, relcb,
                       mw1p, mwCp, mb2, zb, aw2, ab2,
                       msg, attn_raw);
    hipLaunchKernelGGL(k_aggr, dim3((NN + 3) / 4), dim3(256), 0, stream,
                       msg, attn_raw, row_start, cnt, aggr);
    hipLaunchKernelGGL(k_node, dim3((NN + 63) / 64), dim3(512), 0, stream,
                       nf, aggr, g1, b1, fw1p, fb1, fw2p, fb2, g2, b2, out);
}

// Round 9
// 432.203 us; speedup vs baseline: 6.4110x; 1.0913x over previous
//
#include <hip/hip_runtime.h>
#include <hip/hip_bf16.h>

#define NN 100000
#define NE 600000
#define DD 128
#define RR 200
#define SCAN_NB ((NN + 255) / 256)   // 391

typedef __attribute__((ext_vector_type(8))) short bf16x8;
typedef __attribute__((ext_vector_type(4))) float f32x4;

__device__ __forceinline__ unsigned int bfbits(float x) {
    return (unsigned int)__builtin_bit_cast(unsigned short, __float2bfloat16(x));
}
__device__ __forceinline__ unsigned int pk2(float a, float b) {
    return bfbits(a) | (bfbits(b) << 16);
}
__device__ __forceinline__ unsigned short bf16s(float x) {
    return __builtin_bit_cast(unsigned short, __float2bfloat16(x));
}
__device__ __forceinline__ float unbf(unsigned short u) {
    return __builtin_bit_cast(float, ((unsigned int)u) << 16);
}
__device__ __forceinline__ float unlo(unsigned int u) {
    return __builtin_bit_cast(float, u << 16);
}
__device__ __forceinline__ float unhi(unsigned int u) {
    return __builtin_bit_cast(float, u & 0xffff0000u);
}

__device__ __forceinline__ void gload_lds16(const void* g, void* l) {
    __builtin_amdgcn_global_load_lds(
        (const __attribute__((address_space(1))) void*)g,
        (__attribute__((address_space(3))) void*)l, 16, 0, 0);
}

// ---------------- zero edge-count histogram ----------------
__global__ void k_initc(int* __restrict__ cnt) {
    int i = blockIdx.x * 256 + threadIdx.x;
    if (i < NN) cnt[i] = 0;
}

// ---------------- histogram of dst ----------------
__global__ void k_hist(const int* __restrict__ dst, int* __restrict__ cnt) {
    int e = blockIdx.x * 256 + threadIdx.x;
    if (e < NE) atomicAdd(&cnt[dst[e]], 1);
}

// ---------------- 3-kernel exclusive scan over cnt[NN] ----------------
__global__ void k_scanA(const int* __restrict__ cnt, int* __restrict__ bsum) {
    __shared__ int red[256];
    int i = blockIdx.x * 256 + threadIdx.x;
    red[threadIdx.x] = (i < NN) ? cnt[i] : 0;
    __syncthreads();
    for (int off = 128; off >= 1; off >>= 1) {
        if (threadIdx.x < off) red[threadIdx.x] += red[threadIdx.x + off];
        __syncthreads();
    }
    if (threadIdx.x == 0) bsum[blockIdx.x] = red[0];
}

__global__ void k_scanB(int* __restrict__ bsum) {
    __shared__ int sh[512];
    int t = threadIdx.x;
    int v = (t < SCAN_NB) ? bsum[t] : 0;
    sh[t] = v;
    __syncthreads();
    for (int off = 1; off < 512; off <<= 1) {
        int add = (t >= off) ? sh[t - off] : 0;
        __syncthreads();
        sh[t] += add;
        __syncthreads();
    }
    if (t < SCAN_NB) bsum[t] = sh[t] - v;   // exclusive
}

__global__ void k_scanC(const int* __restrict__ cnt, const int* __restrict__ bsum,
                        int* __restrict__ row_start, int* __restrict__ cursor) {
    __shared__ int sh[256];
    int i = blockIdx.x * 256 + threadIdx.x;
    int t = threadIdx.x;
    int v = (i < NN) ? cnt[i] : 0;
    sh[t] = v;
    __syncthreads();
    for (int off = 1; off < 256; off <<= 1) {
        int add = (t >= off) ? sh[t - off] : 0;
        __syncthreads();
        sh[t] += add;
        __syncthreads();
    }
    if (i < NN) {
        int ex = bsum[blockIdx.x] + sh[t] - v;
        row_start[i] = ex;
        cursor[i] = ex;
    }
}

// ---------------- bucket: permuted src/etype/dst grouped by dst ----------------
__global__ void k_bucket(const int* __restrict__ src, const int* __restrict__ dst,
                         const int* __restrict__ etype, int* __restrict__ cursor,
                         int* __restrict__ srcs, int* __restrict__ ets,
                         int* __restrict__ dsts) {
    int e = blockIdx.x * 256 + threadIdx.x;
    if (e < NE) {
        int d = dst[e];
        int p = atomicAdd(&cursor[d], 1);
        srcs[p] = src[e];
        ets[p]  = etype[e];
        dsts[p] = d;
    }
}

// ---------------- prep: bf16 copy of node features ----------------
__global__ void k_prep(const float* __restrict__ nf, unsigned short* __restrict__ nfb) {
    int i = blockIdx.x * 256 + threadIdx.x;
    if (i >= NN * DD / 8) return;
    const float* sp = nf + (size_t)i * 8;
    float4 f0 = *reinterpret_cast<const float4*>(sp);
    float4 f1 = *reinterpret_cast<const float4*>(sp + 4);
    uint4 v;
    v.x = pk2(f0.x, f0.y); v.y = pk2(f0.z, f0.w);
    v.z = pk2(f1.x, f1.y); v.w = pk2(f1.z, f1.w);
    *reinterpret_cast<uint4*>(nfb + (size_t)i * 8) = v;
}

// ---------------- setup: all weight packing + small folds (one launch) ------
// segments: [0,16K) mw1p | [16K,32K) mw2p | [32K,48K) awTp | [48K,64K) mwBp
//           [64K,128K) fw1p | [128K,192K) fw2p | [192K,+25600) relcb | +128 zb
__global__ void k_setup(const float* __restrict__ mw1, const float* __restrict__ mb1,
                        const float* __restrict__ mw2, const float* __restrict__ mb2,
                        const float* __restrict__ aw1, const float* __restrict__ rel,
                        const float* __restrict__ fw1, const float* __restrict__ fw2,
                        unsigned short* __restrict__ mw1p,
                        unsigned short* __restrict__ mw2p,
                        unsigned short* __restrict__ awTp,
                        unsigned short* __restrict__ mwBp,
                        unsigned short* __restrict__ fw1p,
                        unsigned short* __restrict__ fw2p,
                        unsigned short* __restrict__ relcb,
                        float* __restrict__ zb) {
    int idx = blockIdx.x * 256 + threadIdx.x;   // 222336 total
    if (idx < 16384) {            // mw1 TOP: K=128, N=128
        int i = idx & 7, l = (idx >> 3) & 63, ks = (idx >> 9) & 3, nt = idx >> 11;
        int k = ks * 32 + (l >> 4) * 8 + i, n = nt * 16 + (l & 15);
        mw1p[idx] = bf16s(mw1[k * 128 + n]);
    } else if (idx < 32768) {     // mw2: K=128, N=128
        int j = idx - 16384;
        int i = j & 7, l = (j >> 3) & 63, ks = (j >> 9) & 3, nt = j >> 11;
        int k = ks * 32 + (l >> 4) * 8 + i, n = nt * 16 + (l & 15);
        mw2p[j] = bf16s(mw2[k * 128 + n]);
    } else if (idx < 49152) {     // aw1 TOP: K=128, N=128
        int j = idx - 32768;
        int i = j & 7, l = (j >> 3) & 63, ks = (j >> 9) & 3, nt = j >> 11;
        int k = ks * 32 + (l >> 4) * 8 + i, n = nt * 16 + (l & 15);
        awTp[j] = bf16s(aw1[k * 128 + n]);
    } else if (idx < 65536) {     // mwB = mw2 @ aw1_bot: K=128, N=128 (direct dot)
        int j = idx - 49152;
        int i = j & 7, l = (j >> 3) & 63, ks = (j >> 9) & 3, nt = j >> 11;
        int k = ks * 32 + (l >> 4) * 8 + i, n = nt * 16 + (l & 15);
        float s = 0.0f;
        for (int j2 = 0; j2 < 128; ++j2)
            s = fmaf(mw2[k * 128 + j2], aw1[(128 + j2) * 128 + n], s);
        mwBp[j] = bf16s(s);
    } else if (idx < 131072) {    // fw1: K=128, N=512
        int j = idx - 65536;
        int i = j & 7, l = (j >> 3) & 63, ks = (j >> 9) & 3, nt = j >> 11;
        int k = ks * 32 + (l >> 4) * 8 + i, n = nt * 16 + (l & 15);
        fw1p[j] = bf16s(fw1[k * 512 + n]);
    } else if (idx < 196608) {    // fw2: K=512 (KS=16), N=128
        int j = idx - 131072;
        int i = j & 7, l = (j >> 3) & 63, ks = (j >> 9) & 15, nt = j >> 13;
        int k = ks * 32 + (l >> 4) * 8 + i, n = nt * 16 + (l & 15);
        fw2p[j] = bf16s(fw2[k * 128 + n]);
    } else if (idx < 222208) {    // relcb = bf16(rel @ mw1_bot + mb1)
        int j = idx - 196608;
        int r = j >> 7, n = j & 127;
        float s = mb1[n];
        for (int k = 0; k < 128; ++k)
            s = fmaf(rel[r * 128 + k], mw1[(128 + k) * 128 + n], s);
        relcb[j] = bf16s(s);
    } else if (idx < 222336) {    // zb = mb2 @ aw1_bot
        int n = idx - 222208;
        float s = 0.0f;
        for (int j2 = 0; j2 < 128; ++j2)
            s = fmaf(mb2[j2], aw1[(128 + j2) * 128 + n], s);
        zb[n] = s;
    }
}

// ---------------- nfa = nf @ aw1_top + ab1 (bf16, MFMA) ----------------
__global__ __launch_bounds__(256) void k_nfa(
    const unsigned short* __restrict__ nfb, const unsigned short* __restrict__ awTp,
    const float* __restrict__ ab1, unsigned short* __restrict__ nfa)
{
    __shared__ alignas(16) unsigned short XB[64 * 128]; // 16 KB
    const int t = threadIdx.x;
    const int w = t >> 6, l = t & 63;
    const int wm = w >> 1, wn = w & 1;
    const int lm = l & 15, lk = l >> 4;
    const int lrow = l >> 4, lslot = l & 15;
    const int n0 = blockIdx.x * 64;

    #pragma unroll
    for (int it = 0; it < 4; ++it) {
        int rb = w * 16 + it * 4;
        int row = rb + lrow;
        long grow = n0 + row; if (grow >= NN) grow = NN - 1;
        int c = lslot ^ (row & 7);
        gload_lds16(nfb + grow * DD + c * 8, &XB[rb * 128]);
    }
    __syncthreads();

    f32x4 acc[2][4];
    #pragma unroll
    for (int mf = 0; mf < 2; ++mf)
        #pragma unroll
        for (int nfr = 0; nfr < 4; ++nfr) acc[mf][nfr] = (f32x4){0.f, 0.f, 0.f, 0.f};

    #pragma unroll
    for (int ks = 0; ks < 4; ++ks) {
        bf16x8 a[2];
        #pragma unroll
        for (int mf = 0; mf < 2; ++mf) {
            int m = wm * 32 + mf * 16 + lm;
            int slot = (ks * 4 + lk) ^ (m & 7);
            a[mf] = *reinterpret_cast<const bf16x8*>(&XB[m * 128 + slot * 8]);
        }
        #pragma unroll
        for (int nfr = 0; nfr < 4; ++nfr) {
            int nt = wn * 4 + nfr;
            bf16x8 b = *reinterpret_cast<const bf16x8*>(&awTp[((nt * 4 + ks) * 64 + l) * 8]);
            acc[0][nfr] = __builtin_amdgcn_mfma_f32_16x16x32_bf16(a[0], b, acc[0][nfr], 0, 0, 0);
            acc[1][nfr] = __builtin_amdgcn_mfma_f32_16x16x32_bf16(a[1], b, acc[1][nfr], 0, 0, 0);
        }
    }
    __syncthreads();

    #pragma unroll
    for (int nfr = 0; nfr < 4; ++nfr) {
        int n = wn * 64 + nfr * 16 + lm;
        float bv = ab1[n];
        #pragma unroll
        for (int mf = 0; mf < 2; ++mf)
            #pragma unroll
            for (int r = 0; r < 4; ++r) {
                int m = wm * 32 + mf * 16 + lk * 4 + r;
                XB[m * 128 + n] = bf16s(acc[mf][nfr][r] + bv);
            }
    }
    __syncthreads();

    #pragma unroll
    for (int j = 0; j < 4; ++j) {
        int q = j * 256 + t;
        int row = q >> 4, c16 = q & 15;
        if (n0 + row < NN)
            *reinterpret_cast<uint4*>(&nfa[(size_t)(n0 + row) * DD + c16 * 8]) =
                *reinterpret_cast<const uint4*>(&XB[row * 128 + c16 * 8]);
    }
}

// ---------------- edge kernel: GEMM1(hidden) + GEMM-z(logits) ---------------
// block = 512 thr (8 waves, wm=w>>2, wn=w&3), 64 sorted-edge slots/block.
// Writes hidden (not msg) — mw2 is applied per-node in k_node.
__global__ __launch_bounds__(512) void k_edge(
    const unsigned short* __restrict__ nfb, const int* __restrict__ srcs,
    const int* __restrict__ dsts, const int* __restrict__ ets,
    const unsigned short* __restrict__ nfa, const unsigned short* __restrict__ relcb,
    const unsigned short* __restrict__ mw1p, const unsigned short* __restrict__ mwBp,
    const float* __restrict__ zb, const float* __restrict__ aw2,
    const float* __restrict__ ab2,
    unsigned short* __restrict__ hid_out, float* __restrict__ attn_raw)
{
    __shared__ alignas(16) unsigned short S[64 * 128];  // src rows, then nfa[dst]
    __shared__ alignas(16) unsigned short H[64 * 128];  // relc, then hidden
    __shared__ float RED[64][4];

    const int t = threadIdx.x;
    const int w = t >> 6, l = t & 63;
    const int wm = w >> 2, wn = w & 3;
    const int lm = l & 15, lk = l >> 4;
    const int lrow = l >> 4, lslot = l & 15;
    const int e0 = blockIdx.x * 64;

    // ---- phase 0: S <- nfb[srcs], H <- relcb[ets] ----
    #pragma unroll
    for (int it = 0; it < 2; ++it) {
        int rb = w * 8 + it * 4;
        int row = rb + lrow;
        int c = lslot ^ (row & 7);
        gload_lds16(nfb + (size_t)srcs[e0 + row] * DD + c * 8, &S[rb * 128]);
    }
    #pragma unroll
    for (int it = 0; it < 2; ++it) {
        int rb = w * 8 + it * 4;
        int row = rb + lrow;
        int c = lslot ^ (row & 7);
        gload_lds16(relcb + (size_t)ets[e0 + row] * DD + c * 8, &H[rb * 128]);
    }
    __syncthreads();

    // ---- GEMM1: hidden = relu(src @ mw1_top + relc), K=128; H slot RMW ----
    {
        f32x4 acc1[2][2];
        #pragma unroll
        for (int mf = 0; mf < 2; ++mf)
            #pragma unroll
            for (int nfr = 0; nfr < 2; ++nfr) acc1[mf][nfr] = (f32x4){0.f, 0.f, 0.f, 0.f};

        #pragma unroll
        for (int ks = 0; ks < 4; ++ks) {
            bf16x8 a[2];
            #pragma unroll
            for (int mf = 0; mf < 2; ++mf) {
                int m = wm * 32 + mf * 16 + lm;
                int slot = (ks * 4 + lk) ^ (m & 7);
                a[mf] = *reinterpret_cast<const bf16x8*>(&S[m * 128 + slot * 8]);
            }
            #pragma unroll
            for (int nfr = 0; nfr < 2; ++nfr) {
                int nt = wn * 2 + nfr;
                bf16x8 b = *reinterpret_cast<const bf16x8*>(&mw1p[((nt * 4 + ks) * 64 + l) * 8]);
                acc1[0][nfr] = __builtin_amdgcn_mfma_f32_16x16x32_bf16(a[0], b, acc1[0][nfr], 0, 0, 0);
                acc1[1][nfr] = __builtin_amdgcn_mfma_f32_16x16x32_bf16(a[1], b, acc1[1][nfr], 0, 0, 0);
            }
        }
        #pragma unroll
        for (int nfr = 0; nfr < 2; ++nfr) {
            int n = (wn * 2 + nfr) * 16 + lm;
            #pragma unroll
            for (int mf = 0; mf < 2; ++mf)
                #pragma unroll
                for (int r = 0; r < 4; ++r) {
                    int m = wm * 32 + mf * 16 + lk * 4 + r;
                    int sl = m * 128 + ((n >> 3) ^ (m & 7)) * 8 + (n & 7);
                    float v = acc1[mf][nfr][r] + unbf(H[sl]);
                    v = fmaxf(v, 0.0f);
                    H[sl] = bf16s(v);
                }
        }
    }
    __syncthreads(); // hidden complete; S (src) reads done

    // ---- copy hidden -> global (overlaps GEMM-z); stage S <- nfa[dsts] ----
    #pragma unroll
    for (int j = 0; j < 2; ++j) {
        int q = j * 512 + t;
        int row = q >> 4, c16 = q & 15;
        int slot = c16 ^ (row & 7);
        *reinterpret_cast<uint4*>(&hid_out[(size_t)(e0 + row) * DD + c16 * 8]) =
            *reinterpret_cast<const uint4*>(&H[row * 128 + slot * 8]);
    }
    #pragma unroll
    for (int it = 0; it < 2; ++it) {
        int rb = w * 8 + it * 4;
        int row = rb + lrow;
        int c = lslot ^ (row & 7);
        gload_lds16(nfa + (size_t)dsts[e0 + row] * DD + c * 8, &S[rb * 128]);
    }

    // ---- GEMM-z: zpre = hidden @ mwB, K=128, N=128 ----
    f32x4 acc[2][2];
    #pragma unroll
    for (int mf = 0; mf < 2; ++mf)
        #pragma unroll
        for (int nfr = 0; nfr < 2; ++nfr) acc[mf][nfr] = (f32x4){0.f, 0.f, 0.f, 0.f};

    #pragma unroll
    for (int ks = 0; ks < 4; ++ks) {
        bf16x8 a[2];
        #pragma unroll
        for (int mf = 0; mf < 2; ++mf) {
            int m = wm * 32 + mf * 16 + lm;
            int slot = (ks * 4 + lk) ^ (m & 7);
            a[mf] = *reinterpret_cast<const bf16x8*>(&H[m * 128 + slot * 8]);
        }
        #pragma unroll
        for (int nfr = 0; nfr < 2; ++nfr) {
            int nt = wn * 2 + nfr;
            bf16x8 b = *reinterpret_cast<const bf16x8*>(&mwBp[((nt * 4 + ks) * 64 + l) * 8]);
            acc[0][nfr] = __builtin_amdgcn_mfma_f32_16x16x32_bf16(a[0], b, acc[0][nfr], 0, 0, 0);
            acc[1][nfr] = __builtin_amdgcn_mfma_f32_16x16x32_bf16(a[1], b, acc[1][nfr], 0, 0, 0);
        }
    }
    __syncthreads(); // nfa staged into S; H reads done

    // ---- z epilogue (all 8 waves): z = zpre + zb + nfa[dst]; leaky; dot aw2 ----
    {
        float zbv[2], aw2v[2];
        #pragma unroll
        for (int nfr = 0; nfr < 2; ++nfr) {
            int nc = (wn * 2 + nfr) * 16 + lm;
            zbv[nfr] = zb[nc];
            aw2v[nfr] = aw2[nc];
        }
        #pragma unroll
        for (int mf = 0; mf < 2; ++mf)
            #pragma unroll
            for (int r = 0; r < 4; ++r) {
                int m = wm * 32 + mf * 16 + lk * 4 + r;
                float s = 0.0f;
                #pragma unroll
                for (int nfr = 0; nfr < 2; ++nfr) {
                    int nc = (wn * 2 + nfr) * 16 + lm;
                    float v = acc[mf][nfr][r] + zbv[nfr]
                            + unbf(S[m * 128 + ((nc >> 3) ^ (m & 7)) * 8 + (nc & 7)]);
                    v = (v > 0.0f) ? v : 0.2f * v;
                    s = fmaf(v, aw2v[nfr], s);
                }
                s += __shfl_xor(s, 1, 64);
                s += __shfl_xor(s, 2, 64);
                s += __shfl_xor(s, 4, 64);
                s += __shfl_xor(s, 8, 64);
                if (lm == 0) RED[m][wn] = s;
            }
    }
    __syncthreads();

    if (t < 64) {
        attn_raw[e0 + t] = RED[t][0] + RED[t][1] + RED[t][2] + RED[t][3] + ab2[0];
    }
}

// ---------------- fused per-node softmax + hidden aggregate (bf16 out) ------
__global__ __launch_bounds__(256) void k_aggr(
    const unsigned short* __restrict__ hid, const float* __restrict__ raw,
    const int* __restrict__ row_start, const int* __restrict__ cnt,
    unsigned short* __restrict__ haggrb)
{
    const int l = threadIdx.x & 63;
    const int n = blockIdx.x * 4 + (threadIdx.x >> 6);
    if (n >= NN) return;
    const int rs = row_start[n], deg = cnt[n];

    float m = -INFINITY;
    for (int j = l; j < deg; j += 64) m = fmaxf(m, raw[rs + j]);
    #pragma unroll
    for (int off = 32; off >= 1; off >>= 1) m = fmaxf(m, __shfl_xor(m, off, 64));

    float s = 0.0f;
    for (int j = l; j < deg; j += 64) s += expf(raw[rs + j] - m);
    #pragma unroll
    for (int off = 32; off >= 1; off >>= 1) s += __shfl_xor(s, off, 64);
    const float rinv = 1.0f / (s + 1e-8f);

    float a0 = 0.0f, a1 = 0.0f;
    for (int j = 0; j < deg; ++j) {
        float w = expf(raw[rs + j] - m) * rinv;   // uniform across lanes
        unsigned int v = *reinterpret_cast<const unsigned int*>(
            &hid[(size_t)(rs + j) * DD + l * 2]);
        a0 = fmaf(w, unlo(v), a0);
        a1 = fmaf(w, unhi(v), a1);
    }
    *reinterpret_cast<unsigned int*>(&haggrb[(size_t)n * DD + l * 2]) = pk2(a0, a1);
}

// ---------------- node kernel: GEMM0(mw2) + LN1 + FFN + LN2 (8 waves) -------
__global__ __launch_bounds__(512) void k_node(
    const float* __restrict__ nf, const unsigned short* __restrict__ haggrb,
    const unsigned short* __restrict__ mw2p, const float* __restrict__ mb2,
    const float* __restrict__ g1, const float* __restrict__ b1,
    const unsigned short* __restrict__ fw1p, const float* __restrict__ fb1,
    const unsigned short* __restrict__ fw2p, const float* __restrict__ fb2,
    const float* __restrict__ g2, const float* __restrict__ b2,
    float* __restrict__ out)
{
    __shared__ alignas(16) unsigned short XB[64 * 128]; // 16 KB
    __shared__ alignas(16) unsigned short HB[64 * 256]; // 32 KB (first 16KB = HG)

    const int t = threadIdx.x;
    const int w = t >> 6, l = t & 63;
    const int wm = w >> 2, wn = w & 3;
    const int lm = l & 15, lk = l >> 4;
    const int lrow = l >> 4, lslot = l & 15;
    const int row = t >> 3;      // 0..63
    const int q = t & 7;         // 16-col segment
    const long n0 = (long)blockIdx.x * 64;
    const long rg = n0 + row;
    const long rc = (rg < NN) ? rg : (NN - 1);

    // ---- stage HG <- haggrb (swizzled src) ----
    unsigned short* HG = HB;
    #pragma unroll
    for (int it = 0; it < 2; ++it) {
        int rb = w * 8 + it * 4;
        int rr = rb + lrow;
        long grow = n0 + rr; if (grow >= NN) grow = NN - 1;
        int c = lslot ^ (rr & 7);
        gload_lds16(haggrb + grow * DD + c * 8, &HG[rb * 128]);
    }
    __syncthreads();

    // ---- GEMM0: aggr = haggr @ mw2 + mb2 -> XB (bf16, swizzled) ----
    {
        f32x4 acc0[2][2];
        #pragma unroll
        for (int mf = 0; mf < 2; ++mf)
            #pragma unroll
            for (int nfr = 0; nfr < 2; ++nfr) acc0[mf][nfr] = (f32x4){0.f, 0.f, 0.f, 0.f};

        #pragma unroll
        for (int ks = 0; ks < 4; ++ks) {
            bf16x8 a[2];
            #pragma unroll
            for (int mf = 0; mf < 2; ++mf) {
                int m = wm * 32 + mf * 16 + lm;
                int slot = (ks * 4 + lk) ^ (m & 7);
                a[mf] = *reinterpret_cast<const bf16x8*>(&HG[m * 128 + slot * 8]);
            }
            #pragma unroll
            for (int nfr = 0; nfr < 2; ++nfr) {
                int nt = wn * 2 + nfr;
                bf16x8 b = *reinterpret_cast<const bf16x8*>(&mw2p[((nt * 4 + ks) * 64 + l) * 8]);
                acc0[0][nfr] = __builtin_amdgcn_mfma_f32_16x16x32_bf16(a[0], b, acc0[0][nfr], 0, 0, 0);
                acc0[1][nfr] = __builtin_amdgcn_mfma_f32_16x16x32_bf16(a[1], b, acc0[1][nfr], 0, 0, 0);
            }
        }
        #pragma unroll
        for (int nfr = 0; nfr < 2; ++nfr) {
            int n = (wn * 2 + nfr) * 16 + lm;
            float bv = mb2[n];
            #pragma unroll
            for (int mf = 0; mf < 2; ++mf)
                #pragma unroll
                for (int r = 0; r < 4; ++r) {
                    int m = wm * 32 + mf * 16 + lk * 4 + r;
                    XB[m * 128 + ((n >> 3) ^ (m & 7)) * 8 + (n & 7)] = bf16s(acc0[mf][nfr][r] + bv);
                }
        }
    }
    __syncthreads(); // XB = aggr (bf16)

    // ---- LN1: x = nf + aggr ----
    float xr[16];
    float s = 0.0f, ss = 0.0f;
    {
        const float* xp = nf + rc * DD + q * 16;
        #pragma unroll
        for (int i = 0; i < 2; ++i) {
            int c = q * 2 + i, slot = c ^ (row & 7);
            uint4 v = *reinterpret_cast<const uint4*>(&XB[row * 128 + slot * 8]);
            float f[8];
            f[0] = unlo(v.x); f[1] = unhi(v.x); f[2] = unlo(v.y); f[3] = unhi(v.y);
            f[4] = unlo(v.z); f[5] = unhi(v.z); f[6] = unlo(v.w); f[7] = unhi(v.w);
            float4 a = *reinterpret_cast<const float4*>(xp + i * 8);
            float4 b = *reinterpret_cast<const float4*>(xp + i * 8 + 4);
            float vv[8] = {a.x + f[0], a.y + f[1], a.z + f[2], a.w + f[3],
                           b.x + f[4], b.y + f[5], b.z + f[6], b.w + f[7]};
            #pragma unroll
            for (int j = 0; j < 8; ++j) {
                xr[i * 8 + j] = vv[j];
                s += vv[j];
                ss = fmaf(vv[j], vv[j], ss);
            }
        }
    }
    s  += __shfl_xor(s, 1, 64);  s  += __shfl_xor(s, 2, 64);  s  += __shfl_xor(s, 4, 64);
    ss += __shfl_xor(ss, 1, 64); ss += __shfl_xor(ss, 2, 64); ss += __shfl_xor(ss, 4, 64);
    {
        float mu = s * (1.0f / DD);
        float var = ss * (1.0f / DD) - mu * mu;
        float rstd = rsqrtf(var + 1e-5f);
        #pragma unroll
        for (int i = 0; i < 4; ++i) {
            float4 gv = *reinterpret_cast<const float4*>(g1 + q * 16 + i * 4);
            float4 bv = *reinterpret_cast<const float4*>(b1 + q * 16 + i * 4);
            xr[i * 4 + 0] = (xr[i * 4 + 0] - mu) * rstd * gv.x + bv.x;
            xr[i * 4 + 1] = (xr[i * 4 + 1] - mu) * rstd * gv.y + bv.y;
            xr[i * 4 + 2] = (xr[i * 4 + 2] - mu) * rstd * gv.z + bv.z;
            xr[i * 4 + 3] = (xr[i * 4 + 3] - mu) * rstd * gv.w + bv.w;
        }
        #pragma unroll
        for (int i = 0; i < 2; ++i) {
            int c = q * 2 + i, slot = c ^ (row & 7);
            uint4 v;
            v.x = pk2(xr[i * 8 + 0], xr[i * 8 + 1]);
            v.y = pk2(xr[i * 8 + 2], xr[i * 8 + 3]);
            v.z = pk2(xr[i * 8 + 4], xr[i * 8 + 5]);
            v.w = pk2(xr[i * 8 + 6], xr[i * 8 + 7]);
            *reinterpret_cast<uint4*>(&XB[row * 128 + slot * 8]) = v;
        }
    }
    __syncthreads();

    // ---- FFN: two 256-col halves ----
    f32x4 acc2[2][2];
    #pragma unroll
    for (int mf = 0; mf < 2; ++mf)
        #pragma unroll
        for (int nfr = 0; nfr < 2; ++nfr) acc2[mf][nfr] = (f32x4){0.f, 0.f, 0.f, 0.f};

    #pragma unroll
    for (int half = 0; half < 2; ++half) {
        f32x4 acc[2][4];
        #pragma unroll
        for (int mf = 0; mf < 2; ++mf)
            #pragma unroll
            for (int nfr = 0; nfr < 4; ++nfr) acc[mf][nfr] = (f32x4){0.f, 0.f, 0.f, 0.f};

        #pragma unroll
        for (int ks = 0; ks < 4; ++ks) {
            bf16x8 a[2];
            #pragma unroll
            for (int mf = 0; mf < 2; ++mf) {
                int m = wm * 32 + mf * 16 + lm;
                int slot = (ks * 4 + lk) ^ (m & 7);
                a[mf] = *reinterpret_cast<const bf16x8*>(&XB[m * 128 + slot * 8]);
            }
            #pragma unroll
            for (int nfr = 0; nfr < 4; ++nfr) {
                int nt = half * 16 + wn * 4 + nfr;
                bf16x8 b = *reinterpret_cast<const bf16x8*>(&fw1p[((nt * 4 + ks) * 64 + l) * 8]);
                acc[0][nfr] = __builtin_amdgcn_mfma_f32_16x16x32_bf16(a[0], b, acc[0][nfr], 0, 0, 0);
                acc[1][nfr] = __builtin_amdgcn_mfma_f32_16x16x32_bf16(a[1], b, acc[1][nfr], 0, 0, 0);
            }
        }
        #pragma unroll
        for (int nfr = 0; nfr < 4; ++nfr) {
            int nl = (wn * 4 + nfr) * 16 + lm;
            float bv = fb1[half * 256 + nl];
            #pragma unroll
            for (int mf = 0; mf < 2; ++mf)
                #pragma unroll
                for (int r = 0; r < 4; ++r) {
                    int m = wm * 32 + mf * 16 + lk * 4 + r;
                    float h = acc[mf][nfr][r] + bv;
                    float e = __expf(h * -1.702f);
                    float gvv = h * __builtin_amdgcn_rcpf(1.0f + e);
                    HB[m * 256 + (((nl >> 3) ^ (m & 7)) * 8) + (nl & 7)] = bf16s(gvv);
                }
        }
        __syncthreads();

        #pragma unroll
        for (int ks = 0; ks < 8; ++ks) {
            bf16x8 a[2];
            #pragma unroll
            for (int mf = 0; mf < 2; ++mf) {
                int m = wm * 32 + mf * 16 + lm;
                int slot = (ks * 4 + lk) ^ (m & 7);
                a[mf] = *reinterpret_cast<const bf16x8*>(&HB[m * 256 + slot * 8]);
            }
            #pragma unroll
            for (int nfr = 0; nfr < 2; ++nfr) {
                int nt = wn * 2 + nfr;
                int kg = half * 8 + ks;
                bf16x8 b = *reinterpret_cast<const bf16x8*>(&fw2p[((nt * 16 + kg) * 64 + l) * 8]);
                acc2[0][nfr] = __builtin_amdgcn_mfma_f32_16x16x32_bf16(a[0], b, acc2[0][nfr], 0, 0, 0);
                acc2[1][nfr] = __builtin_amdgcn_mfma_f32_16x16x32_bf16(a[1], b, acc2[1][nfr], 0, 0, 0);
            }
        }
        __syncthreads();
    }

    // ---- ffn -> XB (bf16) ----
    #pragma unroll
    for (int nfr = 0; nfr < 2; ++nfr) {
        int n = (wn * 2 + nfr) * 16 + lm;
        float bv = fb2[n];
        #pragma unroll
        for (int mf = 0; mf < 2; ++mf)
            #pragma unroll
            for (int r = 0; r < 4; ++r) {
                int m = wm * 32 + mf * 16 + lk * 4 + r;
                XB[m * 128 + (((n >> 3) ^ (m & 7)) * 8) + (n & 7)] = bf16s(acc2[mf][nfr][r] + bv);
            }
    }
    __syncthreads();

    // ---- residual + LN2 ----
    float s2 = 0.0f, ss2 = 0.0f;
    #pragma unroll
    for (int i = 0; i < 2; ++i) {
        int c = q * 2 + i, slot = c ^ (row & 7);
        uint4 v = *reinterpret_cast<const uint4*>(&XB[row * 128 + slot * 8]);
        float f[8];
        f[0] = unlo(v.x); f[1] = unhi(v.x); f[2] = unlo(v.y); f[3] = unhi(v.y);
        f[4] = unlo(v.z); f[5] = unhi(v.z); f[6] = unlo(v.w); f[7] = unhi(v.w);
        #pragma unroll
        for (int j = 0; j < 8; ++j) {
            float vv = xr[i * 8 + j] + f[j];
            xr[i * 8 + j] = vv;
            s2 += vv;
            ss2 = fmaf(vv, vv, ss2);
        }
    }
    s2  += __shfl_xor(s2, 1, 64);  s2  += __shfl_xor(s2, 2, 64);  s2  += __shfl_xor(s2, 4, 64);
    ss2 += __shfl_xor(ss2, 1, 64); ss2 += __shfl_xor(ss2, 2, 64); ss2 += __shfl_xor(ss2, 4, 64);
    {
        float mu = s2 * (1.0f / DD);
        float var = ss2 * (1.0f / DD) - mu * mu;
        float rstd = rsqrtf(var + 1e-5f);
        if (rg < NN) {
            float* op = out + rg * DD + q * 16;
            #pragma unroll
            for (int i = 0; i < 4; ++i) {
                float4 gv = *reinterpret_cast<const float4*>(g2 + q * 16 + i * 4);
                float4 bv = *reinterpret_cast<const float4*>(b2 + q * 16 + i * 4);
                float4 o;
                o.x = (xr[i * 4 + 0] - mu) * rstd * gv.x + bv.x;
                o.y = (xr[i * 4 + 1] - mu) * rstd * gv.y + bv.y;
                o.z = (xr[i * 4 + 2] - mu) * rstd * gv.z + bv.z;
                o.w = (xr[i * 4 + 3] - mu) * rstd * gv.w + bv.w;
                *reinterpret_cast<float4*>(op + i * 4) = o;
            }
        }
    }
}

extern "C" void kernel_launch(void* const* d_in, const int* in_sizes, int n_in,
                              void* d_out, int out_size, void* d_ws, size_t ws_size,
                              hipStream_t stream)
{
    const float* nf  = (const float*)d_in[0];
    const int*   ei  = (const int*)d_in[1];
    const int*   et  = (const int*)d_in[2];
    const float* rel = (const float*)d_in[3];
    const float* mw1 = (const float*)d_in[4];
    const float* mb1 = (const float*)d_in[5];
    const float* mw2 = (const float*)d_in[6];
    const float* mb2 = (const float*)d_in[7];
    const float* aw1 = (const float*)d_in[8];
    const float* ab1 = (const float*)d_in[9];
    const float* aw2 = (const float*)d_in[10];
    const float* ab2 = (const float*)d_in[11];
    const float* g1  = (const float*)d_in[12];
    const float* b1  = (const float*)d_in[13];
    const float* fw1 = (const float*)d_in[14];
    const float* fb1 = (const float*)d_in[15];
    const float* fw2 = (const float*)d_in[16];
    const float* fb2 = (const float*)d_in[17];
    const float* g2  = (const float*)d_in[18];
    const float* b2  = (const float*)d_in[19];
    float* out = (float*)d_out;

    char* ws = (char*)d_ws;
    size_t off = 0;
    auto alloc = [&](size_t bytes) -> char* {
        char* p = ws + off;
        off += (bytes + 255) & ~(size_t)255;
        return p;
    };
    unsigned short* hid = (unsigned short*)alloc((size_t)NE * DD * 2);
    float* attn_raw = (float*)alloc((size_t)NE * 4);
    unsigned short* haggrb = (unsigned short*)alloc((size_t)NN * DD * 2);
    unsigned short* nfb  = (unsigned short*)alloc((size_t)NN * DD * 2);
    unsigned short* relcb = (unsigned short*)alloc((size_t)RR * DD * 2);
    float* zb  = (float*)alloc((size_t)128 * 4);
    int* cnt       = (int*)alloc((size_t)NN * 4);
    int* row_start = (int*)alloc((size_t)NN * 4);
    int* cursor    = (int*)alloc((size_t)NN * 4);
    int* srcs      = (int*)alloc((size_t)NE * 4);
    int* ets       = (int*)alloc((size_t)NE * 4);
    int* dsts      = (int*)alloc((size_t)NE * 4);
    int* bsum      = (int*)alloc((size_t)SCAN_NB * 4);
    unsigned short* mw1p = (unsigned short*)alloc(16384 * 2);
    unsigned short* mw2p = (unsigned short*)alloc(16384 * 2);
    unsigned short* awTp = (unsigned short*)alloc(16384 * 2);
    unsigned short* mwBp = (unsigned short*)alloc(16384 * 2);
    unsigned short* fw1p = (unsigned short*)alloc(65536 * 2);
    unsigned short* fw2p = (unsigned short*)alloc(65536 * 2);

    // nfa aliases haggrb (nfa dead after k_edge; haggrb written by k_aggr)
    unsigned short* nfa = haggrb;

    const int* srcp = ei;
    const int* dstp = ei + NE;

    hipLaunchKernelGGL(k_initc, dim3(SCAN_NB), dim3(256), 0, stream, cnt);
    hipLaunchKernelGGL(k_hist, dim3((NE + 255) / 256), dim3(256), 0, stream, dstp, cnt);
    hipLaunchKernelGGL(k_scanA, dim3(SCAN_NB), dim3(256), 0, stream, cnt, bsum);
    hipLaunchKernelGGL(k_scanB, dim3(1), dim3(512), 0, stream, bsum);
    hipLaunchKernelGGL(k_scanC, dim3(SCAN_NB), dim3(256), 0, stream, cnt, bsum, row_start, cursor);
    hipLaunchKernelGGL(k_bucket, dim3((NE + 255) / 256), dim3(256), 0, stream,
                       srcp, dstp, et, cursor, srcs, ets, dsts);
    hipLaunchKernelGGL(k_prep, dim3(NN * DD / 8 / 256), dim3(256), 0, stream, nf, nfb);
    hipLaunchKernelGGL(k_setup, dim3(869), dim3(256), 0, stream,
                       mw1, mb1, mw2, mb2, aw1, rel, fw1, fw2,
                       mw1p, mw2p, awTp, mwBp, fw1p, fw2p, relcb, zb);
    hipLaunchKernelGGL(k_nfa, dim3((NN + 63) / 64), dim3(256), 0, stream,
                       nfb, awTp, ab1, nfa);
    hipLaunchKernelGGL(k_edge, dim3(NE / 64), dim3(512), 0, stream,
                       nfb, srcs, dsts, ets, nfa, relcb,
                       mw1p, mwBp, zb, aw2, ab2,
                       hid, attn_raw);
    hipLaunchKernelGGL(k_aggr, dim3((NN + 3) / 4), dim3(256), 0, stream,
                       hid, attn_raw, row_start, cnt, haggrb);
    hipLaunchKernelGGL(k_node, dim3((NN + 63) / 64), dim3(512), 0, stream,
                       nf, haggrb, mw2p, mb2, g1, b1, fw1p, fb1, fw2p, fb2, g2, b2, out);
}